// Round 9
// baseline (480.792 us; speedup 1.0000x reference)
//
#include <hip/hip_runtime.h>
#include <math.h>

#define L_ 384
#define R_ 128
#define D_ 128
#define H_ 8
#define DH_ 64
#define INNER_ 512

typedef __bf16 bf16x8 __attribute__((ext_vector_type(8)));
typedef __bf16 bf16x4 __attribute__((ext_vector_type(4)));
typedef float f32x4 __attribute__((ext_vector_type(4)));

__device__ __forceinline__ float wred_sum(float v) {
#pragma unroll
  for (int o = 32; o > 0; o >>= 1) v += __shfl_xor(v, o, 64);
  return v;
}
__device__ __forceinline__ float wred_max(float v) {
#pragma unroll
  for (int o = 32; o > 0; o >>= 1) v = fmaxf(v, __shfl_xor(v, o, 64));
  return v;
}

// ---------------------------------------------------------------------------
// prep: m fp32->bf16 AND mT (per-r transposed m) (blocks 0..1535, 64x64 tiles)
//       + all weight transposes (blocks 1536..1671)
// ---------------------------------------------------------------------------
__global__ __launch_bounds__(256) void prep_kernel(
    const float* __restrict__ m, __bf16* __restrict__ m_bf,
    const float* __restrict__ Wq_w, const float* __restrict__ Wkv_w,
    const float* __restrict__ Wq_h, const float* __restrict__ Wkv_h,
    const float* __restrict__ Wo_w, const float* __restrict__ Wo_h,
    const float* __restrict__ Wsk, const float* __restrict__ Wsq,
    __bf16* __restrict__ WTw, __bf16* __restrict__ WThqk,
    __bf16* __restrict__ WTvh, __bf16* __restrict__ WoTw,
    __bf16* __restrict__ WoTh, __bf16* __restrict__ WskT,
    __bf16* __restrict__ WsqT, __bf16* __restrict__ mT) {
  __shared__ float Ls[64 * 65];
  int b = blockIdx.x;
  int t = threadIdx.x;
  if (b < 1536) {
    // m tile: r = b/12, 6 j-tiles x 2 c-tiles of 64x64
    int r = b / 12, tile = b - r * 12;
    int j0 = (tile >> 1) * 64, c0v = (tile & 1) * 64;
#pragma unroll
    for (int u = 0; u < 4; ++u) {
      int flat = t + 256 * u;
      int jr = flat >> 4, cc = (flat & 15) * 4;
      size_t idx = ((size_t)(r * L_ + j0 + jr)) * 128 + c0v + cc;
      float4 v = *(const float4*)&m[idx];
      Ls[jr * 65 + cc + 0] = v.x;
      Ls[jr * 65 + cc + 1] = v.y;
      Ls[jr * 65 + cc + 2] = v.z;
      Ls[jr * 65 + cc + 3] = v.w;
      bf16x4 o4;
      o4[0] = (__bf16)v.x; o4[1] = (__bf16)v.y; o4[2] = (__bf16)v.z; o4[3] = (__bf16)v.w;
      *(uint2*)&m_bf[idx] = __builtin_bit_cast(uint2, o4);
    }
    __syncthreads();
#pragma unroll
    for (int u = 0; u < 2; ++u) {
      int flat = t + 256 * u;
      int cr = flat >> 3, jc = (flat & 7) * 8;
      bf16x8 o;
#pragma unroll
      for (int q = 0; q < 8; ++q) o[q] = (__bf16)Ls[(jc + q) * 65 + cr];
      *(uint4*)&mT[((size_t)(r * 128 + c0v + cr)) * L_ + j0 + jc] =
          __builtin_bit_cast(uint4, o);
    }
    return;
  }
  int j = b - 1536;
  const float* src; __bf16* dst; int Kd, Ns, noff, gx, base;
  if (j < 16)       { src = Wq_w;  dst = WTw;             Kd = 128; Ns = 512;  noff = 0;   gx = 8;  base = 0; }
  else if (j < 48)  { src = Wkv_w; dst = WTw + 512 * 128; Kd = 128; Ns = 1024; noff = 0;   gx = 16; base = 16; }
  else if (j < 64)  { src = Wq_h;  dst = WThqk;           Kd = 128; Ns = 512;  noff = 0;   gx = 8;  base = 48; }
  else if (j < 80)  { src = Wkv_h; dst = WThqk + 512 * 128; Kd = 128; Ns = 1024; noff = 0; gx = 8;  base = 64; }
  else if (j < 96)  { src = Wkv_h; dst = WTvh;            Kd = 128; Ns = 1024; noff = 512; gx = 8;  base = 80; }
  else if (j < 112) { src = Wo_w;  dst = WoTw;            Kd = 512; Ns = 128;  noff = 0;   gx = 2;  base = 96; }
  else if (j < 128) { src = Wo_h;  dst = WoTh;            Kd = 512; Ns = 128;  noff = 0;   gx = 2;  base = 112; }
  else if (j < 132) { src = Wsk;   dst = WskT;            Kd = 128; Ns = 128;  noff = 0;   gx = 2;  base = 128; }
  else              { src = Wsq;   dst = WsqT;            Kd = 128; Ns = 128;  noff = 0;   gx = 2;  base = 132; }
  int jl = j - base;
  int n0 = (jl % gx) * 64, k0 = (jl / gx) * 64;
#pragma unroll
  for (int u = 0; u < 4; ++u) {
    int flat = t + 256 * u;
    int kr = flat >> 4, nc = (flat & 15) * 4;
    float4 v = *(const float4*)&src[(size_t)(k0 + kr) * Ns + noff + n0 + nc];
    Ls[kr * 65 + nc + 0] = v.x;
    Ls[kr * 65 + nc + 1] = v.y;
    Ls[kr * 65 + nc + 2] = v.z;
    Ls[kr * 65 + nc + 3] = v.w;
  }
  __syncthreads();
#pragma unroll
  for (int u = 0; u < 2; ++u) {
    int flat = t + 256 * u;
    int nr = flat >> 3, kc = (flat & 7) * 8;
    bf16x8 o;
#pragma unroll
    for (int q = 0; q < 8; ++q) o[q] = (__bf16)Ls[(kc + q) * 65 + nr];
    *(uint4*)&dst[(size_t)(n0 + nr) * Kd + k0 + kc] = __builtin_bit_cast(uint4, o);
  }
}

// ---------------------------------------------------------------------------
// wf_kernel: WfT[h][e][c] = sum_d Wo[h*64+d][e] * Wv[c][h*64+d]
// One block per head. A = WoTh rows (bf16), B = Wkv_h fp32 cols 512.. (convert).
// ---------------------------------------------------------------------------
__global__ __launch_bounds__(256) void wf_kernel(const float* __restrict__ Wkv_h,
                                                 const __bf16* __restrict__ WoTh,
                                                 __bf16* __restrict__ wft) {
  __shared__ __bf16 shm[2 * 128 * 72];
  __bf16* As = shm;
  __bf16* Bs = shm + 128 * 72;
  const int h = blockIdx.x;
  const int t = threadIdx.x;
  const int lane = t & 63, w = t >> 6;
  const int wm = w >> 1, wn = w & 1;
  const int lc = lane & 15, q8 = (lane >> 4) << 3;
  const int lr4 = (lane >> 4) << 2;
#pragma unroll
  for (int u = 0; u < 4; ++u) {
    int flat = t + 256 * u;
    int row = flat >> 3, c8 = (flat & 7) << 3;
    *(uint4*)&As[row * 72 + c8] = *(const uint4*)&WoTh[(size_t)row * 512 + h * 64 + c8];
    float4 a = *(const float4*)&Wkv_h[(size_t)row * 1024 + 512 + h * 64 + c8];
    float4 b = *(const float4*)&Wkv_h[(size_t)row * 1024 + 512 + h * 64 + c8 + 4];
    bf16x8 o;
    o[0] = (__bf16)a.x; o[1] = (__bf16)a.y; o[2] = (__bf16)a.z; o[3] = (__bf16)a.w;
    o[4] = (__bf16)b.x; o[5] = (__bf16)b.y; o[6] = (__bf16)b.z; o[7] = (__bf16)b.w;
    *(uint4*)&Bs[row * 72 + c8] = __builtin_bit_cast(uint4, o);
  }
  __syncthreads();
  f32x4 acc[4][4];
#pragma unroll
  for (int i = 0; i < 4; ++i)
#pragma unroll
    for (int j = 0; j < 4; ++j) acc[i][j] = (f32x4){0.f, 0.f, 0.f, 0.f};
#pragma unroll
  for (int kt = 0; kt < 2; ++kt) {
    bf16x8 af[4], bfr[4];
#pragma unroll
    for (int i = 0; i < 4; ++i) {
      af[i] = *(const bf16x8*)&As[(wm * 64 + i * 16 + lc) * 72 + kt * 32 + q8];
      bfr[i] = *(const bf16x8*)&Bs[(wn * 64 + i * 16 + lc) * 72 + kt * 32 + q8];
    }
#pragma unroll
    for (int i = 0; i < 4; ++i)
#pragma unroll
      for (int j = 0; j < 4; ++j)
        acc[i][j] = __builtin_amdgcn_mfma_f32_16x16x32_bf16(af[i], bfr[j], acc[i][j], 0, 0, 0);
  }
  __syncthreads();
  __bf16* St = shm;
#pragma unroll
  for (int i = 0; i < 4; ++i)
#pragma unroll
    for (int j = 0; j < 4; ++j)
#pragma unroll
      for (int g = 0; g < 4; ++g)
        St[(wm * 64 + i * 16 + lr4 + g) * 136 + wn * 64 + j * 16 + lc] = (__bf16)acc[i][j][g];
  __syncthreads();
#pragma unroll
  for (int u = 0; u < 8; ++u) {
    int flat = t + 256 * u;
    int row = flat >> 4, c8 = (flat & 15) << 3;
    *(uint4*)&wft[(size_t)h * 16384 + row * 128 + c8] = *(uint4*)&St[row * 136 + c8];
  }
}

// ---------------------------------------------------------------------------
// bf16 MFMA GEMM, 128x128 tile, BK=64, 256 threads (4 waves 2x2), 16x16x32 mfma.
// MODE 1: PROJ_H   A=m_bf, B=WThqk, C->qh (tie-scaled) / kh
// MODE 2: DOTS     pure NT GEMM, 1D XCD-swizzled grid, split-K partials fp32
// MODE 4: OUT_W    C = 0.5*(acc+bias) -> out fp32
// MODE 8: TIE PROJ ks (m0<49152) / qs (m0>=49152, B=O2=WsqT, bias=tie=bsq)
// ---------------------------------------------------------------------------
template <int MODE>
__global__ __launch_bounds__(256) void mm_k(
    const __bf16* __restrict__ A, const __bf16* __restrict__ B,
    const float* __restrict__ bias, const float* __restrict__ tie,
    __bf16* __restrict__ O0, __bf16* __restrict__ O1, __bf16* __restrict__ O2,
    float* __restrict__ F0,
    int K, int c0, int Rc, int KT, int firstChunk, int S) {
  __shared__ __bf16 shm[2 * 128 * 72];
  __bf16* As = shm;
  __bf16* Bs = shm + 128 * 72;
  const int t = threadIdx.x;
  const int lane = t & 63, w = t >> 6;
  const int wm = w >> 1, wn = w & 1;
  int n0, m0, h = 0, s = 0, kOff = 0;
  if (MODE == 2) {
    int b = blockIdx.x;
    int xcd = b & 7, t2 = b >> 3;
    int i3 = t2 % 3, slot = t2 / 3;
    int g = xcd * (gridDim.x / 24) + slot;
    n0 = i3 * 128;
    m0 = (g % 3) * 128;
    int z = g / 3;
    h = z / S; s = z % S; kOff = s * K;
  } else if (MODE == 1) {
    const int gx = 8;
    int nb = gx * gridDim.y;
    int bid = blockIdx.y * gx + blockIdx.x;
    int vv = (bid & 7) * (nb >> 3) + (bid >> 3);
    n0 = (vv % gx) * 128;
    m0 = (vv / gx) * 128;
  } else {
    n0 = blockIdx.x * 128;
    m0 = blockIdx.y * 128;
  }
  const int pbase = (MODE == 8 && m0 >= 49152) ? 49152 : 0;
  const __bf16* Bmat = (MODE == 8 && pbase) ? (const __bf16*)O2 : B;

  f32x4 acc[4][4];
#pragma unroll
  for (int i = 0; i < 4; ++i)
#pragma unroll
    for (int j = 0; j < 4; ++j) acc[i][j] = (f32x4){0.f, 0.f, 0.f, 0.f};

  for (int k0 = 0; k0 < K; k0 += 64) {
#pragma unroll
    for (int u = 0; u < 4; ++u) {
      int flat = t + 256 * u;
      int row = flat >> 3;
      int c8 = (flat & 7) << 3;
      const __bf16* ap;
      int p = m0 + row;
      if (MODE == 1) ap = A + ((size_t)(c0 * L_ + p)) * 128 + k0 + c8;
      else if (MODE == 2) ap = A + ((size_t)(h * L_ + p)) * KT + kOff + k0 + c8;
      else if (MODE == 4) ap = A + (size_t)p * INNER_ + k0 + c8;
      else ap = A + (size_t)(p - pbase) * 128 + k0 + c8;
      *(uint4*)&As[row * 72 + c8] = *(const uint4*)ap;
      const __bf16* bp;
      int n = n0 + row;
      if (MODE == 1 || MODE == 8) bp = Bmat + (size_t)n * 128 + k0 + c8;
      else if (MODE == 2) bp = B + ((size_t)(h * L_ + n)) * KT + kOff + k0 + c8;
      else bp = B + (size_t)n * INNER_ + k0 + c8;
      *(uint4*)&Bs[row * 72 + c8] = *(const uint4*)bp;
    }
    __syncthreads();
    {
      int lc = lane & 15, q8 = (lane >> 4) << 3;
#pragma unroll
      for (int kt = 0; kt < 2; ++kt) {
        bf16x8 af[4], bfr[4];
#pragma unroll
        for (int i = 0; i < 4; ++i) {
          af[i] = *(const bf16x8*)&As[(wm * 64 + i * 16 + lc) * 72 + kt * 32 + q8];
          bfr[i] = *(const bf16x8*)&Bs[(wn * 64 + i * 16 + lc) * 72 + kt * 32 + q8];
        }
#pragma unroll
        for (int i = 0; i < 4; ++i)
#pragma unroll
          for (int j = 0; j < 4; ++j)
            acc[i][j] = __builtin_amdgcn_mfma_f32_16x16x32_bf16(af[i], bfr[j], acc[i][j], 0, 0, 0);
      }
    }
    __syncthreads();
  }

  const int lce = lane & 15, lr4 = (lane >> 4) << 2;

  float tw[4][4];
  if (MODE == 1 && n0 < 512) {
    float* tieS = (float*)shm;
    int row = t >> 1, hh2 = t & 1;
    int pmt = m0 + row;
    int rrelt = pmt / L_, lt = pmt - rrelt * L_;
    int h0 = n0 >> 6;
    tieS[row * 2 + hh2] = tie[((size_t)(lt * H_ + h0 + hh2)) * R_ + c0 + rrelt];
    __syncthreads();
#pragma unroll
    for (int i = 0; i < 4; ++i)
#pragma unroll
      for (int g = 0; g < 4; ++g)
        tw[i][g] = tieS[(wm * 64 + i * 16 + lr4 + g) * 2 + wn];
    __syncthreads();
  }

  if (MODE == 1 || MODE == 8) {
    __bf16* St = shm;
    const float* bb8 = (MODE == 8) ? (pbase ? tie : bias) : nullptr;
#pragma unroll
    for (int i = 0; i < 4; ++i)
#pragma unroll
      for (int j = 0; j < 4; ++j)
#pragma unroll
        for (int g = 0; g < 4; ++g) {
          float v = acc[i][j][g];
          if (MODE == 1 && n0 < 512) v *= tw[i][g];
          if (MODE == 8) v += bb8[n0 + wn * 64 + j * 16 + lce];
          St[(wm * 64 + i * 16 + lr4 + g) * 136 + wn * 64 + j * 16 + lce] = (__bf16)v;
        }
    __syncthreads();
#pragma unroll
    for (int u = 0; u < 8; ++u) {
      int flat = t + 256 * u;
      int row = flat >> 4, c8 = (flat & 15) << 3;
      uint4 val = *(uint4*)&St[row * 136 + c8];
      int pm = m0 + row, pn = n0 + c8;
      if (MODE == 1) {
        int nn = pn;
        int rrel = pm / L_, l = pm - rrel * L_;
        if (nn < 512) {
          int hh = nn >> 6, dh = nn & 63;
          *(uint4*)&O0[(((size_t)(hh * L_ + l)) * Rc + rrel) * 64 + dh] = val;
        } else {
          nn -= 512;
          int hh = nn >> 6, dh = nn & 63;
          *(uint4*)&O1[(((size_t)(hh * L_ + l)) * Rc + rrel) * 64 + dh] = val;
        }
      } else {  // MODE 8
        __bf16* dst = pbase ? O1 : O0;
        *(uint4*)&dst[(size_t)(pm - pbase) * 128 + pn] = val;
      }
    }
  } else {
    // fp32 epilogue (modes 2/4)
    float* Sf = (float*)shm;
#pragma unroll
    for (int half = 0; half < 2; ++half) {
      if (half) __syncthreads();
      if (wm == half) {
#pragma unroll
        for (int i = 0; i < 4; ++i)
#pragma unroll
          for (int j = 0; j < 4; ++j)
#pragma unroll
            for (int g = 0; g < 4; ++g)
              Sf[(i * 16 + lr4 + g) * 132 + wn * 64 + j * 16 + lce] = acc[i][j][g];
      }
      __syncthreads();
#pragma unroll
      for (int u = 0; u < 8; ++u) {
        int flat = t + 256 * u;
        int row = flat >> 5, c4 = (flat & 31) << 2;
        float4 v = *(float4*)&Sf[row * 132 + c4];
        int pm = m0 + half * 64 + row, pn = n0 + c4;
        if (MODE == 2) {
          float* ptr = F0 + ((size_t)(s * H_ + h)) * (L_ * L_) + (size_t)pm * L_ + pn;
          v.x *= 0.125f; v.y *= 0.125f; v.z *= 0.125f; v.w *= 0.125f;
          if (firstChunk) {
            *(float4*)ptr = v;
          } else {
            float4 o = *(float4*)ptr;
            o.x += v.x; o.y += v.y; o.z += v.z; o.w += v.w;
            *(float4*)ptr = o;
          }
        } else {  // MODE 4
          float4 bv = *(const float4*)&bias[pn];
          int lrel = pm >> 7, rr = pm & 127;
          float4 o;
          o.x = 0.5f * (v.x + bv.x); o.y = 0.5f * (v.y + bv.y);
          o.z = 0.5f * (v.z + bv.z); o.w = 0.5f * (v.w + bv.w);
          *(float4*)&F0[((size_t)(rr * L_ + c0 + lrel)) * 128 + pn] = o;
        }
      }
    }
  }
}

// ---------------------------------------------------------------------------
// FUSED OH + OUT_H, round-9 geometry: 64-row l-tiles -> grid 768 (3 blocks/CU
// exact balance; LDS 35840 B = 18 granules -> 4 blocks/CU capacity).
// Per block (r, lt): for h in 0..7: T-GEMM [64][128] = attnb[h][l-tile] @ m[r]
// (K=384, B=mT), stage T bf16, acc_out += T @ WfT[h] (K=128, 2 halves).
// Epilogue: single-pass fp32 stage + float4 RMW into out.
// ---------------------------------------------------------------------------
__global__ __launch_bounds__(256, 4) void foh_kernel(
    const __bf16* __restrict__ ab, const __bf16* __restrict__ mT,
    const __bf16* __restrict__ wft, const float* __restrict__ bias,
    float* __restrict__ out) {
  __shared__ __bf16 smem[17920];  // 35840 B
  __bf16* As = smem;            // [64][72]  T-GEMM A (4608)
  __bf16* Bs = smem + 4608;     // [128][72] T-GEMM B (ends 13824)
  __bf16* Ts = smem;            // [64][136] staged T (8704, overlays As+Bs head)
  __bf16* Ws = smem + 8704;     // [128][72] WfT half (ends 17920)
  int bid = blockIdx.x;
  int vv = (bid & 7) * (gridDim.x >> 3) + (bid >> 3);
  int lt = vv % 6, r = vv / 6;
  int l0 = lt * 64;
  const int t = threadIdx.x;
  const int lane = t & 63, w = t >> 6;
  const int wm = w >> 1, wn = w & 1;
  const int lc = lane & 15, q8 = (lane >> 4) << 3;
  const int lr4 = (lane >> 4) << 2;

  f32x4 aco[2][4];
#pragma unroll
  for (int i = 0; i < 2; ++i)
#pragma unroll
    for (int j = 0; j < 4; ++j) aco[i][j] = (f32x4){0.f, 0.f, 0.f, 0.f};

  for (int h = 0; h < H_; ++h) {
    f32x4 act[2][4];
#pragma unroll
    for (int i = 0; i < 2; ++i)
#pragma unroll
      for (int j = 0; j < 4; ++j) act[i][j] = (f32x4){0.f, 0.f, 0.f, 0.f};

    // T-GEMM: T[l][c] = sum_j attnb[h][l0+l][j] * m[r][j][c], K=384
    for (int k0 = 0; k0 < L_; k0 += 64) {
#pragma unroll
      for (int u = 0; u < 2; ++u) {
        int flat = t + 256 * u;
        int row = flat >> 3, c8 = (flat & 7) << 3;
        *(uint4*)&As[row * 72 + c8] =
            *(const uint4*)&ab[((size_t)(h * L_ + l0 + row)) * L_ + k0 + c8];
      }
#pragma unroll
      for (int u = 0; u < 4; ++u) {
        int flat = t + 256 * u;
        int row = flat >> 3, c8 = (flat & 7) << 3;
        *(uint4*)&Bs[row * 72 + c8] =
            *(const uint4*)&mT[((size_t)(r * 128 + row)) * L_ + k0 + c8];
      }
      __syncthreads();
#pragma unroll
      for (int kt = 0; kt < 2; ++kt) {
        bf16x8 af[2], bfr[4];
#pragma unroll
        for (int i = 0; i < 2; ++i)
          af[i] = *(const bf16x8*)&As[(wm * 32 + i * 16 + lc) * 72 + kt * 32 + q8];
#pragma unroll
        for (int j = 0; j < 4; ++j)
          bfr[j] = *(const bf16x8*)&Bs[(wn * 64 + j * 16 + lc) * 72 + kt * 32 + q8];
#pragma unroll
        for (int i = 0; i < 2; ++i)
#pragma unroll
          for (int j = 0; j < 4; ++j)
            act[i][j] = __builtin_amdgcn_mfma_f32_16x16x32_bf16(af[i], bfr[j], act[i][j], 0, 0, 0);
      }
      __syncthreads();
    }

    // stage T as bf16 [64][136] (overlays As+Bs head; safe after last barrier)
#pragma unroll
    for (int i = 0; i < 2; ++i)
#pragma unroll
      for (int j = 0; j < 4; ++j)
#pragma unroll
        for (int g = 0; g < 4; ++g)
          Ts[(wm * 32 + i * 16 + lr4 + g) * 136 + wn * 64 + j * 16 + lc] =
              (__bf16)act[i][j][g];
    __syncthreads();

    // acc_out += T @ WfT[h]: K=128 in 2 halves of 64
#pragma unroll
    for (int kh = 0; kh < 2; ++kh) {
#pragma unroll
      for (int u = 0; u < 4; ++u) {
        int flat = t + 256 * u;
        int row = flat >> 3, c8 = (flat & 7) << 3;
        *(uint4*)&Ws[row * 72 + c8] =
            *(const uint4*)&wft[(size_t)h * 16384 + row * 128 + kh * 64 + c8];
      }
      __syncthreads();
#pragma unroll
      for (int kt = 0; kt < 2; ++kt) {
        bf16x8 af[2], bfr[4];
#pragma unroll
        for (int i = 0; i < 2; ++i)
          af[i] = *(const bf16x8*)&Ts[(wm * 32 + i * 16 + lc) * 136 + kh * 64 + kt * 32 + q8];
#pragma unroll
        for (int j = 0; j < 4; ++j)
          bfr[j] = *(const bf16x8*)&Ws[(wn * 64 + j * 16 + lc) * 72 + kt * 32 + q8];
#pragma unroll
        for (int i = 0; i < 2; ++i)
#pragma unroll
          for (int j = 0; j < 4; ++j)
            aco[i][j] = __builtin_amdgcn_mfma_f32_16x16x32_bf16(af[i], bfr[j], aco[i][j], 0, 0, 0);
      }
      __syncthreads();
    }
  }

  // single-pass fp32 staged epilogue: out RMW (+= 0.5*(acc+bias))
  float* Sf = (float*)smem;  // [64][132] fp32 = 33792 B
#pragma unroll
  for (int i = 0; i < 2; ++i)
#pragma unroll
    for (int j = 0; j < 4; ++j)
#pragma unroll
      for (int g = 0; g < 4; ++g)
        Sf[(wm * 32 + i * 16 + lr4 + g) * 132 + wn * 64 + j * 16 + lc] = aco[i][j][g];
  __syncthreads();
#pragma unroll
  for (int u = 0; u < 8; ++u) {
    int flat = t + 256 * u;
    int row = flat >> 5, c4 = (flat & 31) << 2;
    float4 v = *(float4*)&Sf[row * 132 + c4];
    float4 bv = *(const float4*)&bias[c4];
    float* ptr = out + ((size_t)(r * L_ + l0 + row)) * 128 + c4;
    float4 o = *(float4*)ptr;
    o.x += 0.5f * (v.x + bv.x); o.y += 0.5f * (v.y + bv.y);
    o.z += 0.5f * (v.z + bv.z); o.w += 0.5f * (v.w + bv.w);
    *(float4*)ptr = o;
  }
}

// ---------------------------------------------------------------------------
// tie softmax (bf16 inputs)
// ---------------------------------------------------------------------------
__global__ __launch_bounds__(128) void tie_kernel(const __bf16* __restrict__ qs,
                                                  const __bf16* __restrict__ ks,
                                                  float* __restrict__ wtie) {
  int bid = blockIdx.x;
  int l = bid >> 3, h = bid & 7;
  int r = threadIdx.x;
  int wid = r >> 6;
  const __bf16* qp = qs + (size_t)l * 128 + h * 16;
  const __bf16* kp = ks + ((size_t)r * L_ + l) * 128 + h * 16;
  bf16x8 q0 = *(const bf16x8*)qp;
  bf16x8 q1 = *(const bf16x8*)(qp + 8);
  bf16x8 k0 = *(const bf16x8*)kp;
  bf16x8 k1 = *(const bf16x8*)(kp + 8);
  float s = 0.f;
#pragma unroll
  for (int i = 0; i < 8; ++i)
    s += (float)q0[i] * (float)k0[i] + (float)q1[i] * (float)k1[i];
  s *= 0.25f;
  __shared__ float sm[2], ss[2];
  float wm = wred_max(s);
  if ((r & 63) == 0) sm[wid] = wm;
  __syncthreads();
  float mx = fmaxf(sm[0], sm[1]);
  float e = __expf(s - mx);
  float wsum = wred_sum(e);
  if ((r & 63) == 0) ss[wid] = wsum;
  __syncthreads();
  float tot = ss[0] + ss[1];
  wtie[((size_t)l * H_ + h) * R_ + r] = e / tot;
}

// ---------------------------------------------------------------------------
// pair LN + Wpair -> pb[h][i][j]. One THREAD per (i,j); no cross-lane ops.
// ---------------------------------------------------------------------------
__global__ __launch_bounds__(256) void lnpb_kernel(const float* __restrict__ pair,
                                                   const float* __restrict__ g,
                                                   const float* __restrict__ b,
                                                   const float* __restrict__ wp,
                                                   float* __restrict__ pb) {
  __shared__ float gws[1024];
  __shared__ float c1s[8], c2s[8];
  int t = threadIdx.x;
#pragma unroll
  for (int u = 0; u < 4; ++u) {
    int idx = t * 4 + u;
    int d = idx >> 3, h = idx & 7;
    gws[idx] = g[d] * wp[d * 8 + h];
  }
  __syncthreads();
  if (t < 8) {
    float s1 = 0.f, s2 = 0.f;
    for (int d = 0; d < 128; ++d) {
      s1 += gws[d * 8 + t];
      s2 += b[d] * wp[d * 8 + t];
    }
    c1s[t] = s1;
    c2s[t] = s2;
  }
  __syncthreads();
  int pid = blockIdx.x * 256 + t;
  const float4* xp = (const float4*)(pair + (size_t)pid * 128);
  float sum = 0.f, sumsq = 0.f;
  float dots[8] = {};
#pragma unroll 8
  for (int i = 0; i < 32; ++i) {
    float4 v = xp[i];
#pragma unroll
    for (int j = 0; j < 4; ++j) {
      float e = (&v.x)[j];
      sum += e;
      sumsq = fmaf(e, e, sumsq);
      const float* gr = &gws[(i * 4 + j) * 8];
#pragma unroll
      for (int hh = 0; hh < 8; ++hh) dots[hh] = fmaf(e, gr[hh], dots[hh]);
    }
  }
  float mu = sum * (1.0f / 128.0f);
  float var = sumsq * (1.0f / 128.0f) - mu * mu;
  float rs = 1.0f / sqrtf(var + 1e-5f);
#pragma unroll
  for (int hh = 0; hh < 8; ++hh)
    pb[(size_t)hh * (L_ * L_) + pid] = rs * (dots[hh] - mu * c1s[hh]) + c2s[hh];
}

// ---------------------------------------------------------------------------
// softmax over last dim of (pb + sum of S split-K partials) -> attn bf16
// ---------------------------------------------------------------------------
__global__ __launch_bounds__(128) void sm_kernel(const float* __restrict__ pb,
                                                 const float* __restrict__ dp,
                                                 int S, __bf16* __restrict__ ab) {
  size_t row = blockIdx.x;
  int t = threadIdx.x;
  int wid = t >> 6;
  const float* p0 = pb + row * L_;
  float x0 = p0[t], x1 = p0[t + 128], x2 = p0[t + 256];
  const size_t HLL = (size_t)H_ * L_ * L_;
  for (int s = 0; s < S; ++s) {
    const float* ps = dp + s * HLL + row * L_;
    x0 += ps[t]; x1 += ps[t + 128]; x2 += ps[t + 256];
  }
  __shared__ float sm[2], ss[2];
  float m = wred_max(fmaxf(x0, fmaxf(x1, x2)));
  if ((t & 63) == 0) sm[wid] = m;
  __syncthreads();
  m = fmaxf(sm[0], sm[1]);
  float e0 = __expf(x0 - m), e1 = __expf(x1 - m), e2 = __expf(x2 - m);
  float s2 = wred_sum(e0 + e1 + e2);
  if ((t & 63) == 0) ss[wid] = s2;
  __syncthreads();
  float inv = 1.0f / (ss[0] + ss[1]);
  __bf16* op = ab + row * L_;
  op[t] = (__bf16)(e0 * inv);
  op[t + 128] = (__bf16)(e1 * inv);
  op[t + 256] = (__bf16)(e2 * inv);
}

// ---------------------------------------------------------------------------
// FUSED column attention (round-7 proven, 67us): per block (l, h), LDS 52224 B
// -> 3 blocks/CU. Proj Xs + per-group Wg, attn with v-in-regs, Ps/Vt overlay.
// ---------------------------------------------------------------------------
__global__ __launch_bounds__(256, 3) void fattw_kernel(const __bf16* __restrict__ m_bf,
                                                       const __bf16* __restrict__ WTw,
                                                       __bf16* __restrict__ ob, int c0) {
  __shared__ __bf16 smem[26112];  // 52224 B
  __bf16* Xs = smem;           // [128][136] proj (17408)
  __bf16* Wg = smem + 17408;   // [64][136]  proj per-group (8704)
  __bf16* Qs = smem;           // [128][72]  attn (9216)
  __bf16* Ks = smem + 9216;    // [128][72]  attn (ends 18432)
  __bf16* Ps = smem;           // [128][136] over Qs+Ks (0..17408)
  __bf16* Vt = smem + 17408;   // [64][136]  over Wg (17408..26112)
  __bf16* Ot = smem;           // [128][72]  after PV

  int bid = blockIdx.x;
  int v = (bid & 7) * (gridDim.x >> 3) + (bid >> 3);
  int lrel = v >> 3, h = v & 7;
  int l = c0 + lrel;
  int t = threadIdx.x;
  const int lane = t & 63, w = t >> 6;
  const int lc = lane & 15, q8 = (lane >> 4) << 3;
  const int lr4 = (lane >> 4) << 2;

#pragma unroll
  for (int u = 0; u < 8; ++u) {
    int flat = t + 256 * u;
    int row = flat >> 4, c8 = (flat & 15) << 3;
    *(uint4*)&Xs[row * 136 + c8] =
        *(const uint4*)&m_bf[((size_t)(row * L_ + l)) * 128 + c8];
  }

  f32x4 accp[2][12];
#pragma unroll
  for (int i = 0; i < 2; ++i)
#pragma unroll
    for (int j = 0; j < 12; ++j) accp[i][j] = (f32x4){0.f, 0.f, 0.f, 0.f};

#pragma unroll
  for (int g = 0; g < 3; ++g) {
#pragma unroll
    for (int u = 0; u < 4; ++u) {
      int flat = t + 256 * u;
      int row = flat >> 4, c8 = (flat & 15) << 3;
      *(uint4*)&Wg[row * 136 + c8] =
          *(const uint4*)&WTw[((size_t)(g * 512 + h * 64 + row)) * 128 + c8];
    }
    __syncthreads();
#pragma unroll
    for (int kt = 0; kt < 4; ++kt) {
      bf16x8 a0 = *(const bf16x8*)&Xs[(w * 32 + lc) * 136 + kt * 32 + q8];
      bf16x8 a1 = *(const bf16x8*)&Xs[(w * 32 + 16 + lc) * 136 + kt * 32 + q8];
#pragma unroll
      for (int j = 0; j < 4; ++j) {
        bf16x8 b = *(const bf16x8*)&Wg[(j * 16 + lc) * 136 + kt * 32 + q8];
        accp[0][g * 4 + j] = __builtin_amdgcn_mfma_f32_16x16x32_bf16(a0, b, accp[0][g * 4 + j], 0, 0, 0);
        accp[1][g * 4 + j] = __builtin_amdgcn_mfma_f32_16x16x32_bf16(a1, b, accp[1][g * 4 + j], 0, 0, 0);
      }
    }
    __syncthreads();
  }

#pragma unroll
  for (int i = 0; i < 2; ++i)
#pragma unroll
    for (int j = 0; j < 8; ++j)
#pragma unroll
      for (int g = 0; g < 4; ++g) {
        int r_loc = w * 32 + i * 16 + lr4 + g;
        __bf16 val = (__bf16)accp[i][j][g];
        if (j < 4) Qs[r_loc * 72 + j * 16 + lc] = val;
        else Ks[r_loc * 72 + (j - 4) * 16 + lc] = val;
      }
  __syncthreads();

  f32x4 s[2][8];
#pragma unroll
  for (int i = 0; i < 2; ++i)
#pragma unroll
    for (int n = 0; n < 8; ++n) s[i][n] = (f32x4){0.f, 0.f, 0.f, 0.f};
#pragma unroll
  for (int kt = 0; kt < 2; ++kt) {
    bf16x8 a[2];
#pragma unroll
    for (int i = 0; i < 2; ++i)
      a[i] = *(const bf16x8*)&Qs[(w * 32 + i * 16 + lc) * 72 + kt * 32 + q8];
#pragma unroll
    for (int n = 0; n < 8; ++n) {
      bf16x8 b = *(const bf16x8*)&Ks[(n * 16 + lc) * 72 + kt * 32 + q8];
#pragma unroll
      for (int i = 0; i < 2; ++i)
        s[i][n] = __builtin_amdgcn_mfma_f32_16x16x32_bf16(a[i], b, s[i][n], 0, 0, 0);
    }
  }

  float linv[2][4];
#pragma unroll
  for (int i = 0; i < 2; ++i) {
#pragma unroll
    for (int g = 0; g < 4; ++g) {
      float mx = -1e30f;
#pragma unroll
      for (int n = 0; n < 8; ++n) mx = fmaxf(mx, s[i][n][g]);
      mx = fmaxf(mx, __shfl_xor(mx, 1, 64));
      mx = fmaxf(mx, __shfl_xor(mx, 2, 64));
      mx = fmaxf(mx, __shfl_xor(mx, 4, 64));
      mx = fmaxf(mx, __shfl_xor(mx, 8, 64));
      float sum = 0.f;
#pragma unroll
      for (int n = 0; n < 8; ++n) {
        float e = __expf(0.125f * (s[i][n][g] - mx));
        s[i][n][g] = e;
        sum += e;
      }
      sum += __shfl_xor(sum, 1, 64);
      sum += __shfl_xor(sum, 2, 64);
      sum += __shfl_xor(sum, 4, 64);
      sum += __shfl_xor(sum, 8, 64);
      linv[i][g] = 1.0f / sum;
    }
  }
  __syncthreads();

#pragma unroll
  for (int i = 0; i < 2; ++i)
#pragma unroll
    for (int n = 0; n < 8; ++n)
#pragma unroll
      for (int g = 0; g < 4; ++g)
        Ps[(size_t)(w * 32 + i * 16 + lr4 + g) * 136 + n * 16 + lc] = (__bf16)s[i][n][g];
#pragma unroll
  for (int i = 0; i < 2; ++i)
#pragma unroll
    for (int j = 8; j < 12; ++j) {
      bf16x4 pv;
#pragma unroll
      for (int g = 0; g < 4; ++g) pv[g] = (__bf16)accp[i][j][g];
      *(uint2*)&Vt[(size_t)((j - 8) * 16 + lc) * 136 + w * 32 + i * 16 + lr4] =
          __builtin_bit_cast(uint2, pv);
    }
  __syncthreads();

  f32x4 o[2][4];
#pragma unroll
  for (int i = 0; i < 2; ++i)
#pragma unroll
    for (int n = 0; n < 4; ++n) o[i][n] = (f32x4){0.f, 0.f, 0.f, 0.f};
#pragma unroll
  for (int kt = 0; kt < 4; ++kt) {
    bf16x8 a[2];
#pragma unroll
    for (int i = 0; i < 2; ++i)
      a[i] = *(const bf16x8*)&Ps[(w * 32 + i * 16 + lc) * 136 + kt * 32 + q8];
#pragma unroll
    for (int n = 0; n < 4; ++n) {
      bf16x8 b = *(const bf16x8*)&Vt[(n * 16 + lc) * 136 + kt * 32 + q8];
#pragma unroll
      for (int i = 0; i < 2; ++i)
        o[i][n] = __builtin_amdgcn_mfma_f32_16x16x32_bf16(a[i], b, o[i][n], 0, 0, 0);
    }
  }

  __syncthreads();
#pragma unroll
  for (int i = 0; i < 2; ++i)
#pragma unroll
    for (int n = 0; n < 4; ++n)
#pragma unroll
      for (int g = 0; g < 4; ++g) {
        int r = w * 32 + i * 16 + lr4 + g;
        int dh = n * 16 + lc;
        Ot[r * 72 + dh] = (__bf16)(o[i][n][g] * linv[i][g]);
      }
  __syncthreads();
#pragma unroll
  for (int u = 0; u < 4; ++u) {
    int flat = t + 256 * u;
    int r = flat >> 3, c8 = (flat & 7) << 3;
    uint4 val = *(uint4*)&Ot[r * 72 + c8];
    *(uint4*)&ob[((size_t)(lrel * R_ + r)) * INNER_ + h * 64 + c8] = val;
  }
}

// ---------------------------------------------------------------------------
extern "C" void kernel_launch(void* const* d_in, const int* in_sizes, int n_in,
                              void* d_out, int out_size, void* d_ws,
                              size_t ws_size, hipStream_t stream) {
  (void)in_sizes; (void)n_in; (void)out_size;
  const float* m = (const float*)d_in[0];
  const float* pair = (const float*)d_in[1];
  const float* Wq_w = (const float*)d_in[2];
  const float* Wkv_w = (const float*)d_in[3];
  const float* Wo_w = (const float*)d_in[4];
  const float* bo_w = (const float*)d_in[5];
  const float* Wq_h = (const float*)d_in[6];
  const float* Wkv_h = (const float*)d_in[7];
  const float* Wo_h = (const float*)d_in[8];
  const float* bo_h = (const float*)d_in[9];
  const float* ln_g = (const float*)d_in[10];
  const float* ln_b = (const float*)d_in[11];
  const float* Wpair = (const float*)d_in[12];
  const float* Wsq = (const float*)d_in[13];
  const float* bsq = (const float*)d_in[14];
  const float* Wsk = (const float*)d_in[15];
  const float* bsk = (const float*)d_in[16];
  float* out = (float*)d_out;

  // ---- choose chunking (CH) and split count (S = 8/CH) to fit workspace ----
  const size_t fixedBase = 22708224u;
  int CH = 1;
  for (; CH < 8; CH *= 2) {
    size_t partials = (size_t)(8 / CH) * 4718592u;
    size_t o = 201326592u / CH;
    if (o < 25165824u) o = 25165824u;
    if (fixedBase + partials + o <= ws_size) break;
  }
  const int S = 8 / CH;
  const int Lc = L_ / CH;
  const int Rc = R_ / CH;

  unsigned char* base = (unsigned char*)d_ws;
  __bf16* m_bf = (__bf16*)base;       base += 12582912;
  __bf16* WTw = (__bf16*)base;        base += 393216;
  __bf16* WThqk = (__bf16*)base;      base += 262144;
  __bf16* WTvh = (__bf16*)base;       base += 131072;
  __bf16* WoTw = (__bf16*)base;       base += 131072;
  __bf16* WoTh = (__bf16*)base;       base += 131072;
  __bf16* WskT = (__bf16*)base;       base += 32768;
  __bf16* WsqT = (__bf16*)base;       base += 32768;
  float* wtie = (float*)base;         base += 1572864;
  float* pb = (float*)base;           base += 4718592;
  __bf16* attnb = (__bf16*)base;      base += 2359296;
  __bf16* qsb = (__bf16*)base;        base += 98304;
  __bf16* wft = (__bf16*)base;        base += 262144;
  float* dotsP = (float*)base;        base += (size_t)S * 4718592u;
  unsigned char* ovl = base;
  __bf16* ksb = (__bf16*)ovl;  // phase A only

  const size_t BUF = 25165824u / CH;
  __bf16* qb = (__bf16*)ovl;
  __bf16* kb = qb + BUF;
  __bf16* vbslot = kb + BUF;   // vb slot now hosts mT (v-transpose path deleted)
  __bf16* ob = vbslot + BUF;
  __bf16* mT = vbslot;         // 12.58 MB, fits BUF for CH<=2

  prep_kernel<<<1672, 256, 0, stream>>>(m, m_bf, Wq_w, Wkv_w, Wq_h, Wkv_h, Wo_w,
                                        Wo_h, Wsk, Wsq, WTw, WThqk, WTvh, WoTw,
                                        WoTh, WskT, WsqT, mT);

  // tie projections + softmax + pair bias + fused Wv@Wo weights
  mm_k<8><<<dim3(1, 387), 256, 0, stream>>>(m_bf, WskT, bsk, bsq, ksb, qsb, WsqT,
                                            nullptr, 128, 0, Rc, 0, 0, 1);
  wf_kernel<<<8, 256, 0, stream>>>(Wkv_h, WoTh, wft);
  tie_kernel<<<L_ * H_, 128, 0, stream>>>(qsb, ksb, wtie);
  lnpb_kernel<<<(L_ * L_) / 256, 256, 0, stream>>>(pair, ln_g, ln_b, Wpair, pb);

  for (int c = 0; c < CH; ++c) {
    int l0 = c * Lc;
    fattw_kernel<<<Lc * H_, 256, 0, stream>>>(m_bf, WTw, ob, l0);
    mm_k<4><<<dim3(1, Lc), 256, 0, stream>>>(ob, WoTw, bo_w, nullptr, nullptr, nullptr,
                                             nullptr, out, 512, l0, Rc, 0, 0, 1);
  }

  for (int c = 0; c < CH; ++c) {
    int r0 = c * Rc;
    mm_k<1><<<dim3(8, Rc * 3), 256, 0, stream>>>(m_bf, WThqk, nullptr, wtie, qb, kb,
                                                 nullptr, nullptr, 128, r0, Rc, 0, 0, 1);
    mm_k<2><<<9 * H_ * S, 256, 0, stream>>>(qb, kb, nullptr, nullptr, nullptr,
                                            nullptr, nullptr, dotsP,
                                            (Rc * 64) / S, r0, Rc, Rc * 64,
                                            (c == 0) ? 1 : 0, S);
  }
  sm_kernel<<<H_ * L_, 128, 0, stream>>>(pb, dotsP, S, attnb);

  // fused OH + OUT_H (replaces mm_k<6>, mm_k<3>, mm_k<5>)
  foh_kernel<<<R_ * 6, 256, 0, stream>>>(attnb, mT, wft, bo_h, out);
}

// Round 10
// 460.837 us; speedup vs baseline: 1.0433x; 1.0433x over previous
//
#include <hip/hip_runtime.h>
#include <math.h>

#define L_ 384
#define R_ 128
#define D_ 128
#define H_ 8
#define DH_ 64
#define INNER_ 512

typedef __bf16 bf16x8 __attribute__((ext_vector_type(8)));
typedef __bf16 bf16x4 __attribute__((ext_vector_type(4)));
typedef float f32x4 __attribute__((ext_vector_type(4)));

__device__ __forceinline__ float wred_sum(float v) {
#pragma unroll
  for (int o = 32; o > 0; o >>= 1) v += __shfl_xor(v, o, 64);
  return v;
}
__device__ __forceinline__ float wred_max(float v) {
#pragma unroll
  for (int o = 32; o > 0; o >>= 1) v = fmaxf(v, __shfl_xor(v, o, 64));
  return v;
}

// ---------------------------------------------------------------------------
// prep: m fp32->bf16 (blocks 0..3071) + all weight transposes (blocks 3072..3207)
// ---------------------------------------------------------------------------
__global__ __launch_bounds__(256) void prep_kernel(
    const float* __restrict__ m, __bf16* __restrict__ m_bf,
    const float* __restrict__ Wq_w, const float* __restrict__ Wkv_w,
    const float* __restrict__ Wq_h, const float* __restrict__ Wkv_h,
    const float* __restrict__ Wo_w, const float* __restrict__ Wo_h,
    const float* __restrict__ Wsk, const float* __restrict__ Wsq,
    __bf16* __restrict__ WTw, __bf16* __restrict__ WThqk,
    __bf16* __restrict__ WTvh, __bf16* __restrict__ WoTw,
    __bf16* __restrict__ WoTh, __bf16* __restrict__ WskT,
    __bf16* __restrict__ WsqT) {
  __shared__ float Ls[64 * 65];
  int b = blockIdx.x;
  int t = threadIdx.x;
  if (b < 3072) {
    int i = b * 256 + t;
    float4 a = *(const float4*)(m + (size_t)i * 8);
    float4 c = *(const float4*)(m + (size_t)i * 8 + 4);
    bf16x8 o;
    o[0] = (__bf16)a.x; o[1] = (__bf16)a.y; o[2] = (__bf16)a.z; o[3] = (__bf16)a.w;
    o[4] = (__bf16)c.x; o[5] = (__bf16)c.y; o[6] = (__bf16)c.z; o[7] = (__bf16)c.w;
    *(uint4*)(m_bf + (size_t)i * 8) = __builtin_bit_cast(uint4, o);
    return;
  }
  int j = b - 3072;
  const float* src; __bf16* dst; int Kd, Ns, noff, gx, base;
  if (j < 16)       { src = Wq_w;  dst = WTw;             Kd = 128; Ns = 512;  noff = 0;   gx = 8;  base = 0; }
  else if (j < 48)  { src = Wkv_w; dst = WTw + 512 * 128; Kd = 128; Ns = 1024; noff = 0;   gx = 16; base = 16; }
  else if (j < 64)  { src = Wq_h;  dst = WThqk;           Kd = 128; Ns = 512;  noff = 0;   gx = 8;  base = 48; }
  else if (j < 80)  { src = Wkv_h; dst = WThqk + 512 * 128; Kd = 128; Ns = 1024; noff = 0; gx = 8;  base = 64; }
  else if (j < 96)  { src = Wkv_h; dst = WTvh;            Kd = 128; Ns = 1024; noff = 512; gx = 8;  base = 80; }
  else if (j < 112) { src = Wo_w;  dst = WoTw;            Kd = 512; Ns = 128;  noff = 0;   gx = 2;  base = 96; }
  else if (j < 128) { src = Wo_h;  dst = WoTh;            Kd = 512; Ns = 128;  noff = 0;   gx = 2;  base = 112; }
  else if (j < 132) { src = Wsk;   dst = WskT;            Kd = 128; Ns = 128;  noff = 0;   gx = 2;  base = 128; }
  else              { src = Wsq;   dst = WsqT;            Kd = 128; Ns = 128;  noff = 0;   gx = 2;  base = 132; }
  int jl = j - base;
  int n0 = (jl % gx) * 64, k0 = (jl / gx) * 64;
#pragma unroll
  for (int u = 0; u < 4; ++u) {
    int flat = t + 256 * u;
    int kr = flat >> 4, nc = (flat & 15) * 4;
    float4 v = *(const float4*)&src[(size_t)(k0 + kr) * Ns + noff + n0 + nc];
    Ls[kr * 65 + nc + 0] = v.x;
    Ls[kr * 65 + nc + 1] = v.y;
    Ls[kr * 65 + nc + 2] = v.z;
    Ls[kr * 65 + nc + 3] = v.w;
  }
  __syncthreads();
#pragma unroll
  for (int u = 0; u < 2; ++u) {
    int flat = t + 256 * u;
    int nr = flat >> 3, kc = (flat & 7) * 8;
    bf16x8 o;
#pragma unroll
    for (int q = 0; q < 8; ++q) o[q] = (__bf16)Ls[(kc + q) * 65 + nr];
    *(uint4*)&dst[(size_t)(n0 + nr) * Kd + k0 + kc] = __builtin_bit_cast(uint4, o);
  }
}

// ---------------------------------------------------------------------------
// bf16 MFMA GEMM, 128x128 tile, BK=64, 256 threads (4 waves 2x2), 16x16x32 mfma.
// Epilogue: LDS-staged, fully vectorized (uint4 bf16 / float4 fp32) stores.
// MODE 1: PROJ_H   A=m_bf, B=WThqk, C->qh (tie-scaled) / kh
// MODE 2: DOTS     pure NT GEMM, 1D XCD-swizzled grid, split-K partials fp32
// MODE 3: OH       A=attnb[h][L][L], B=vt[h][n][L], C->ob bf16
// MODE 4: OUT_W    C = 0.5*(acc+bias) -> out fp32
// MODE 5: OUT_H    C += 0.5*(acc+bias) -> out fp32
// MODE 6: PROJ_VT  A=WTvh, B=m_bf rows, C->vt bf16 (transposed v)
// MODE 8: TIE PROJ ks (m0<49152) / qs (m0>=49152, B=O2=WsqT, bias=tie=bsq)
// ---------------------------------------------------------------------------
template <int MODE>
__global__ __launch_bounds__(256) void mm_k(
    const __bf16* __restrict__ A, const __bf16* __restrict__ B,
    const float* __restrict__ bias, const float* __restrict__ tie,
    __bf16* __restrict__ O0, __bf16* __restrict__ O1, __bf16* __restrict__ O2,
    float* __restrict__ F0,
    int K, int c0, int Rc, int KT, int firstChunk, int S) {
  __shared__ __bf16 shm[2 * 128 * 72];
  __bf16* As = shm;
  __bf16* Bs = shm + 128 * 72;
  const int t = threadIdx.x;
  const int lane = t & 63, w = t >> 6;
  const int wm = w >> 1, wn = w & 1;
  int n0, m0, h = 0, s = 0, kOff = 0;
  const int bz = blockIdx.z;
  if (MODE == 2) {
    int b = blockIdx.x;
    int xcd = b & 7, t2 = b >> 3;
    int i3 = t2 % 3, slot = t2 / 3;
    int g = xcd * (gridDim.x / 24) + slot;
    n0 = i3 * 128;
    m0 = (g % 3) * 128;
    int z = g / 3;
    h = z / S; s = z % S; kOff = s * K;
  } else if (MODE == 1) {
    // XCD-chunked remap: all n-tiles of an m-tile on one XCD's L2.
    const int gx = 8;
    int nb = gx * gridDim.y;
    int bid = blockIdx.y * gx + blockIdx.x;
    int vv = (bid & 7) * (nb >> 3) + (bid >> 3);
    n0 = (vv % gx) * 128;
    m0 = (vv / gx) * 128;
  } else {
    n0 = blockIdx.x * 128;
    m0 = blockIdx.y * 128;
    if (MODE == 3) h = bz;
  }
  const int pbase = (MODE == 8 && m0 >= 49152) ? 49152 : 0;
  const __bf16* Bmat = (MODE == 8 && pbase) ? (const __bf16*)O2 : B;

  f32x4 acc[4][4];
#pragma unroll
  for (int i = 0; i < 4; ++i)
#pragma unroll
    for (int j = 0; j < 4; ++j) acc[i][j] = (f32x4){0.f, 0.f, 0.f, 0.f};

  for (int k0 = 0; k0 < K; k0 += 64) {
#pragma unroll
    for (int u = 0; u < 4; ++u) {
      int flat = t + 256 * u;
      int row = flat >> 3;
      int c8 = (flat & 7) << 3;
      const __bf16* ap;
      int p = m0 + row;
      if (MODE == 1) ap = A + ((size_t)(c0 * L_ + p)) * 128 + k0 + c8;
      else if (MODE == 2) ap = A + ((size_t)(h * L_ + p)) * KT + kOff + k0 + c8;
      else if (MODE == 3) ap = A + ((size_t)(h * L_ + p)) * L_ + k0 + c8;
      else if (MODE == 4) ap = A + (size_t)p * INNER_ + k0 + c8;
      else if (MODE == 5) { int rrel = p / L_, l = p - rrel * L_;
        ap = A + (((size_t)((k0 >> 6) * L_ + l)) * Rc + rrel) * 64 + c8; }
      else if (MODE == 8) ap = A + (size_t)(p - pbase) * 128 + k0 + c8;
      else ap = A + (size_t)p * 128 + k0 + c8;
      *(uint4*)&As[row * 72 + c8] = *(const uint4*)ap;
      const __bf16* bp;
      int n = n0 + row;
      if (MODE == 1 || MODE == 8) bp = Bmat + (size_t)n * 128 + k0 + c8;
      else if (MODE == 2) bp = B + ((size_t)(h * L_ + n)) * KT + kOff + k0 + c8;
      else if (MODE == 3) bp = B + ((size_t)(h * Rc * 64 + n)) * L_ + k0 + c8;
      else if (MODE == 4 || MODE == 5) bp = B + (size_t)n * INNER_ + k0 + c8;
      else bp = B + ((size_t)((c0 + bz) * L_ + n)) * 128 + k0 + c8;
      *(uint4*)&Bs[row * 72 + c8] = *(const uint4*)bp;
    }
    __syncthreads();
    {
      int lc = lane & 15, q8 = (lane >> 4) << 3;
#pragma unroll
      for (int kt = 0; kt < 2; ++kt) {
        bf16x8 af[4], bfr[4];
#pragma unroll
        for (int i = 0; i < 4; ++i) {
          af[i] = *(const bf16x8*)&As[(wm * 64 + i * 16 + lc) * 72 + kt * 32 + q8];
          bfr[i] = *(const bf16x8*)&Bs[(wn * 64 + i * 16 + lc) * 72 + kt * 32 + q8];
        }
#pragma unroll
        for (int i = 0; i < 4; ++i)
#pragma unroll
          for (int j = 0; j < 4; ++j)
            acc[i][j] = __builtin_amdgcn_mfma_f32_16x16x32_bf16(af[i], bfr[j], acc[i][j], 0, 0, 0);
      }
    }
    __syncthreads();
  }

  const int lce = lane & 15, lr4 = (lane >> 4) << 2;

  // MODE 1 (qh blocks): stage the 256 tie weights into LDS, pull into regs.
  float tw[4][4];
  if (MODE == 1 && n0 < 512) {
    float* tieS = (float*)shm;  // safe: all LDS reads done (barrier above)
    int row = t >> 1, hh2 = t & 1;
    int pmt = m0 + row;
    int rrelt = pmt / L_, lt = pmt - rrelt * L_;
    int h0 = n0 >> 6;
    tieS[row * 2 + hh2] = tie[((size_t)(lt * H_ + h0 + hh2)) * R_ + c0 + rrelt];
    __syncthreads();
#pragma unroll
    for (int i = 0; i < 4; ++i)
#pragma unroll
      for (int g = 0; g < 4; ++g)
        tw[i][g] = tieS[(wm * 64 + i * 16 + lr4 + g) * 2 + wn];
    __syncthreads();
  }

  if (MODE == 1 || MODE == 3 || MODE == 6 || MODE == 8) {
    // ---- bf16 epilogue: stage full 128x128 tile, store uint4 (8 bf16) ----
    __bf16* St = shm;  // pitch 136 bf16 (272 B, 16B-aligned rows), 34816 B
    const float* bb8 = (MODE == 8) ? (pbase ? tie : bias) : nullptr;
#pragma unroll
    for (int i = 0; i < 4; ++i)
#pragma unroll
      for (int j = 0; j < 4; ++j)
#pragma unroll
        for (int g = 0; g < 4; ++g) {
          float v = acc[i][j][g];
          if (MODE == 1 && n0 < 512) v *= tw[i][g];
          if (MODE == 8) v += bb8[n0 + wn * 64 + j * 16 + lce];
          St[(wm * 64 + i * 16 + lr4 + g) * 136 + wn * 64 + j * 16 + lce] = (__bf16)v;
        }
    __syncthreads();
#pragma unroll
    for (int u = 0; u < 8; ++u) {
      int flat = t + 256 * u;
      int row = flat >> 4, c8 = (flat & 15) << 3;
      uint4 val = *(uint4*)&St[row * 136 + c8];
      int pm = m0 + row, pn = n0 + c8;
      if (MODE == 1) {
        int nn = pn;
        int rrel = pm / L_, l = pm - rrel * L_;
        if (nn < 512) {
          int hh = nn >> 6, dh = nn & 63;
          *(uint4*)&O0[(((size_t)(hh * L_ + l)) * Rc + rrel) * 64 + dh] = val;
        } else {
          nn -= 512;
          int hh = nn >> 6, dh = nn & 63;
          *(uint4*)&O1[(((size_t)(hh * L_ + l)) * Rc + rrel) * 64 + dh] = val;
        }
      } else if (MODE == 3) {
        *(uint4*)&O0[((size_t)(h * L_ + pm)) * ((size_t)Rc * 64) + pn] = val;
      } else if (MODE == 6) {
        *(uint4*)&O0[(((size_t)((pm >> 6) * Rc + bz)) * 64 + (pm & 63)) * (size_t)L_ + pn] = val;
      } else {  // MODE 8
        __bf16* dst = pbase ? O1 : O0;
        *(uint4*)&dst[(size_t)(pm - pbase) * 128 + pn] = val;
      }
    }
  } else {
    // ---- fp32 epilogue (modes 2/4/5): 2 half-tiles of 64 rows, float4 ----
    float* Sf = (float*)shm;  // 64 rows, pitch 132 fp32 (528 B), 33792 B
#pragma unroll
    for (int half = 0; half < 2; ++half) {
      if (half) __syncthreads();
      if (wm == half) {
#pragma unroll
        for (int i = 0; i < 4; ++i)
#pragma unroll
          for (int j = 0; j < 4; ++j)
#pragma unroll
            for (int g = 0; g < 4; ++g)
              Sf[(i * 16 + lr4 + g) * 132 + wn * 64 + j * 16 + lce] = acc[i][j][g];
      }
      __syncthreads();
#pragma unroll
      for (int u = 0; u < 8; ++u) {
        int flat = t + 256 * u;
        int row = flat >> 5, c4 = (flat & 31) << 2;
        float4 v = *(float4*)&Sf[row * 132 + c4];
        int pm = m0 + half * 64 + row, pn = n0 + c4;
        if (MODE == 2) {
          float* ptr = F0 + ((size_t)(s * H_ + h)) * (L_ * L_) + (size_t)pm * L_ + pn;
          v.x *= 0.125f; v.y *= 0.125f; v.z *= 0.125f; v.w *= 0.125f;
          if (firstChunk) {
            *(float4*)ptr = v;
          } else {
            float4 o = *(float4*)ptr;
            o.x += v.x; o.y += v.y; o.z += v.z; o.w += v.w;
            *(float4*)ptr = o;
          }
        } else if (MODE == 4) {
          float4 bv = *(const float4*)&bias[pn];
          int lrel = pm >> 7, rr = pm & 127;
          float4 o;
          o.x = 0.5f * (v.x + bv.x); o.y = 0.5f * (v.y + bv.y);
          o.z = 0.5f * (v.z + bv.z); o.w = 0.5f * (v.w + bv.w);
          *(float4*)&F0[((size_t)(rr * L_ + c0 + lrel)) * 128 + pn] = o;
        } else {  // MODE 5: RMW accumulate into out
          float4 bv = *(const float4*)&bias[pn];
          int rrel = pm / L_, l = pm - rrel * L_;
          float* ptr = F0 + ((size_t)((c0 + rrel) * L_ + l)) * 128 + pn;
          float4 o = *(float4*)ptr;
          o.x += 0.5f * (v.x + bv.x); o.y += 0.5f * (v.y + bv.y);
          o.z += 0.5f * (v.z + bv.z); o.w += 0.5f * (v.w + bv.w);
          *(float4*)ptr = o;
        }
      }
    }
  }
}

// ---------------------------------------------------------------------------
// tie softmax (bf16 inputs)
// ---------------------------------------------------------------------------
__global__ __launch_bounds__(128) void tie_kernel(const __bf16* __restrict__ qs,
                                                  const __bf16* __restrict__ ks,
                                                  float* __restrict__ wtie) {
  int bid = blockIdx.x;
  int l = bid >> 3, h = bid & 7;
  int r = threadIdx.x;
  int wid = r >> 6;
  const __bf16* qp = qs + (size_t)l * 128 + h * 16;
  const __bf16* kp = ks + ((size_t)r * L_ + l) * 128 + h * 16;
  bf16x8 q0 = *(const bf16x8*)qp;
  bf16x8 q1 = *(const bf16x8*)(qp + 8);
  bf16x8 k0 = *(const bf16x8*)kp;
  bf16x8 k1 = *(const bf16x8*)(kp + 8);
  float s = 0.f;
#pragma unroll
  for (int i = 0; i < 8; ++i)
    s += (float)q0[i] * (float)k0[i] + (float)q1[i] * (float)k1[i];
  s *= 0.25f;
  __shared__ float sm[2], ss[2];
  float wm = wred_max(s);
  if ((r & 63) == 0) sm[wid] = wm;
  __syncthreads();
  float mx = fmaxf(sm[0], sm[1]);
  float e = __expf(s - mx);
  float wsum = wred_sum(e);
  if ((r & 63) == 0) ss[wid] = wsum;
  __syncthreads();
  float tot = ss[0] + ss[1];
  wtie[((size_t)l * H_ + h) * R_ + r] = e / tot;
}

// ---------------------------------------------------------------------------
// pair LN + Wpair -> pb[h][i][j]. One THREAD per (i,j); no cross-lane ops.
// ---------------------------------------------------------------------------
__global__ __launch_bounds__(256) void lnpb_kernel(const float* __restrict__ pair,
                                                   const float* __restrict__ g,
                                                   const float* __restrict__ b,
                                                   const float* __restrict__ wp,
                                                   float* __restrict__ pb) {
  __shared__ float gws[1024];
  __shared__ float c1s[8], c2s[8];
  int t = threadIdx.x;
#pragma unroll
  for (int u = 0; u < 4; ++u) {
    int idx = t * 4 + u;
    int d = idx >> 3, h = idx & 7;
    gws[idx] = g[d] * wp[d * 8 + h];
  }
  __syncthreads();
  if (t < 8) {
    float s1 = 0.f, s2 = 0.f;
    for (int d = 0; d < 128; ++d) {
      s1 += gws[d * 8 + t];
      s2 += b[d] * wp[d * 8 + t];
    }
    c1s[t] = s1;
    c2s[t] = s2;
  }
  __syncthreads();
  int pid = blockIdx.x * 256 + t;
  const float4* xp = (const float4*)(pair + (size_t)pid * 128);
  float sum = 0.f, sumsq = 0.f;
  float dots[8] = {};
#pragma unroll 8
  for (int i = 0; i < 32; ++i) {
    float4 v = xp[i];
#pragma unroll
    for (int j = 0; j < 4; ++j) {
      float e = (&v.x)[j];
      sum += e;
      sumsq = fmaf(e, e, sumsq);
      const float* gr = &gws[(i * 4 + j) * 8];
#pragma unroll
      for (int hh = 0; hh < 8; ++hh) dots[hh] = fmaf(e, gr[hh], dots[hh]);
    }
  }
  float mu = sum * (1.0f / 128.0f);
  float var = sumsq * (1.0f / 128.0f) - mu * mu;
  float rs = 1.0f / sqrtf(var + 1e-5f);
#pragma unroll
  for (int hh = 0; hh < 8; ++hh)
    pb[(size_t)hh * (L_ * L_) + pid] = rs * (dots[hh] - mu * c1s[hh]) + c2s[hh];
}

// ---------------------------------------------------------------------------
// softmax over last dim of (pb + sum of S split-K partials) -> attn bf16
// ---------------------------------------------------------------------------
__global__ __launch_bounds__(128) void sm_kernel(const float* __restrict__ pb,
                                                 const float* __restrict__ dp,
                                                 int S, __bf16* __restrict__ ab) {
  size_t row = blockIdx.x;
  int t = threadIdx.x;
  int wid = t >> 6;
  const float* p0 = pb + row * L_;
  float x0 = p0[t], x1 = p0[t + 128], x2 = p0[t + 256];
  const size_t HLL = (size_t)H_ * L_ * L_;
  for (int s = 0; s < S; ++s) {
    const float* ps = dp + s * HLL + row * L_;
    x0 += ps[t]; x1 += ps[t + 128]; x2 += ps[t + 256];
  }
  __shared__ float sm[2], ss[2];
  float m = wred_max(fmaxf(x0, fmaxf(x1, x2)));
  if ((t & 63) == 0) sm[wid] = m;
  __syncthreads();
  m = fmaxf(sm[0], sm[1]);
  float e0 = __expf(x0 - m), e1 = __expf(x1 - m), e2 = __expf(x2 - m);
  float s2 = wred_sum(e0 + e1 + e2);
  if ((t & 63) == 0) ss[wid] = s2;
  __syncthreads();
  float inv = 1.0f / (ss[0] + ss[1]);
  __bf16* op = ab + row * L_;
  op[t] = (__bf16)(e0 * inv);
  op[t + 128] = (__bf16)(e1 * inv);
  op[t + 256] = (__bf16)(e2 * inv);
}

// ---------------------------------------------------------------------------
// FUSED column attention, round-7: per block (l, h). LDS peak 52224 B
// (<= 26*2048 so 3 blocks/CU survive granule-2048 rounding).
// Proj: Xs[128][136] staged (coalesced) + W staged per qkv GROUP [64][136];
// 3 stage/mfma cycles. Attn: q/k scattered to LDS; v HELD IN REGISTERS
// through QK^T+softmax, then Ps[128][136] overlays Qs+Ks and Vt[64][136]
// overlays the dead Wg region (b64-packed writes). PV -> Ot -> ob.
// XCD-chunked bid remap: 8 head-blocks of one l land on one XCD's L2.
// ---------------------------------------------------------------------------
__global__ __launch_bounds__(256, 3) void fattw_kernel(const __bf16* __restrict__ m_bf,
                                                       const __bf16* __restrict__ WTw,
                                                       __bf16* __restrict__ ob, int c0) {
  __shared__ __bf16 smem[26112];  // 52224 B
  __bf16* Xs = smem;           // [128][136] proj (17408)
  __bf16* Wg = smem + 17408;   // [64][136]  proj per-group (8704)
  __bf16* Qs = smem;           // [128][72]  attn (9216)
  __bf16* Ks = smem + 9216;    // [128][72]  attn (ends 18432)
  __bf16* Ps = smem;           // [128][136] over Qs+Ks (0..17408)
  __bf16* Vt = smem + 17408;   // [64][136]  over Wg (17408..26112)
  __bf16* Ot = smem;           // [128][72]  after PV

  int bid = blockIdx.x;
  int v = (bid & 7) * (gridDim.x >> 3) + (bid >> 3);
  int lrel = v >> 3, h = v & 7;
  int l = c0 + lrel;
  int t = threadIdx.x;
  const int lane = t & 63, w = t >> 6;
  const int lc = lane & 15, q8 = (lane >> 4) << 3;
  const int lr4 = (lane >> 4) << 2;

  // stage x_l [128][136] (coalesced)
#pragma unroll
  for (int u = 0; u < 8; ++u) {
    int flat = t + 256 * u;
    int row = flat >> 4, c8 = (flat & 15) << 3;
    *(uint4*)&Xs[row * 136 + c8] =
        *(const uint4*)&m_bf[((size_t)(row * L_ + l)) * 128 + c8];
  }

  f32x4 accp[2][12];
#pragma unroll
  for (int i = 0; i < 2; ++i)
#pragma unroll
    for (int j = 0; j < 12; ++j) accp[i][j] = (f32x4){0.f, 0.f, 0.f, 0.f};

  // proj GEMM in 3 qkv groups: stage Wg[64][136] -> 32 MFMAs, full K=128 each
#pragma unroll
  for (int g = 0; g < 3; ++g) {
#pragma unroll
    for (int u = 0; u < 4; ++u) {
      int flat = t + 256 * u;
      int row = flat >> 4, c8 = (flat & 15) << 3;
      *(uint4*)&Wg[row * 136 + c8] =
          *(const uint4*)&WTw[((size_t)(g * 512 + h * 64 + row)) * 128 + c8];
    }
    __syncthreads();
#pragma unroll
    for (int kt = 0; kt < 4; ++kt) {
      bf16x8 a0 = *(const bf16x8*)&Xs[(w * 32 + lc) * 136 + kt * 32 + q8];
      bf16x8 a1 = *(const bf16x8*)&Xs[(w * 32 + 16 + lc) * 136 + kt * 32 + q8];
#pragma unroll
      for (int j = 0; j < 4; ++j) {
        bf16x8 b = *(const bf16x8*)&Wg[(j * 16 + lc) * 136 + kt * 32 + q8];
        accp[0][g * 4 + j] = __builtin_amdgcn_mfma_f32_16x16x32_bf16(a0, b, accp[0][g * 4 + j], 0, 0, 0);
        accp[1][g * 4 + j] = __builtin_amdgcn_mfma_f32_16x16x32_bf16(a1, b, accp[1][g * 4 + j], 0, 0, 0);
      }
    }
    __syncthreads();
  }

  // scatter q/k into attn LDS (v stays in registers)
#pragma unroll
  for (int i = 0; i < 2; ++i)
#pragma unroll
    for (int j = 0; j < 8; ++j)
#pragma unroll
      for (int g = 0; g < 4; ++g) {
        int r_loc = w * 32 + i * 16 + lr4 + g;
        __bf16 val = (__bf16)accp[i][j][g];
        if (j < 4) Qs[r_loc * 72 + j * 16 + lc] = val;
        else Ks[r_loc * 72 + (j - 4) * 16 + lc] = val;
      }
  __syncthreads();

  // QK^T
  f32x4 s[2][8];
#pragma unroll
  for (int i = 0; i < 2; ++i)
#pragma unroll
    for (int n = 0; n < 8; ++n) s[i][n] = (f32x4){0.f, 0.f, 0.f, 0.f};
#pragma unroll
  for (int kt = 0; kt < 2; ++kt) {
    bf16x8 a[2];
#pragma unroll
    for (int i = 0; i < 2; ++i)
      a[i] = *(const bf16x8*)&Qs[(w * 32 + i * 16 + lc) * 72 + kt * 32 + q8];
#pragma unroll
    for (int n = 0; n < 8; ++n) {
      bf16x8 b = *(const bf16x8*)&Ks[(n * 16 + lc) * 72 + kt * 32 + q8];
#pragma unroll
      for (int i = 0; i < 2; ++i)
        s[i][n] = __builtin_amdgcn_mfma_f32_16x16x32_bf16(a[i], b, s[i][n], 0, 0, 0);
    }
  }

  // softmax over 128 cols (4-lane-group reduce across n-frags)
  float linv[2][4];
#pragma unroll
  for (int i = 0; i < 2; ++i) {
#pragma unroll
    for (int g = 0; g < 4; ++g) {
      float mx = -1e30f;
#pragma unroll
      for (int n = 0; n < 8; ++n) mx = fmaxf(mx, s[i][n][g]);
      mx = fmaxf(mx, __shfl_xor(mx, 1, 64));
      mx = fmaxf(mx, __shfl_xor(mx, 2, 64));
      mx = fmaxf(mx, __shfl_xor(mx, 4, 64));
      mx = fmaxf(mx, __shfl_xor(mx, 8, 64));
      float sum = 0.f;
#pragma unroll
      for (int n = 0; n < 8; ++n) {
        float e = __expf(0.125f * (s[i][n][g] - mx));
        s[i][n][g] = e;
        sum += e;
      }
      sum += __shfl_xor(sum, 1, 64);
      sum += __shfl_xor(sum, 2, 64);
      sum += __shfl_xor(sum, 4, 64);
      sum += __shfl_xor(sum, 8, 64);
      linv[i][g] = 1.0f / sum;
    }
  }
  __syncthreads();  // Qs/Ks reads done; Ps/Vt may overlay

  // write Ps (over Qs+Ks) and Vt from registers (b64-packed, 4 r per store)
#pragma unroll
  for (int i = 0; i < 2; ++i)
#pragma unroll
    for (int n = 0; n < 8; ++n)
#pragma unroll
      for (int g = 0; g < 4; ++g)
        Ps[(size_t)(w * 32 + i * 16 + lr4 + g) * 136 + n * 16 + lc] = (__bf16)s[i][n][g];
#pragma unroll
  for (int i = 0; i < 2; ++i)
#pragma unroll
    for (int j = 8; j < 12; ++j) {
      bf16x4 pv;
#pragma unroll
      for (int g = 0; g < 4; ++g) pv[g] = (__bf16)accp[i][j][g];
      *(uint2*)&Vt[(size_t)((j - 8) * 16 + lc) * 136 + w * 32 + i * 16 + lr4] =
          __builtin_bit_cast(uint2, pv);
    }
  __syncthreads();

  // PV
  f32x4 o[2][4];
#pragma unroll
  for (int i = 0; i < 2; ++i)
#pragma unroll
    for (int n = 0; n < 4; ++n) o[i][n] = (f32x4){0.f, 0.f, 0.f, 0.f};
#pragma unroll
  for (int kt = 0; kt < 4; ++kt) {
    bf16x8 a[2];
#pragma unroll
    for (int i = 0; i < 2; ++i)
      a[i] = *(const bf16x8*)&Ps[(w * 32 + i * 16 + lc) * 136 + kt * 32 + q8];
#pragma unroll
    for (int n = 0; n < 4; ++n) {
      bf16x8 b = *(const bf16x8*)&Vt[(n * 16 + lc) * 136 + kt * 32 + q8];
#pragma unroll
      for (int i = 0; i < 2; ++i)
        o[i][n] = __builtin_amdgcn_mfma_f32_16x16x32_bf16(a[i], b, o[i][n], 0, 0, 0);
    }
  }

  // staged, vectorized ob write
  __syncthreads();
#pragma unroll
  for (int i = 0; i < 2; ++i)
#pragma unroll
    for (int n = 0; n < 4; ++n)
#pragma unroll
      for (int g = 0; g < 4; ++g) {
        int r = w * 32 + i * 16 + lr4 + g;
        int dh = n * 16 + lc;
        Ot[r * 72 + dh] = (__bf16)(o[i][n][g] * linv[i][g]);
      }
  __syncthreads();
#pragma unroll
  for (int u = 0; u < 4; ++u) {
    int flat = t + 256 * u;
    int r = flat >> 3, c8 = (flat & 7) << 3;
    uint4 val = *(uint4*)&Ot[r * 72 + c8];
    *(uint4*)&ob[((size_t)(lrel * R_ + r)) * INNER_ + h * 64 + c8] = val;
  }
}

// ---------------------------------------------------------------------------
extern "C" void kernel_launch(void* const* d_in, const int* in_sizes, int n_in,
                              void* d_out, int out_size, void* d_ws,
                              size_t ws_size, hipStream_t stream) {
  (void)in_sizes; (void)n_in; (void)out_size;
  const float* m = (const float*)d_in[0];
  const float* pair = (const float*)d_in[1];
  const float* Wq_w = (const float*)d_in[2];
  const float* Wkv_w = (const float*)d_in[3];
  const float* Wo_w = (const float*)d_in[4];
  const float* bo_w = (const float*)d_in[5];
  const float* Wq_h = (const float*)d_in[6];
  const float* Wkv_h = (const float*)d_in[7];
  const float* Wo_h = (const float*)d_in[8];
  const float* bo_h = (const float*)d_in[9];
  const float* ln_g = (const float*)d_in[10];
  const float* ln_b = (const float*)d_in[11];
  const float* Wpair = (const float*)d_in[12];
  const float* Wsq = (const float*)d_in[13];
  const float* bsq = (const float*)d_in[14];
  const float* Wsk = (const float*)d_in[15];
  const float* bsk = (const float*)d_in[16];
  float* out = (float*)d_out;

  // ---- choose chunking (CH) and split count (S = 8/CH) to fit workspace ----
  const size_t fixedBase = 22446080u;
  int CH = 1;
  for (; CH < 8; CH *= 2) {
    size_t partials = (size_t)(8 / CH) * 4718592u;
    size_t o = 201326592u / CH;
    if (o < 25165824u) o = 25165824u;
    if (fixedBase + partials + o <= ws_size) break;
  }
  const int S = 8 / CH;
  const int Lc = L_ / CH;
  const int Rc = R_ / CH;

  unsigned char* base = (unsigned char*)d_ws;
  __bf16* m_bf = (__bf16*)base;       base += 12582912;
  __bf16* WTw = (__bf16*)base;        base += 393216;
  __bf16* WThqk = (__bf16*)base;      base += 262144;
  __bf16* WTvh = (__bf16*)base;       base += 131072;
  __bf16* WoTw = (__bf16*)base;       base += 131072;
  __bf16* WoTh = (__bf16*)base;       base += 131072;
  __bf16* WskT = (__bf16*)base;       base += 32768;
  __bf16* WsqT = (__bf16*)base;       base += 32768;
  float* wtie = (float*)base;         base += 1572864;
  float* pb = (float*)base;           base += 4718592;
  __bf16* attnb = (__bf16*)base;      base += 2359296;
  __bf16* qsb = (__bf16*)base;        base += 98304;
  float* dotsP = (float*)base;        base += (size_t)S * 4718592u;
  unsigned char* ovl = base;
  __bf16* ksb = (__bf16*)ovl;  // phase A only

  const size_t BUF = 25165824u / CH;
  __bf16* qb = (__bf16*)ovl;
  __bf16* kb = qb + BUF;
  __bf16* vb = kb + BUF;
  __bf16* ob = vb + BUF;

  prep_kernel<<<3208, 256, 0, stream>>>(m, m_bf, Wq_w, Wkv_w, Wq_h, Wkv_h, Wo_w,
                                        Wo_h, Wsk, Wsq, WTw, WThqk, WTvh, WoTw,
                                        WoTh, WskT, WsqT);

  // tie projections (ks rows 0..383 tiles, qs rows 384..386) + softmax + pair bias
  mm_k<8><<<dim3(1, 387), 256, 0, stream>>>(m_bf, WskT, bsk, bsq, ksb, qsb, WsqT,
                                            nullptr, 128, 0, Rc, 0, 0, 1);
  tie_kernel<<<L_ * H_, 128, 0, stream>>>(qsb, ksb, wtie);
  lnpb_kernel<<<(L_ * L_) / 256, 256, 0, stream>>>(pair, ln_g, ln_b, Wpair, pb);

  for (int c = 0; c < CH; ++c) {
    int l0 = c * Lc;
    fattw_kernel<<<Lc * H_, 256, 0, stream>>>(m_bf, WTw, ob, l0);
    mm_k<4><<<dim3(1, Lc), 256, 0, stream>>>(ob, WoTw, bo_w, nullptr, nullptr, nullptr,
                                             nullptr, out, 512, l0, Rc, 0, 0, 1);
  }

  for (int c = 0; c < CH; ++c) {
    int r0 = c * Rc;
    mm_k<1><<<dim3(8, Rc * 3), 256, 0, stream>>>(m_bf, WThqk, nullptr, wtie, qb, kb,
                                                 nullptr, nullptr, 128, r0, Rc, 0, 0, 1);
    mm_k<2><<<9 * H_ * S, 256, 0, stream>>>(qb, kb, nullptr, nullptr, nullptr,
                                            nullptr, nullptr, dotsP,
                                            (Rc * 64) / S, r0, Rc, Rc * 64,
                                            (c == 0) ? 1 : 0, S);
  }
  sm_kernel<<<H_ * L_, 128, 0, stream>>>(pb, dotsP, S, attnb);

  for (int c = 0; c < CH; ++c) {
    int r0 = c * Rc;
    mm_k<6><<<dim3(3, 4, Rc), 256, 0, stream>>>(WTvh, m_bf, nullptr, nullptr, vb, nullptr,
                                                nullptr, nullptr, 128, r0, Rc, 0, 0, 1);
    mm_k<3><<<dim3(Rc / 2, 3, 8), 256, 0, stream>>>(attnb, vb, nullptr, nullptr, ob, nullptr,
                                                    nullptr, nullptr, 384, r0, Rc, 0, 0, 1);
    mm_k<5><<<dim3(1, Rc * 3), 256, 0, stream>>>(ob, WoTh, bo_h, nullptr, nullptr, nullptr,
                                                 nullptr, out, 512, r0, Rc, 0, 0, 1);
  }
}

// Round 11
// 455.653 us; speedup vs baseline: 1.0552x; 1.0114x over previous
//
#include <hip/hip_runtime.h>
#include <math.h>

#define L_ 384
#define R_ 128
#define D_ 128
#define H_ 8
#define DH_ 64
#define INNER_ 512

typedef __bf16 bf16x8 __attribute__((ext_vector_type(8)));
typedef __bf16 bf16x4 __attribute__((ext_vector_type(4)));
typedef float f32x4 __attribute__((ext_vector_type(4)));

__device__ __forceinline__ float wred_sum(float v) {
#pragma unroll
  for (int o = 32; o > 0; o >>= 1) v += __shfl_xor(v, o, 64);
  return v;
}
__device__ __forceinline__ float wred_max(float v) {
#pragma unroll
  for (int o = 32; o > 0; o >>= 1) v = fmaxf(v, __shfl_xor(v, o, 64));
  return v;
}

// ---------------------------------------------------------------------------
// prep: m fp32->bf16 (blocks 0..3071) + all weight transposes (blocks 3072..3207)
// ---------------------------------------------------------------------------
__global__ __launch_bounds__(256) void prep_kernel(
    const float* __restrict__ m, __bf16* __restrict__ m_bf,
    const float* __restrict__ Wq_w, const float* __restrict__ Wkv_w,
    const float* __restrict__ Wq_h, const float* __restrict__ Wkv_h,
    const float* __restrict__ Wo_w, const float* __restrict__ Wo_h,
    const float* __restrict__ Wsk, const float* __restrict__ Wsq,
    __bf16* __restrict__ WTw, __bf16* __restrict__ WThqk,
    __bf16* __restrict__ WTvh, __bf16* __restrict__ WoTw,
    __bf16* __restrict__ WoTh, __bf16* __restrict__ WskT,
    __bf16* __restrict__ WsqT) {
  __shared__ float Ls[64 * 65];
  int b = blockIdx.x;
  int t = threadIdx.x;
  if (b < 3072) {
    int i = b * 256 + t;
    float4 a = *(const float4*)(m + (size_t)i * 8);
    float4 c = *(const float4*)(m + (size_t)i * 8 + 4);
    bf16x8 o;
    o[0] = (__bf16)a.x; o[1] = (__bf16)a.y; o[2] = (__bf16)a.z; o[3] = (__bf16)a.w;
    o[4] = (__bf16)c.x; o[5] = (__bf16)c.y; o[6] = (__bf16)c.z; o[7] = (__bf16)c.w;
    *(uint4*)(m_bf + (size_t)i * 8) = __builtin_bit_cast(uint4, o);
    return;
  }
  int j = b - 3072;
  const float* src; __bf16* dst; int Kd, Ns, noff, gx, base;
  if (j < 16)       { src = Wq_w;  dst = WTw;             Kd = 128; Ns = 512;  noff = 0;   gx = 8;  base = 0; }
  else if (j < 48)  { src = Wkv_w; dst = WTw + 512 * 128; Kd = 128; Ns = 1024; noff = 0;   gx = 16; base = 16; }
  else if (j < 64)  { src = Wq_h;  dst = WThqk;           Kd = 128; Ns = 512;  noff = 0;   gx = 8;  base = 48; }
  else if (j < 80)  { src = Wkv_h; dst = WThqk + 512 * 128; Kd = 128; Ns = 1024; noff = 0; gx = 8;  base = 64; }
  else if (j < 96)  { src = Wkv_h; dst = WTvh;            Kd = 128; Ns = 1024; noff = 512; gx = 8;  base = 80; }
  else if (j < 112) { src = Wo_w;  dst = WoTw;            Kd = 512; Ns = 128;  noff = 0;   gx = 2;  base = 96; }
  else if (j < 128) { src = Wo_h;  dst = WoTh;            Kd = 512; Ns = 128;  noff = 0;   gx = 2;  base = 112; }
  else if (j < 132) { src = Wsk;   dst = WskT;            Kd = 128; Ns = 128;  noff = 0;   gx = 2;  base = 128; }
  else              { src = Wsq;   dst = WsqT;            Kd = 128; Ns = 128;  noff = 0;   gx = 2;  base = 132; }
  int jl = j - base;
  int n0 = (jl % gx) * 64, k0 = (jl / gx) * 64;
#pragma unroll
  for (int u = 0; u < 4; ++u) {
    int flat = t + 256 * u;
    int kr = flat >> 4, nc = (flat & 15) * 4;
    float4 v = *(const float4*)&src[(size_t)(k0 + kr) * Ns + noff + n0 + nc];
    Ls[kr * 65 + nc + 0] = v.x;
    Ls[kr * 65 + nc + 1] = v.y;
    Ls[kr * 65 + nc + 2] = v.z;
    Ls[kr * 65 + nc + 3] = v.w;
  }
  __syncthreads();
#pragma unroll
  for (int u = 0; u < 2; ++u) {
    int flat = t + 256 * u;
    int nr = flat >> 3, kc = (flat & 7) * 8;
    bf16x8 o;
#pragma unroll
    for (int q = 0; q < 8; ++q) o[q] = (__bf16)Ls[(kc + q) * 65 + nr];
    *(uint4*)&dst[(size_t)(n0 + nr) * Kd + k0 + kc] = __builtin_bit_cast(uint4, o);
  }
}

// ---------------------------------------------------------------------------
// bf16 MFMA GEMM, 128x128 tile, BK=64, 256 threads (4 waves 2x2), 16x16x32 mfma.
// Epilogue: LDS-staged, fully vectorized (uint4 bf16 / float4 fp32) stores.
// MODE 1: PROJ_H   A=m_bf, B=WThqk, C->qh (tie-scaled) / kh
// MODE 2: DOTS     pure NT GEMM, 1D XCD-swizzled grid, split-K partials fp32
// MODE 3: OH       A=attnb[h][L][L], B=vt[h][n][L], C->ob bf16
//                  1D XCD-chunked grid, m-tile fastest (3 blocks share B-tile)
// MODE 4: OUT_W    C = 0.5*(acc+bias) -> out fp32
// MODE 5: OUT_H    C += 0.5*(acc+bias) -> out fp32
// MODE 6: PROJ_VT  A=WTvh, B=m_bf rows, C->vt bf16 (transposed v)
//                  1D XCD-chunked grid, y(A-row-tile) fastest (4 share B-tile)
// MODE 8: TIE PROJ ks (m0<49152) / qs (m0>=49152, B=O2=WsqT, bias=tie=bsq)
// ---------------------------------------------------------------------------
template <int MODE>
__global__ __launch_bounds__(256) void mm_k(
    const __bf16* __restrict__ A, const __bf16* __restrict__ B,
    const float* __restrict__ bias, const float* __restrict__ tie,
    __bf16* __restrict__ O0, __bf16* __restrict__ O1, __bf16* __restrict__ O2,
    float* __restrict__ F0,
    int K, int c0, int Rc, int KT, int firstChunk, int S) {
  __shared__ __bf16 shm[2 * 128 * 72];
  __bf16* As = shm;
  __bf16* Bs = shm + 128 * 72;
  const int t = threadIdx.x;
  const int lane = t & 63, w = t >> 6;
  const int wm = w >> 1, wn = w & 1;
  int n0, m0, h = 0, s = 0, kOff = 0, zr = 0;
  if (MODE == 2) {
    int b = blockIdx.x;
    int xcd = b & 7, t2 = b >> 3;
    int i3 = t2 % 3, slot = t2 / 3;
    int g = xcd * (gridDim.x / 24) + slot;
    n0 = i3 * 128;
    m0 = (g % 3) * 128;
    int z = g / 3;
    h = z / S; s = z % S; kOff = s * K;
  } else if (MODE == 1) {
    // XCD-chunked remap: all n-tiles of an m-tile on one XCD's L2.
    const int gx = 8;
    int nb = gx * gridDim.y;
    int bid = blockIdx.y * gx + blockIdx.x;
    int vv = (bid & 7) * (nb >> 3) + (bid >> 3);
    n0 = (vv % gx) * 128;
    m0 = (vv / gx) * 128;
  } else if (MODE == 3) {
    // 1D chunked: vv = ((h*(Rc/2) + nx)*3 + y); y (m-tile) fastest so the
    // 3 blocks sharing one vt B-tile run consecutively on one XCD.
    int nwg = gridDim.x, bid = blockIdx.x;
    int vv = (bid & 7) * (nwg >> 3) + (bid >> 3);
    int y = vv % 3; int tt = vv / 3;
    int half = Rc >> 1;
    int nx = tt % half; h = tt / half;
    n0 = nx * 128; m0 = y * 128;
  } else if (MODE == 6) {
    // 1D chunked: vv = ((zr*3 + x)*4 + y); y (WTvh row-tile) fastest so the
    // 4 blocks sharing one m_bf B-tile run consecutively on one XCD.
    int nwg = gridDim.x, bid = blockIdx.x;
    int vv = (bid & 7) * (nwg >> 3) + (bid >> 3);
    int y = vv & 3; int tt = vv >> 2;
    int x = tt % 3; zr = tt / 3;
    n0 = x * 128; m0 = y * 128;
  } else {
    n0 = blockIdx.x * 128;
    m0 = blockIdx.y * 128;
  }
  const int pbase = (MODE == 8 && m0 >= 49152) ? 49152 : 0;
  const __bf16* Bmat = (MODE == 8 && pbase) ? (const __bf16*)O2 : B;

  f32x4 acc[4][4];
#pragma unroll
  for (int i = 0; i < 4; ++i)
#pragma unroll
    for (int j = 0; j < 4; ++j) acc[i][j] = (f32x4){0.f, 0.f, 0.f, 0.f};

  for (int k0 = 0; k0 < K; k0 += 64) {
#pragma unroll
    for (int u = 0; u < 4; ++u) {
      int flat = t + 256 * u;
      int row = flat >> 3;
      int c8 = (flat & 7) << 3;
      const __bf16* ap;
      int p = m0 + row;
      if (MODE == 1) ap = A + ((size_t)(c0 * L_ + p)) * 128 + k0 + c8;
      else if (MODE == 2) ap = A + ((size_t)(h * L_ + p)) * KT + kOff + k0 + c8;
      else if (MODE == 3) ap = A + ((size_t)(h * L_ + p)) * L_ + k0 + c8;
      else if (MODE == 4) ap = A + (size_t)p * INNER_ + k0 + c8;
      else if (MODE == 5) { int rrel = p / L_, l = p - rrel * L_;
        ap = A + (((size_t)((k0 >> 6) * L_ + l)) * Rc + rrel) * 64 + c8; }
      else if (MODE == 8) ap = A + (size_t)(p - pbase) * 128 + k0 + c8;
      else ap = A + (size_t)p * 128 + k0 + c8;
      *(uint4*)&As[row * 72 + c8] = *(const uint4*)ap;
      const __bf16* bp;
      int n = n0 + row;
      if (MODE == 1 || MODE == 8) bp = Bmat + (size_t)n * 128 + k0 + c8;
      else if (MODE == 2) bp = B + ((size_t)(h * L_ + n)) * KT + kOff + k0 + c8;
      else if (MODE == 3) bp = B + ((size_t)(h * Rc * 64 + n)) * L_ + k0 + c8;
      else if (MODE == 4 || MODE == 5) bp = B + (size_t)n * INNER_ + k0 + c8;
      else bp = B + ((size_t)((c0 + zr) * L_ + n)) * 128 + k0 + c8;
      *(uint4*)&Bs[row * 72 + c8] = *(const uint4*)bp;
    }
    __syncthreads();
    {
      int lc = lane & 15, q8 = (lane >> 4) << 3;
#pragma unroll
      for (int kt = 0; kt < 2; ++kt) {
        bf16x8 af[4], bfr[4];
#pragma unroll
        for (int i = 0; i < 4; ++i) {
          af[i] = *(const bf16x8*)&As[(wm * 64 + i * 16 + lc) * 72 + kt * 32 + q8];
          bfr[i] = *(const bf16x8*)&Bs[(wn * 64 + i * 16 + lc) * 72 + kt * 32 + q8];
        }
#pragma unroll
        for (int i = 0; i < 4; ++i)
#pragma unroll
          for (int j = 0; j < 4; ++j)
            acc[i][j] = __builtin_amdgcn_mfma_f32_16x16x32_bf16(af[i], bfr[j], acc[i][j], 0, 0, 0);
      }
    }
    __syncthreads();
  }

  const int lce = lane & 15, lr4 = (lane >> 4) << 2;

  // MODE 1 (qh blocks): stage the 256 tie weights into LDS, pull into regs.
  float tw[4][4];
  if (MODE == 1 && n0 < 512) {
    float* tieS = (float*)shm;  // safe: all LDS reads done (barrier above)
    int row = t >> 1, hh2 = t & 1;
    int pmt = m0 + row;
    int rrelt = pmt / L_, lt = pmt - rrelt * L_;
    int h0 = n0 >> 6;
    tieS[row * 2 + hh2] = tie[((size_t)(lt * H_ + h0 + hh2)) * R_ + c0 + rrelt];
    __syncthreads();
#pragma unroll
    for (int i = 0; i < 4; ++i)
#pragma unroll
      for (int g = 0; g < 4; ++g)
        tw[i][g] = tieS[(wm * 64 + i * 16 + lr4 + g) * 2 + wn];
    __syncthreads();
  }

  if (MODE == 1 || MODE == 3 || MODE == 6 || MODE == 8) {
    // ---- bf16 epilogue: stage full 128x128 tile, store uint4 (8 bf16) ----
    __bf16* St = shm;  // pitch 136 bf16 (272 B, 16B-aligned rows), 34816 B
    const float* bb8 = (MODE == 8) ? (pbase ? tie : bias) : nullptr;
#pragma unroll
    for (int i = 0; i < 4; ++i)
#pragma unroll
      for (int j = 0; j < 4; ++j)
#pragma unroll
        for (int g = 0; g < 4; ++g) {
          float v = acc[i][j][g];
          if (MODE == 1 && n0 < 512) v *= tw[i][g];
          if (MODE == 8) v += bb8[n0 + wn * 64 + j * 16 + lce];
          St[(wm * 64 + i * 16 + lr4 + g) * 136 + wn * 64 + j * 16 + lce] = (__bf16)v;
        }
    __syncthreads();
#pragma unroll
    for (int u = 0; u < 8; ++u) {
      int flat = t + 256 * u;
      int row = flat >> 4, c8 = (flat & 15) << 3;
      uint4 val = *(uint4*)&St[row * 136 + c8];
      int pm = m0 + row, pn = n0 + c8;
      if (MODE == 1) {
        int nn = pn;
        int rrel = pm / L_, l = pm - rrel * L_;
        if (nn < 512) {
          int hh = nn >> 6, dh = nn & 63;
          *(uint4*)&O0[(((size_t)(hh * L_ + l)) * Rc + rrel) * 64 + dh] = val;
        } else {
          nn -= 512;
          int hh = nn >> 6, dh = nn & 63;
          *(uint4*)&O1[(((size_t)(hh * L_ + l)) * Rc + rrel) * 64 + dh] = val;
        }
      } else if (MODE == 3) {
        *(uint4*)&O0[((size_t)(h * L_ + pm)) * ((size_t)Rc * 64) + pn] = val;
      } else if (MODE == 6) {
        *(uint4*)&O0[(((size_t)((pm >> 6) * Rc + zr)) * 64 + (pm & 63)) * (size_t)L_ + pn] = val;
      } else {  // MODE 8
        __bf16* dst = pbase ? O1 : O0;
        *(uint4*)&dst[(size_t)(pm - pbase) * 128 + pn] = val;
      }
    }
  } else {
    // ---- fp32 epilogue (modes 2/4/5): 2 half-tiles of 64 rows, float4 ----
    float* Sf = (float*)shm;  // 64 rows, pitch 132 fp32 (528 B), 33792 B
#pragma unroll
    for (int half = 0; half < 2; ++half) {
      if (half) __syncthreads();
      if (wm == half) {
#pragma unroll
        for (int i = 0; i < 4; ++i)
#pragma unroll
          for (int j = 0; j < 4; ++j)
#pragma unroll
            for (int g = 0; g < 4; ++g)
              Sf[(i * 16 + lr4 + g) * 132 + wn * 64 + j * 16 + lce] = acc[i][j][g];
      }
      __syncthreads();
#pragma unroll
      for (int u = 0; u < 8; ++u) {
        int flat = t + 256 * u;
        int row = flat >> 5, c4 = (flat & 31) << 2;
        float4 v = *(float4*)&Sf[row * 132 + c4];
        int pm = m0 + half * 64 + row, pn = n0 + c4;
        if (MODE == 2) {
          float* ptr = F0 + ((size_t)(s * H_ + h)) * (L_ * L_) + (size_t)pm * L_ + pn;
          v.x *= 0.125f; v.y *= 0.125f; v.z *= 0.125f; v.w *= 0.125f;
          if (firstChunk) {
            *(float4*)ptr = v;
          } else {
            float4 o = *(float4*)ptr;
            o.x += v.x; o.y += v.y; o.z += v.z; o.w += v.w;
            *(float4*)ptr = o;
          }
        } else if (MODE == 4) {
          float4 bv = *(const float4*)&bias[pn];
          int lrel = pm >> 7, rr = pm & 127;
          float4 o;
          o.x = 0.5f * (v.x + bv.x); o.y = 0.5f * (v.y + bv.y);
          o.z = 0.5f * (v.z + bv.z); o.w = 0.5f * (v.w + bv.w);
          *(float4*)&F0[((size_t)(rr * L_ + c0 + lrel)) * 128 + pn] = o;
        } else {  // MODE 5: RMW accumulate into out
          float4 bv = *(const float4*)&bias[pn];
          int rrel = pm / L_, l = pm - rrel * L_;
          float* ptr = F0 + ((size_t)((c0 + rrel) * L_ + l)) * 128 + pn;
          float4 o = *(float4*)ptr;
          o.x += 0.5f * (v.x + bv.x); o.y += 0.5f * (v.y + bv.y);
          o.z += 0.5f * (v.z + bv.z); o.w += 0.5f * (v.w + bv.w);
          *(float4*)ptr = o;
        }
      }
    }
  }
}

// ---------------------------------------------------------------------------
// tie softmax (bf16 inputs)
// ---------------------------------------------------------------------------
__global__ __launch_bounds__(128) void tie_kernel(const __bf16* __restrict__ qs,
                                                  const __bf16* __restrict__ ks,
                                                  float* __restrict__ wtie) {
  int bid = blockIdx.x;
  int l = bid >> 3, h = bid & 7;
  int r = threadIdx.x;
  int wid = r >> 6;
  const __bf16* qp = qs + (size_t)l * 128 + h * 16;
  const __bf16* kp = ks + ((size_t)r * L_ + l) * 128 + h * 16;
  bf16x8 q0 = *(const bf16x8*)qp;
  bf16x8 q1 = *(const bf16x8*)(qp + 8);
  bf16x8 k0 = *(const bf16x8*)kp;
  bf16x8 k1 = *(const bf16x8*)(kp + 8);
  float s = 0.f;
#pragma unroll
  for (int i = 0; i < 8; ++i)
    s += (float)q0[i] * (float)k0[i] + (float)q1[i] * (float)k1[i];
  s *= 0.25f;
  __shared__ float sm[2], ss[2];
  float wm = wred_max(s);
  if ((r & 63) == 0) sm[wid] = wm;
  __syncthreads();
  float mx = fmaxf(sm[0], sm[1]);
  float e = __expf(s - mx);
  float wsum = wred_sum(e);
  if ((r & 63) == 0) ss[wid] = wsum;
  __syncthreads();
  float tot = ss[0] + ss[1];
  wtie[((size_t)l * H_ + h) * R_ + r] = e / tot;
}

// ---------------------------------------------------------------------------
// pair LN + Wpair -> pb[h][i][j]. One THREAD per (i,j); no cross-lane ops.
// ---------------------------------------------------------------------------
__global__ __launch_bounds__(256) void lnpb_kernel(const float* __restrict__ pair,
                                                   const float* __restrict__ g,
                                                   const float* __restrict__ b,
                                                   const float* __restrict__ wp,
                                                   float* __restrict__ pb) {
  __shared__ float gws[1024];
  __shared__ float c1s[8], c2s[8];
  int t = threadIdx.x;
#pragma unroll
  for (int u = 0; u < 4; ++u) {
    int idx = t * 4 + u;
    int d = idx >> 3, h = idx & 7;
    gws[idx] = g[d] * wp[d * 8 + h];
  }
  __syncthreads();
  if (t < 8) {
    float s1 = 0.f, s2 = 0.f;
    for (int d = 0; d < 128; ++d) {
      s1 += gws[d * 8 + t];
      s2 += b[d] * wp[d * 8 + t];
    }
    c1s[t] = s1;
    c2s[t] = s2;
  }
  __syncthreads();
  int pid = blockIdx.x * 256 + t;
  const float4* xp = (const float4*)(pair + (size_t)pid * 128);
  float sum = 0.f, sumsq = 0.f;
  float dots[8] = {};
#pragma unroll 8
  for (int i = 0; i < 32; ++i) {
    float4 v = xp[i];
#pragma unroll
    for (int j = 0; j < 4; ++j) {
      float e = (&v.x)[j];
      sum += e;
      sumsq = fmaf(e, e, sumsq);
      const float* gr = &gws[(i * 4 + j) * 8];
#pragma unroll
      for (int hh = 0; hh < 8; ++hh) dots[hh] = fmaf(e, gr[hh], dots[hh]);
    }
  }
  float mu = sum * (1.0f / 128.0f);
  float var = sumsq * (1.0f / 128.0f) - mu * mu;
  float rs = 1.0f / sqrtf(var + 1e-5f);
#pragma unroll
  for (int hh = 0; hh < 8; ++hh)
    pb[(size_t)hh * (L_ * L_) + pid] = rs * (dots[hh] - mu * c1s[hh]) + c2s[hh];
}

// ---------------------------------------------------------------------------
// softmax over last dim of (pb + sum of S split-K partials) -> attn bf16
// ---------------------------------------------------------------------------
__global__ __launch_bounds__(128) void sm_kernel(const float* __restrict__ pb,
                                                 const float* __restrict__ dp,
                                                 int S, __bf16* __restrict__ ab) {
  size_t row = blockIdx.x;
  int t = threadIdx.x;
  int wid = t >> 6;
  const float* p0 = pb + row * L_;
  float x0 = p0[t], x1 = p0[t + 128], x2 = p0[t + 256];
  const size_t HLL = (size_t)H_ * L_ * L_;
  for (int s = 0; s < S; ++s) {
    const float* ps = dp + s * HLL + row * L_;
    x0 += ps[t]; x1 += ps[t + 128]; x2 += ps[t + 256];
  }
  __shared__ float sm[2], ss[2];
  float m = wred_max(fmaxf(x0, fmaxf(x1, x2)));
  if ((t & 63) == 0) sm[wid] = m;
  __syncthreads();
  m = fmaxf(sm[0], sm[1]);
  float e0 = __expf(x0 - m), e1 = __expf(x1 - m), e2 = __expf(x2 - m);
  float s2 = wred_sum(e0 + e1 + e2);
  if ((t & 63) == 0) ss[wid] = s2;
  __syncthreads();
  float inv = 1.0f / (ss[0] + ss[1]);
  __bf16* op = ab + row * L_;
  op[t] = (__bf16)(e0 * inv);
  op[t + 128] = (__bf16)(e1 * inv);
  op[t + 256] = (__bf16)(e2 * inv);
}

// ---------------------------------------------------------------------------
// FUSED column attention, round-7: per block (l, h). LDS peak 52224 B
// (<= 26*2048 so 3 blocks/CU survive granule-2048 rounding).
// Proj: Xs[128][136] staged (coalesced) + W staged per qkv GROUP [64][136];
// 3 stage/mfma cycles. Attn: q/k scattered to LDS; v HELD IN REGISTERS
// through QK^T+softmax, then Ps[128][136] overlays Qs+Ks and Vt[64][136]
// overlays the dead Wg region (b64-packed writes). PV -> Ot -> ob.
// XCD-chunked bid remap: 8 head-blocks of one l land on one XCD's L2.
// ---------------------------------------------------------------------------
__global__ __launch_bounds__(256, 3) void fattw_kernel(const __bf16* __restrict__ m_bf,
                                                       const __bf16* __restrict__ WTw,
                                                       __bf16* __restrict__ ob, int c0) {
  __shared__ __bf16 smem[26112];  // 52224 B
  __bf16* Xs = smem;           // [128][136] proj (17408)
  __bf16* Wg = smem + 17408;   // [64][136]  proj per-group (8704)
  __bf16* Qs = smem;           // [128][72]  attn (9216)
  __bf16* Ks = smem + 9216;    // [128][72]  attn (ends 18432)
  __bf16* Ps = smem;           // [128][136] over Qs+Ks (0..17408)
  __bf16* Vt = smem + 17408;   // [64][136]  over Wg (17408..26112)
  __bf16* Ot = smem;           // [128][72]  after PV

  int bid = blockIdx.x;
  int v = (bid & 7) * (gridDim.x >> 3) + (bid >> 3);
  int lrel = v >> 3, h = v & 7;
  int l = c0 + lrel;
  int t = threadIdx.x;
  const int lane = t & 63, w = t >> 6;
  const int lc = lane & 15, q8 = (lane >> 4) << 3;
  const int lr4 = (lane >> 4) << 2;

  // stage x_l [128][136] (coalesced)
#pragma unroll
  for (int u = 0; u < 8; ++u) {
    int flat = t + 256 * u;
    int row = flat >> 4, c8 = (flat & 15) << 3;
    *(uint4*)&Xs[row * 136 + c8] =
        *(const uint4*)&m_bf[((size_t)(row * L_ + l)) * 128 + c8];
  }

  f32x4 accp[2][12];
#pragma unroll
  for (int i = 0; i < 2; ++i)
#pragma unroll
    for (int j = 0; j < 12; ++j) accp[i][j] = (f32x4){0.f, 0.f, 0.f, 0.f};

  // proj GEMM in 3 qkv groups: stage Wg[64][136] -> 32 MFMAs, full K=128 each
#pragma unroll
  for (int g = 0; g < 3; ++g) {
#pragma unroll
    for (int u = 0; u < 4; ++u) {
      int flat = t + 256 * u;
      int row = flat >> 4, c8 = (flat & 15) << 3;
      *(uint4*)&Wg[row * 136 + c8] =
          *(const uint4*)&WTw[((size_t)(g * 512 + h * 64 + row)) * 128 + c8];
    }
    __syncthreads();
#pragma unroll
    for (int kt = 0; kt < 4; ++kt) {
      bf16x8 a0 = *(const bf16x8*)&Xs[(w * 32 + lc) * 136 + kt * 32 + q8];
      bf16x8 a1 = *(const bf16x8*)&Xs[(w * 32 + 16 + lc) * 136 + kt * 32 + q8];
#pragma unroll
      for (int j = 0; j < 4; ++j) {
        bf16x8 b = *(const bf16x8*)&Wg[(j * 16 + lc) * 136 + kt * 32 + q8];
        accp[0][g * 4 + j] = __builtin_amdgcn_mfma_f32_16x16x32_bf16(a0, b, accp[0][g * 4 + j], 0, 0, 0);
        accp[1][g * 4 + j] = __builtin_amdgcn_mfma_f32_16x16x32_bf16(a1, b, accp[1][g * 4 + j], 0, 0, 0);
      }
    }
    __syncthreads();
  }

  // scatter q/k into attn LDS (v stays in registers)
#pragma unroll
  for (int i = 0; i < 2; ++i)
#pragma unroll
    for (int j = 0; j < 8; ++j)
#pragma unroll
      for (int g = 0; g < 4; ++g) {
        int r_loc = w * 32 + i * 16 + lr4 + g;
        __bf16 val = (__bf16)accp[i][j][g];
        if (j < 4) Qs[r_loc * 72 + j * 16 + lc] = val;
        else Ks[r_loc * 72 + (j - 4) * 16 + lc] = val;
      }
  __syncthreads();

  // QK^T
  f32x4 s[2][8];
#pragma unroll
  for (int i = 0; i < 2; ++i)
#pragma unroll
    for (int n = 0; n < 8; ++n) s[i][n] = (f32x4){0.f, 0.f, 0.f, 0.f};
#pragma unroll
  for (int kt = 0; kt < 2; ++kt) {
    bf16x8 a[2];
#pragma unroll
    for (int i = 0; i < 2; ++i)
      a[i] = *(const bf16x8*)&Qs[(w * 32 + i * 16 + lc) * 72 + kt * 32 + q8];
#pragma unroll
    for (int n = 0; n < 8; ++n) {
      bf16x8 b = *(const bf16x8*)&Ks[(n * 16 + lc) * 72 + kt * 32 + q8];
#pragma unroll
      for (int i = 0; i < 2; ++i)
        s[i][n] = __builtin_amdgcn_mfma_f32_16x16x32_bf16(a[i], b, s[i][n], 0, 0, 0);
    }
  }

  // softmax over 128 cols (4-lane-group reduce across n-frags)
  float linv[2][4];
#pragma unroll
  for (int i = 0; i < 2; ++i) {
#pragma unroll
    for (int g = 0; g < 4; ++g) {
      float mx = -1e30f;
#pragma unroll
      for (int n = 0; n < 8; ++n) mx = fmaxf(mx, s[i][n][g]);
      mx = fmaxf(mx, __shfl_xor(mx, 1, 64));
      mx = fmaxf(mx, __shfl_xor(mx, 2, 64));
      mx = fmaxf(mx, __shfl_xor(mx, 4, 64));
      mx = fmaxf(mx, __shfl_xor(mx, 8, 64));
      float sum = 0.f;
#pragma unroll
      for (int n = 0; n < 8; ++n) {
        float e = __expf(0.125f * (s[i][n][g] - mx));
        s[i][n][g] = e;
        sum += e;
      }
      sum += __shfl_xor(sum, 1, 64);
      sum += __shfl_xor(sum, 2, 64);
      sum += __shfl_xor(sum, 4, 64);
      sum += __shfl_xor(sum, 8, 64);
      linv[i][g] = 1.0f / sum;
    }
  }
  __syncthreads();  // Qs/Ks reads done; Ps/Vt may overlay

  // write Ps (over Qs+Ks) and Vt from registers (b64-packed, 4 r per store)
#pragma unroll
  for (int i = 0; i < 2; ++i)
#pragma unroll
    for (int n = 0; n < 8; ++n)
#pragma unroll
      for (int g = 0; g < 4; ++g)
        Ps[(size_t)(w * 32 + i * 16 + lr4 + g) * 136 + n * 16 + lc] = (__bf16)s[i][n][g];
#pragma unroll
  for (int i = 0; i < 2; ++i)
#pragma unroll
    for (int j = 8; j < 12; ++j) {
      bf16x4 pv;
#pragma unroll
      for (int g = 0; g < 4; ++g) pv[g] = (__bf16)accp[i][j][g];
      *(uint2*)&Vt[(size_t)((j - 8) * 16 + lc) * 136 + w * 32 + i * 16 + lr4] =
          __builtin_bit_cast(uint2, pv);
    }
  __syncthreads();

  // PV
  f32x4 o[2][4];
#pragma unroll
  for (int i = 0; i < 2; ++i)
#pragma unroll
    for (int n = 0; n < 4; ++n) o[i][n] = (f32x4){0.f, 0.f, 0.f, 0.f};
#pragma unroll
  for (int kt = 0; kt < 4; ++kt) {
    bf16x8 a[2];
#pragma unroll
    for (int i = 0; i < 2; ++i)
      a[i] = *(const bf16x8*)&Ps[(w * 32 + i * 16 + lc) * 136 + kt * 32 + q8];
#pragma unroll
    for (int n = 0; n < 4; ++n) {
      bf16x8 b = *(const bf16x8*)&Vt[(n * 16 + lc) * 136 + kt * 32 + q8];
#pragma unroll
      for (int i = 0; i < 2; ++i)
        o[i][n] = __builtin_amdgcn_mfma_f32_16x16x32_bf16(a[i], b, o[i][n], 0, 0, 0);
    }
  }

  // staged, vectorized ob write
  __syncthreads();
#pragma unroll
  for (int i = 0; i < 2; ++i)
#pragma unroll
    for (int n = 0; n < 4; ++n)
#pragma unroll
      for (int g = 0; g < 4; ++g) {
        int r = w * 32 + i * 16 + lr4 + g;
        int dh = n * 16 + lc;
        Ot[r * 72 + dh] = (__bf16)(o[i][n][g] * linv[i][g]);
      }
  __syncthreads();
#pragma unroll
  for (int u = 0; u < 4; ++u) {
    int flat = t + 256 * u;
    int r = flat >> 3, c8 = (flat & 7) << 3;
    uint4 val = *(uint4*)&Ot[r * 72 + c8];
    *(uint4*)&ob[((size_t)(lrel * R_ + r)) * INNER_ + h * 64 + c8] = val;
  }
}

// ---------------------------------------------------------------------------
extern "C" void kernel_launch(void* const* d_in, const int* in_sizes, int n_in,
                              void* d_out, int out_size, void* d_ws,
                              size_t ws_size, hipStream_t stream) {
  (void)in_sizes; (void)n_in; (void)out_size;
  const float* m = (const float*)d_in[0];
  const float* pair = (const float*)d_in[1];
  const float* Wq_w = (const float*)d_in[2];
  const float* Wkv_w = (const float*)d_in[3];
  const float* Wo_w = (const float*)d_in[4];
  const float* bo_w = (const float*)d_in[5];
  const float* Wq_h = (const float*)d_in[6];
  const float* Wkv_h = (const float*)d_in[7];
  const float* Wo_h = (const float*)d_in[8];
  const float* bo_h = (const float*)d_in[9];
  const float* ln_g = (const float*)d_in[10];
  const float* ln_b = (const float*)d_in[11];
  const float* Wpair = (const float*)d_in[12];
  const float* Wsq = (const float*)d_in[13];
  const float* bsq = (const float*)d_in[14];
  const float* Wsk = (const float*)d_in[15];
  const float* bsk = (const float*)d_in[16];
  float* out = (float*)d_out;

  // ---- choose chunking (CH) and split count (S = 8/CH) to fit workspace ----
  const size_t fixedBase = 22446080u;
  int CH = 1;
  for (; CH < 8; CH *= 2) {
    size_t partials = (size_t)(8 / CH) * 4718592u;
    size_t o = 201326592u / CH;
    if (o < 25165824u) o = 25165824u;
    if (fixedBase + partials + o <= ws_size) break;
  }
  const int S = 8 / CH;
  const int Lc = L_ / CH;
  const int Rc = R_ / CH;

  unsigned char* base = (unsigned char*)d_ws;
  __bf16* m_bf = (__bf16*)base;       base += 12582912;
  __bf16* WTw = (__bf16*)base;        base += 393216;
  __bf16* WThqk = (__bf16*)base;      base += 262144;
  __bf16* WTvh = (__bf16*)base;       base += 131072;
  __bf16* WoTw = (__bf16*)base;       base += 131072;
  __bf16* WoTh = (__bf16*)base;       base += 131072;
  __bf16* WskT = (__bf16*)base;       base += 32768;
  __bf16* WsqT = (__bf16*)base;       base += 32768;
  float* wtie = (float*)base;         base += 1572864;
  float* pb = (float*)base;           base += 4718592;
  __bf16* attnb = (__bf16*)base;      base += 2359296;
  __bf16* qsb = (__bf16*)base;        base += 98304;
  float* dotsP = (float*)base;        base += (size_t)S * 4718592u;
  unsigned char* ovl = base;
  __bf16* ksb = (__bf16*)ovl;  // phase A only

  const size_t BUF = 25165824u / CH;
  __bf16* qb = (__bf16*)ovl;
  __bf16* kb = qb + BUF;
  __bf16* vb = kb + BUF;
  __bf16* ob = vb + BUF;

  prep_kernel<<<3208, 256, 0, stream>>>(m, m_bf, Wq_w, Wkv_w, Wq_h, Wkv_h, Wo_w,
                                        Wo_h, Wsk, Wsq, WTw, WThqk, WTvh, WoTw,
                                        WoTh, WskT, WsqT);

  // tie projections (ks rows 0..383 tiles, qs rows 384..386) + softmax + pair bias
  mm_k<8><<<dim3(1, 387), 256, 0, stream>>>(m_bf, WskT, bsk, bsq, ksb, qsb, WsqT,
                                            nullptr, 128, 0, Rc, 0, 0, 1);
  tie_kernel<<<L_ * H_, 128, 0, stream>>>(qsb, ksb, wtie);
  lnpb_kernel<<<(L_ * L_) / 256, 256, 0, stream>>>(pair, ln_g, ln_b, Wpair, pb);

  for (int c = 0; c < CH; ++c) {
    int l0 = c * Lc;
    fattw_kernel<<<Lc * H_, 256, 0, stream>>>(m_bf, WTw, ob, l0);
    mm_k<4><<<dim3(1, Lc), 256, 0, stream>>>(ob, WoTw, bo_w, nullptr, nullptr, nullptr,
                                             nullptr, out, 512, l0, Rc, 0, 0, 1);
  }

  for (int c = 0; c < CH; ++c) {
    int r0 = c * Rc;
    mm_k<1><<<dim3(8, Rc * 3), 256, 0, stream>>>(m_bf, WThqk, nullptr, wtie, qb, kb,
                                                 nullptr, nullptr, 128, r0, Rc, 0, 0, 1);
    mm_k<2><<<9 * H_ * S, 256, 0, stream>>>(qb, kb, nullptr, nullptr, nullptr,
                                            nullptr, nullptr, dotsP,
                                            (Rc * 64) / S, r0, Rc, Rc * 64,
                                            (c == 0) ? 1 : 0, S);
  }
  sm_kernel<<<H_ * L_, 128, 0, stream>>>(pb, dotsP, S, attnb);

  for (int c = 0; c < CH; ++c) {
    int r0 = c * Rc;
    mm_k<6><<<12 * Rc, 256, 0, stream>>>(WTvh, m_bf, nullptr, nullptr, vb, nullptr,
                                         nullptr, nullptr, 128, r0, Rc, 0, 0, 1);
    mm_k<3><<<12 * Rc, 256, 0, stream>>>(attnb, vb, nullptr, nullptr, ob, nullptr,
                                         nullptr, nullptr, 384, r0, Rc, 0, 0, 1);
    mm_k<5><<<dim3(1, Rc * 3), 256, 0, stream>>>(ob, WoTh, bo_h, nullptr, nullptr, nullptr,
                                                 nullptr, out, 512, r0, Rc, 0, 0, 1);
  }
}

// Round 12
// 452.833 us; speedup vs baseline: 1.0617x; 1.0062x over previous
//
#include <hip/hip_runtime.h>
#include <math.h>

#define L_ 384
#define R_ 128
#define D_ 128
#define H_ 8
#define DH_ 64
#define INNER_ 512

typedef __bf16 bf16x8 __attribute__((ext_vector_type(8)));
typedef __bf16 bf16x4 __attribute__((ext_vector_type(4)));
typedef float f32x4 __attribute__((ext_vector_type(4)));

__device__ __forceinline__ float wred_sum(float v) {
#pragma unroll
  for (int o = 32; o > 0; o >>= 1) v += __shfl_xor(v, o, 64);
  return v;
}
__device__ __forceinline__ float wred_max(float v) {
#pragma unroll
  for (int o = 32; o > 0; o >>= 1) v = fmaxf(v, __shfl_xor(v, o, 64));
  return v;
}

// ---------------------------------------------------------------------------
// prep: m fp32->bf16 (blocks 0..3071) + all weight transposes (blocks 3072..3207)
// ---------------------------------------------------------------------------
__global__ __launch_bounds__(256) void prep_kernel(
    const float* __restrict__ m, __bf16* __restrict__ m_bf,
    const float* __restrict__ Wq_w, const float* __restrict__ Wkv_w,
    const float* __restrict__ Wq_h, const float* __restrict__ Wkv_h,
    const float* __restrict__ Wo_w, const float* __restrict__ Wo_h,
    const float* __restrict__ Wsk, const float* __restrict__ Wsq,
    __bf16* __restrict__ WTw, __bf16* __restrict__ WThqk,
    __bf16* __restrict__ WTvh, __bf16* __restrict__ WoTw,
    __bf16* __restrict__ WoTh, __bf16* __restrict__ WskT,
    __bf16* __restrict__ WsqT) {
  __shared__ float Ls[64 * 65];
  int b = blockIdx.x;
  int t = threadIdx.x;
  if (b < 3072) {
    int i = b * 256 + t;
    float4 a = *(const float4*)(m + (size_t)i * 8);
    float4 c = *(const float4*)(m + (size_t)i * 8 + 4);
    bf16x8 o;
    o[0] = (__bf16)a.x; o[1] = (__bf16)a.y; o[2] = (__bf16)a.z; o[3] = (__bf16)a.w;
    o[4] = (__bf16)c.x; o[5] = (__bf16)c.y; o[6] = (__bf16)c.z; o[7] = (__bf16)c.w;
    *(uint4*)(m_bf + (size_t)i * 8) = __builtin_bit_cast(uint4, o);
    return;
  }
  int j = b - 3072;
  const float* src; __bf16* dst; int Kd, Ns, noff, gx, base;
  if (j < 16)       { src = Wq_w;  dst = WTw;             Kd = 128; Ns = 512;  noff = 0;   gx = 8;  base = 0; }
  else if (j < 48)  { src = Wkv_w; dst = WTw + 512 * 128; Kd = 128; Ns = 1024; noff = 0;   gx = 16; base = 16; }
  else if (j < 64)  { src = Wq_h;  dst = WThqk;           Kd = 128; Ns = 512;  noff = 0;   gx = 8;  base = 48; }
  else if (j < 80)  { src = Wkv_h; dst = WThqk + 512 * 128; Kd = 128; Ns = 1024; noff = 0; gx = 8;  base = 64; }
  else if (j < 96)  { src = Wkv_h; dst = WTvh;            Kd = 128; Ns = 1024; noff = 512; gx = 8;  base = 80; }
  else if (j < 112) { src = Wo_w;  dst = WoTw;            Kd = 512; Ns = 128;  noff = 0;   gx = 2;  base = 96; }
  else if (j < 128) { src = Wo_h;  dst = WoTh;            Kd = 512; Ns = 128;  noff = 0;   gx = 2;  base = 112; }
  else if (j < 132) { src = Wsk;   dst = WskT;            Kd = 128; Ns = 128;  noff = 0;   gx = 2;  base = 128; }
  else              { src = Wsq;   dst = WsqT;            Kd = 128; Ns = 128;  noff = 0;   gx = 2;  base = 132; }
  int jl = j - base;
  int n0 = (jl % gx) * 64, k0 = (jl / gx) * 64;
#pragma unroll
  for (int u = 0; u < 4; ++u) {
    int flat = t + 256 * u;
    int kr = flat >> 4, nc = (flat & 15) * 4;
    float4 v = *(const float4*)&src[(size_t)(k0 + kr) * Ns + noff + n0 + nc];
    Ls[kr * 65 + nc + 0] = v.x;
    Ls[kr * 65 + nc + 1] = v.y;
    Ls[kr * 65 + nc + 2] = v.z;
    Ls[kr * 65 + nc + 3] = v.w;
  }
  __syncthreads();
#pragma unroll
  for (int u = 0; u < 2; ++u) {
    int flat = t + 256 * u;
    int nr = flat >> 3, kc = (flat & 7) * 8;
    bf16x8 o;
#pragma unroll
    for (int q = 0; q < 8; ++q) o[q] = (__bf16)Ls[(kc + q) * 65 + nr];
    *(uint4*)&dst[(size_t)(n0 + nr) * Kd + k0 + kc] = __builtin_bit_cast(uint4, o);
  }
}

// ---------------------------------------------------------------------------
// Shared GEMM body: bf16 MFMA, 128x128 tile, BK=64, 4 waves 2x2, 16x16x32.
// Caller computes n0/m0/h/s/kOff/zr. Needs >= 36864 B of LDS at shm.
// ---------------------------------------------------------------------------
template <int MODE>
__device__ __forceinline__ void mmk_body(
    __bf16* shm,
    const __bf16* __restrict__ A, const __bf16* __restrict__ B,
    const float* __restrict__ bias, const float* __restrict__ tie,
    __bf16* __restrict__ O0, __bf16* __restrict__ O1, __bf16* __restrict__ O2,
    float* __restrict__ F0,
    int K, int c0, int Rc, int KT, int firstChunk, int S,
    int n0, int m0, int h, int s, int kOff, int zr) {
  __bf16* As = shm;
  __bf16* Bs = shm + 128 * 72;
  const int t = threadIdx.x;
  const int lane = t & 63, w = t >> 6;
  const int wm = w >> 1, wn = w & 1;
  const int pbase = (MODE == 8 && m0 >= 49152) ? 49152 : 0;
  const __bf16* Bmat = (MODE == 8 && pbase) ? (const __bf16*)O2 : B;

  f32x4 acc[4][4];
#pragma unroll
  for (int i = 0; i < 4; ++i)
#pragma unroll
    for (int j = 0; j < 4; ++j) acc[i][j] = (f32x4){0.f, 0.f, 0.f, 0.f};

  for (int k0 = 0; k0 < K; k0 += 64) {
#pragma unroll
    for (int u = 0; u < 4; ++u) {
      int flat = t + 256 * u;
      int row = flat >> 3;
      int c8 = (flat & 7) << 3;
      const __bf16* ap;
      int p = m0 + row;
      if (MODE == 1) ap = A + ((size_t)(c0 * L_ + p)) * 128 + k0 + c8;
      else if (MODE == 2) ap = A + ((size_t)(h * L_ + p)) * KT + kOff + k0 + c8;
      else if (MODE == 3) ap = A + ((size_t)(h * L_ + p)) * L_ + k0 + c8;
      else if (MODE == 4) ap = A + (size_t)p * INNER_ + k0 + c8;
      else if (MODE == 5) { int rrel = p / L_, l = p - rrel * L_;
        ap = A + (((size_t)((k0 >> 6) * L_ + l)) * Rc + rrel) * 64 + c8; }
      else if (MODE == 8) ap = A + (size_t)(p - pbase) * 128 + k0 + c8;
      else ap = A + (size_t)p * 128 + k0 + c8;
      *(uint4*)&As[row * 72 + c8] = *(const uint4*)ap;
      const __bf16* bp;
      int n = n0 + row;
      if (MODE == 1 || MODE == 8) bp = Bmat + (size_t)n * 128 + k0 + c8;
      else if (MODE == 2) bp = B + ((size_t)(h * L_ + n)) * KT + kOff + k0 + c8;
      else if (MODE == 3) bp = B + ((size_t)(h * Rc * 64 + n)) * L_ + k0 + c8;
      else if (MODE == 4 || MODE == 5) bp = B + (size_t)n * INNER_ + k0 + c8;
      else bp = B + ((size_t)((c0 + zr) * L_ + n)) * 128 + k0 + c8;
      *(uint4*)&Bs[row * 72 + c8] = *(const uint4*)bp;
    }
    __syncthreads();
    {
      int lc = lane & 15, q8 = (lane >> 4) << 3;
#pragma unroll
      for (int kt = 0; kt < 2; ++kt) {
        bf16x8 af[4], bfr[4];
#pragma unroll
        for (int i = 0; i < 4; ++i) {
          af[i] = *(const bf16x8*)&As[(wm * 64 + i * 16 + lc) * 72 + kt * 32 + q8];
          bfr[i] = *(const bf16x8*)&Bs[(wn * 64 + i * 16 + lc) * 72 + kt * 32 + q8];
        }
#pragma unroll
        for (int i = 0; i < 4; ++i)
#pragma unroll
          for (int j = 0; j < 4; ++j)
            acc[i][j] = __builtin_amdgcn_mfma_f32_16x16x32_bf16(af[i], bfr[j], acc[i][j], 0, 0, 0);
      }
    }
    __syncthreads();
  }

  const int lce = lane & 15, lr4 = (lane >> 4) << 2;

  // MODE 1 (qh blocks): stage the 256 tie weights into LDS, pull into regs.
  float tw[4][4];
  if (MODE == 1 && n0 < 512) {
    float* tieS = (float*)shm;  // safe: all LDS reads done (barrier above)
    int row = t >> 1, hh2 = t & 1;
    int pmt = m0 + row;
    int rrelt = pmt / L_, lt = pmt - rrelt * L_;
    int h0 = n0 >> 6;
    tieS[row * 2 + hh2] = tie[((size_t)(lt * H_ + h0 + hh2)) * R_ + c0 + rrelt];
    __syncthreads();
#pragma unroll
    for (int i = 0; i < 4; ++i)
#pragma unroll
      for (int g = 0; g < 4; ++g)
        tw[i][g] = tieS[(wm * 64 + i * 16 + lr4 + g) * 2 + wn];
    __syncthreads();
  }

  if (MODE == 1 || MODE == 3 || MODE == 6 || MODE == 8) {
    // ---- bf16 epilogue: stage full 128x128 tile, store uint4 (8 bf16) ----
    __bf16* St = shm;  // pitch 136 bf16, 34816 B
    const float* bb8 = (MODE == 8) ? (pbase ? tie : bias) : nullptr;
#pragma unroll
    for (int i = 0; i < 4; ++i)
#pragma unroll
      for (int j = 0; j < 4; ++j)
#pragma unroll
        for (int g = 0; g < 4; ++g) {
          float v = acc[i][j][g];
          if (MODE == 1 && n0 < 512) v *= tw[i][g];
          if (MODE == 8) v += bb8[n0 + wn * 64 + j * 16 + lce];
          St[(wm * 64 + i * 16 + lr4 + g) * 136 + wn * 64 + j * 16 + lce] = (__bf16)v;
        }
    __syncthreads();
#pragma unroll
    for (int u = 0; u < 8; ++u) {
      int flat = t + 256 * u;
      int row = flat >> 4, c8 = (flat & 15) << 3;
      uint4 val = *(uint4*)&St[row * 136 + c8];
      int pm = m0 + row, pn = n0 + c8;
      if (MODE == 1) {
        int nn = pn;
        int rrel = pm / L_, l = pm - rrel * L_;
        if (nn < 512) {
          int hh = nn >> 6, dh = nn & 63;
          *(uint4*)&O0[(((size_t)(hh * L_ + l)) * Rc + rrel) * 64 + dh] = val;
        } else {
          nn -= 512;
          int hh = nn >> 6, dh = nn & 63;
          *(uint4*)&O1[(((size_t)(hh * L_ + l)) * Rc + rrel) * 64 + dh] = val;
        }
      } else if (MODE == 3) {
        *(uint4*)&O0[((size_t)(h * L_ + pm)) * ((size_t)Rc * 64) + pn] = val;
      } else if (MODE == 6) {
        *(uint4*)&O0[(((size_t)((pm >> 6) * Rc + zr)) * 64 + (pm & 63)) * (size_t)L_ + pn] = val;
      } else {  // MODE 8
        __bf16* dst = pbase ? O1 : O0;
        *(uint4*)&dst[(size_t)(pm - pbase) * 128 + pn] = val;
      }
    }
  } else {
    // ---- fp32 epilogue (modes 2/4/5): 2 half-tiles of 64 rows, float4 ----
    float* Sf = (float*)shm;  // 64 rows, pitch 132 fp32, 33792 B
#pragma unroll
    for (int half = 0; half < 2; ++half) {
      if (half) __syncthreads();
      if (wm == half) {
#pragma unroll
        for (int i = 0; i < 4; ++i)
#pragma unroll
          for (int j = 0; j < 4; ++j)
#pragma unroll
            for (int g = 0; g < 4; ++g)
              Sf[(i * 16 + lr4 + g) * 132 + wn * 64 + j * 16 + lce] = acc[i][j][g];
      }
      __syncthreads();
#pragma unroll
      for (int u = 0; u < 8; ++u) {
        int flat = t + 256 * u;
        int row = flat >> 5, c4 = (flat & 31) << 2;
        float4 v = *(float4*)&Sf[row * 132 + c4];
        int pm = m0 + half * 64 + row, pn = n0 + c4;
        if (MODE == 2) {
          float* ptr = F0 + ((size_t)(s * H_ + h)) * (L_ * L_) + (size_t)pm * L_ + pn;
          v.x *= 0.125f; v.y *= 0.125f; v.z *= 0.125f; v.w *= 0.125f;
          if (firstChunk) {
            *(float4*)ptr = v;
          } else {
            float4 o = *(float4*)ptr;
            o.x += v.x; o.y += v.y; o.z += v.z; o.w += v.w;
            *(float4*)ptr = o;
          }
        } else if (MODE == 4) {
          float4 bv = *(const float4*)&bias[pn];
          int lrel = pm >> 7, rr = pm & 127;
          float4 o;
          o.x = 0.5f * (v.x + bv.x); o.y = 0.5f * (v.y + bv.y);
          o.z = 0.5f * (v.z + bv.z); o.w = 0.5f * (v.w + bv.w);
          *(float4*)&F0[((size_t)(rr * L_ + c0 + lrel)) * 128 + pn] = o;
        } else {  // MODE 5: RMW accumulate into out
          float4 bv = *(const float4*)&bias[pn];
          int rrel = pm / L_, l = pm - rrel * L_;
          float* ptr = F0 + ((size_t)((c0 + rrel) * L_ + l)) * 128 + pn;
          float4 o = *(float4*)ptr;
          o.x += 0.5f * (v.x + bv.x); o.y += 0.5f * (v.y + bv.y);
          o.z += 0.5f * (v.z + bv.z); o.w += 0.5f * (v.w + bv.w);
          *(float4*)ptr = o;
        }
      }
    }
  }
}

// ---------------------------------------------------------------------------
// standalone mm_k wrapper (modes 2/3/4/5/8 + CH>1 fallback for 1/6)
// ---------------------------------------------------------------------------
template <int MODE>
__global__ __launch_bounds__(256) void mm_k(
    const __bf16* __restrict__ A, const __bf16* __restrict__ B,
    const float* __restrict__ bias, const float* __restrict__ tie,
    __bf16* __restrict__ O0, __bf16* __restrict__ O1, __bf16* __restrict__ O2,
    float* __restrict__ F0,
    int K, int c0, int Rc, int KT, int firstChunk, int S) {
  __shared__ __bf16 shm[2 * 128 * 72];
  int n0, m0, h = 0, s = 0, kOff = 0, zr = 0;
  if (MODE == 2) {
    int b = blockIdx.x;
    int xcd = b & 7, t2 = b >> 3;
    int i3 = t2 % 3, slot = t2 / 3;
    int g = xcd * (gridDim.x / 24) + slot;
    n0 = i3 * 128;
    m0 = (g % 3) * 128;
    int z = g / 3;
    h = z / S; s = z % S; kOff = s * K;
  } else if (MODE == 1) {
    const int gx = 8;
    int nb = gx * gridDim.y;
    int bid = blockIdx.y * gx + blockIdx.x;
    int vv = (bid & 7) * (nb >> 3) + (bid >> 3);
    n0 = (vv % gx) * 128;
    m0 = (vv / gx) * 128;
  } else if (MODE == 3) {
    int nwg = gridDim.x, bid = blockIdx.x;
    int vv = (bid & 7) * (nwg >> 3) + (bid >> 3);
    int y = vv % 3; int tt = vv / 3;
    int half = Rc >> 1;
    int nx = tt % half; h = tt / half;
    n0 = nx * 128; m0 = y * 128;
  } else if (MODE == 6) {
    int nwg = gridDim.x, bid = blockIdx.x;
    int vv = (bid & 7) * (nwg >> 3) + (bid >> 3);
    int y = vv & 3; int tt = vv >> 2;
    int x = tt % 3; zr = tt / 3;
    n0 = x * 128; m0 = y * 128;
  } else {
    n0 = blockIdx.x * 128;
    m0 = blockIdx.y * 128;
  }
  mmk_body<MODE>(shm, A, B, bias, tie, O0, O1, O2, F0, K, c0, Rc, KT,
                 firstChunk, S, n0, m0, h, s, kOff, zr);
}

// ---------------------------------------------------------------------------
// FUSED column attention body (round-7 proven): v = remapped block index.
// Needs 26112 bf16 (52224 B) of LDS.
// ---------------------------------------------------------------------------
__device__ __forceinline__ void fattw_body(__bf16* smem,
                                           const __bf16* __restrict__ m_bf,
                                           const __bf16* __restrict__ WTw,
                                           __bf16* __restrict__ ob,
                                           int c0, int v) {
  __bf16* Xs = smem;           // [128][136] proj (17408)
  __bf16* Wg = smem + 17408;   // [64][136]  proj per-group (8704)
  __bf16* Qs = smem;           // [128][72]  attn (9216)
  __bf16* Ks = smem + 9216;    // [128][72]  attn (ends 18432)
  __bf16* Ps = smem;           // [128][136] over Qs+Ks (0..17408)
  __bf16* Vt = smem + 17408;   // [64][136]  over Wg (17408..26112)
  __bf16* Ot = smem;           // [128][72]  after PV

  int lrel = v >> 3, h = v & 7;
  int l = c0 + lrel;
  int t = threadIdx.x;
  const int lane = t & 63, w = t >> 6;
  const int lc = lane & 15, q8 = (lane >> 4) << 3;
  const int lr4 = (lane >> 4) << 2;

  // stage x_l [128][136] (coalesced)
#pragma unroll
  for (int u = 0; u < 8; ++u) {
    int flat = t + 256 * u;
    int row = flat >> 4, c8 = (flat & 15) << 3;
    *(uint4*)&Xs[row * 136 + c8] =
        *(const uint4*)&m_bf[((size_t)(row * L_ + l)) * 128 + c8];
  }

  f32x4 accp[2][12];
#pragma unroll
  for (int i = 0; i < 2; ++i)
#pragma unroll
    for (int j = 0; j < 12; ++j) accp[i][j] = (f32x4){0.f, 0.f, 0.f, 0.f};

  // proj GEMM in 3 qkv groups: stage Wg[64][136] -> 32 MFMAs, full K=128 each
#pragma unroll
  for (int g = 0; g < 3; ++g) {
#pragma unroll
    for (int u = 0; u < 4; ++u) {
      int flat = t + 256 * u;
      int row = flat >> 4, c8 = (flat & 15) << 3;
      *(uint4*)&Wg[row * 136 + c8] =
          *(const uint4*)&WTw[((size_t)(g * 512 + h * 64 + row)) * 128 + c8];
    }
    __syncthreads();
#pragma unroll
    for (int kt = 0; kt < 4; ++kt) {
      bf16x8 a0 = *(const bf16x8*)&Xs[(w * 32 + lc) * 136 + kt * 32 + q8];
      bf16x8 a1 = *(const bf16x8*)&Xs[(w * 32 + 16 + lc) * 136 + kt * 32 + q8];
#pragma unroll
      for (int j = 0; j < 4; ++j) {
        bf16x8 b = *(const bf16x8*)&Wg[(j * 16 + lc) * 136 + kt * 32 + q8];
        accp[0][g * 4 + j] = __builtin_amdgcn_mfma_f32_16x16x32_bf16(a0, b, accp[0][g * 4 + j], 0, 0, 0);
        accp[1][g * 4 + j] = __builtin_amdgcn_mfma_f32_16x16x32_bf16(a1, b, accp[1][g * 4 + j], 0, 0, 0);
      }
    }
    __syncthreads();
  }

  // scatter q/k into attn LDS (v stays in registers)
#pragma unroll
  for (int i = 0; i < 2; ++i)
#pragma unroll
    for (int j = 0; j < 8; ++j)
#pragma unroll
      for (int g = 0; g < 4; ++g) {
        int r_loc = w * 32 + i * 16 + lr4 + g;
        __bf16 val = (__bf16)accp[i][j][g];
        if (j < 4) Qs[r_loc * 72 + j * 16 + lc] = val;
        else Ks[r_loc * 72 + (j - 4) * 16 + lc] = val;
      }
  __syncthreads();

  // QK^T
  f32x4 s[2][8];
#pragma unroll
  for (int i = 0; i < 2; ++i)
#pragma unroll
    for (int n = 0; n < 8; ++n) s[i][n] = (f32x4){0.f, 0.f, 0.f, 0.f};
#pragma unroll
  for (int kt = 0; kt < 2; ++kt) {
    bf16x8 a[2];
#pragma unroll
    for (int i = 0; i < 2; ++i)
      a[i] = *(const bf16x8*)&Qs[(w * 32 + i * 16 + lc) * 72 + kt * 32 + q8];
#pragma unroll
    for (int n = 0; n < 8; ++n) {
      bf16x8 b = *(const bf16x8*)&Ks[(n * 16 + lc) * 72 + kt * 32 + q8];
#pragma unroll
      for (int i = 0; i < 2; ++i)
        s[i][n] = __builtin_amdgcn_mfma_f32_16x16x32_bf16(a[i], b, s[i][n], 0, 0, 0);
    }
  }

  // softmax over 128 cols (4-lane-group reduce across n-frags)
  float linv[2][4];
#pragma unroll
  for (int i = 0; i < 2; ++i) {
#pragma unroll
    for (int g = 0; g < 4; ++g) {
      float mx = -1e30f;
#pragma unroll
      for (int n = 0; n < 8; ++n) mx = fmaxf(mx, s[i][n][g]);
      mx = fmaxf(mx, __shfl_xor(mx, 1, 64));
      mx = fmaxf(mx, __shfl_xor(mx, 2, 64));
      mx = fmaxf(mx, __shfl_xor(mx, 4, 64));
      mx = fmaxf(mx, __shfl_xor(mx, 8, 64));
      float sum = 0.f;
#pragma unroll
      for (int n = 0; n < 8; ++n) {
        float e = __expf(0.125f * (s[i][n][g] - mx));
        s[i][n][g] = e;
        sum += e;
      }
      sum += __shfl_xor(sum, 1, 64);
      sum += __shfl_xor(sum, 2, 64);
      sum += __shfl_xor(sum, 4, 64);
      sum += __shfl_xor(sum, 8, 64);
      linv[i][g] = 1.0f / sum;
    }
  }
  __syncthreads();  // Qs/Ks reads done; Ps/Vt may overlay

  // write Ps (over Qs+Ks) and Vt from registers (b64-packed, 4 r per store)
#pragma unroll
  for (int i = 0; i < 2; ++i)
#pragma unroll
    for (int n = 0; n < 8; ++n)
#pragma unroll
      for (int g = 0; g < 4; ++g)
        Ps[(size_t)(w * 32 + i * 16 + lr4 + g) * 136 + n * 16 + lc] = (__bf16)s[i][n][g];
#pragma unroll
  for (int i = 0; i < 2; ++i)
#pragma unroll
    for (int j = 8; j < 12; ++j) {
      bf16x4 pv;
#pragma unroll
      for (int g = 0; g < 4; ++g) pv[g] = (__bf16)accp[i][j][g];
      *(uint2*)&Vt[(size_t)((j - 8) * 16 + lc) * 136 + w * 32 + i * 16 + lr4] =
          __builtin_bit_cast(uint2, pv);
    }
  __syncthreads();

  // PV
  f32x4 o[2][4];
#pragma unroll
  for (int i = 0; i < 2; ++i)
#pragma unroll
    for (int n = 0; n < 4; ++n) o[i][n] = (f32x4){0.f, 0.f, 0.f, 0.f};
#pragma unroll
  for (int kt = 0; kt < 4; ++kt) {
    bf16x8 a[2];
#pragma unroll
    for (int i = 0; i < 2; ++i)
      a[i] = *(const bf16x8*)&Ps[(w * 32 + i * 16 + lc) * 136 + kt * 32 + q8];
#pragma unroll
    for (int n = 0; n < 4; ++n) {
      bf16x8 b = *(const bf16x8*)&Vt[(n * 16 + lc) * 136 + kt * 32 + q8];
#pragma unroll
      for (int i = 0; i < 2; ++i)
        o[i][n] = __builtin_amdgcn_mfma_f32_16x16x32_bf16(a[i], b, o[i][n], 0, 0, 0);
    }
  }

  // staged, vectorized ob write
  __syncthreads();
#pragma unroll
  for (int i = 0; i < 2; ++i)
#pragma unroll
    for (int n = 0; n < 4; ++n)
#pragma unroll
      for (int g = 0; g < 4; ++g) {
        int r = w * 32 + i * 16 + lr4 + g;
        int dh = n * 16 + lc;
        Ot[r * 72 + dh] = (__bf16)(o[i][n][g] * linv[i][g]);
      }
  __syncthreads();
#pragma unroll
  for (int u = 0; u < 4; ++u) {
    int flat = t + 256 * u;
    int r = flat >> 3, c8 = (flat & 7) << 3;
    uint4 val = *(uint4*)&Ot[r * 72 + c8];
    *(uint4*)&ob[((size_t)(lrel * R_ + r)) * INNER_ + h * 64 + c8] = val;
  }
}

// standalone fattw (CH>1 fallback)
__global__ __launch_bounds__(256, 3) void fattw_kernel(const __bf16* __restrict__ m_bf,
                                                       const __bf16* __restrict__ WTw,
                                                       __bf16* __restrict__ ob, int c0) {
  __shared__ __bf16 smem[26112];
  int bid = blockIdx.x;
  int v = (bid & 7) * (gridDim.x >> 3) + (bid >> 3);
  fattw_body(smem, m_bf, WTw, ob, c0, v);
}

// ---------------------------------------------------------------------------
// MEGA kernel (CH==1): horizontal fusion of fattw (3072) + mm_k<1> (3072) +
// mm_k<6> (1536) = 7680 blocks. Interleaved per 40-block superblock as
// [8 fattw][8 mm1][8 fattw][8 mm1][8 mm6] so all types are co-resident and
// (local_bid & 7) == XCD is preserved for every per-type locality remap.
// LDS 52224 B -> 3 blocks/CU for all branches.
// ---------------------------------------------------------------------------
__global__ __launch_bounds__(256, 3) void mega_kernel(
    const __bf16* __restrict__ m_bf, const __bf16* __restrict__ WTw,
    __bf16* __restrict__ ob_w,
    const __bf16* __restrict__ WThqk, const float* __restrict__ wtie,
    __bf16* __restrict__ qb, __bf16* __restrict__ kb,
    const __bf16* __restrict__ WTvh, __bf16* __restrict__ vb, int Rc) {
  __shared__ __bf16 smem[26112];  // 52224 B
  int gb = blockIdx.x;
  int sb = gb / 40, wb = gb - sb * 40;
  int sub = wb >> 3, xl = wb & 7;
  if (sub == 0 || sub == 2) {
    // fattw: local bid in [0,3072)
    int lbid = sb * 16 + ((sub == 2) ? 8 : 0) + xl;
    int v = (lbid & 7) * (3072 >> 3) + (lbid >> 3);
    fattw_body(smem, m_bf, WTw, ob_w, 0, v);
  } else if (sub == 1 || sub == 3) {
    // mm_k<1>: local bid in [0,3072)
    int lbid = sb * 16 + ((sub == 3) ? 8 : 0) + xl;
    int vv = (lbid & 7) * (3072 >> 3) + (lbid >> 3);
    int n0 = (vv % 8) * 128, m0 = (vv / 8) * 128;
    mmk_body<1>(smem, m_bf, WThqk, nullptr, wtie, qb, kb, nullptr, nullptr,
                128, 0, Rc, 0, 0, 1, n0, m0, 0, 0, 0, 0);
  } else {
    // mm_k<6>: local bid in [0,1536)
    int lbid = sb * 8 + xl;
    int vv = (lbid & 7) * (1536 >> 3) + (lbid >> 3);
    int y = vv & 3, tt = vv >> 2;
    int x = tt % 3, zr = tt / 3;
    mmk_body<6>(smem, WTvh, m_bf, nullptr, nullptr, vb, nullptr, nullptr,
                nullptr, 128, 0, Rc, 0, 0, 1, x * 128, y * 128, 0, 0, 0, zr);
  }
}

// ---------------------------------------------------------------------------
// tie softmax (bf16 inputs)
// ---------------------------------------------------------------------------
__global__ __launch_bounds__(128) void tie_kernel(const __bf16* __restrict__ qs,
                                                  const __bf16* __restrict__ ks,
                                                  float* __restrict__ wtie) {
  int bid = blockIdx.x;
  int l = bid >> 3, h = bid & 7;
  int r = threadIdx.x;
  int wid = r >> 6;
  const __bf16* qp = qs + (size_t)l * 128 + h * 16;
  const __bf16* kp = ks + ((size_t)r * L_ + l) * 128 + h * 16;
  bf16x8 q0 = *(const bf16x8*)qp;
  bf16x8 q1 = *(const bf16x8*)(qp + 8);
  bf16x8 k0 = *(const bf16x8*)kp;
  bf16x8 k1 = *(const bf16x8*)(kp + 8);
  float s = 0.f;
#pragma unroll
  for (int i = 0; i < 8; ++i)
    s += (float)q0[i] * (float)k0[i] + (float)q1[i] * (float)k1[i];
  s *= 0.25f;
  __shared__ float sm[2], ss[2];
  float wm = wred_max(s);
  if ((r & 63) == 0) sm[wid] = wm;
  __syncthreads();
  float mx = fmaxf(sm[0], sm[1]);
  float e = __expf(s - mx);
  float wsum = wred_sum(e);
  if ((r & 63) == 0) ss[wid] = wsum;
  __syncthreads();
  float tot = ss[0] + ss[1];
  wtie[((size_t)l * H_ + h) * R_ + r] = e / tot;
}

// ---------------------------------------------------------------------------
// pair LN + Wpair -> pb[h][i][j]. One THREAD per (i,j); no cross-lane ops.
// ---------------------------------------------------------------------------
__global__ __launch_bounds__(256) void lnpb_kernel(const float* __restrict__ pair,
                                                   const float* __restrict__ g,
                                                   const float* __restrict__ b,
                                                   const float* __restrict__ wp,
                                                   float* __restrict__ pb) {
  __shared__ float gws[1024];
  __shared__ float c1s[8], c2s[8];
  int t = threadIdx.x;
#pragma unroll
  for (int u = 0; u < 4; ++u) {
    int idx = t * 4 + u;
    int d = idx >> 3, h = idx & 7;
    gws[idx] = g[d] * wp[d * 8 + h];
  }
  __syncthreads();
  if (t < 8) {
    float s1 = 0.f, s2 = 0.f;
    for (int d = 0; d < 128; ++d) {
      s1 += gws[d * 8 + t];
      s2 += b[d] * wp[d * 8 + t];
    }
    c1s[t] = s1;
    c2s[t] = s2;
  }
  __syncthreads();
  int pid = blockIdx.x * 256 + t;
  const float4* xp = (const float4*)(pair + (size_t)pid * 128);
  float sum = 0.f, sumsq = 0.f;
  float dots[8] = {};
#pragma unroll 8
  for (int i = 0; i < 32; ++i) {
    float4 v = xp[i];
#pragma unroll
    for (int j = 0; j < 4; ++j) {
      float e = (&v.x)[j];
      sum += e;
      sumsq = fmaf(e, e, sumsq);
      const float* gr = &gws[(i * 4 + j) * 8];
#pragma unroll
      for (int hh = 0; hh < 8; ++hh) dots[hh] = fmaf(e, gr[hh], dots[hh]);
    }
  }
  float mu = sum * (1.0f / 128.0f);
  float var = sumsq * (1.0f / 128.0f) - mu * mu;
  float rs = 1.0f / sqrtf(var + 1e-5f);
#pragma unroll
  for (int hh = 0; hh < 8; ++hh)
    pb[(size_t)hh * (L_ * L_) + pid] = rs * (dots[hh] - mu * c1s[hh]) + c2s[hh];
}

// ---------------------------------------------------------------------------
// softmax over last dim of (pb + sum of S split-K partials) -> attn bf16
// ---------------------------------------------------------------------------
__global__ __launch_bounds__(128) void sm_kernel(const float* __restrict__ pb,
                                                 const float* __restrict__ dp,
                                                 int S, __bf16* __restrict__ ab) {
  size_t row = blockIdx.x;
  int t = threadIdx.x;
  int wid = t >> 6;
  const float* p0 = pb + row * L_;
  float x0 = p0[t], x1 = p0[t + 128], x2 = p0[t + 256];
  const size_t HLL = (size_t)H_ * L_ * L_;
  for (int s = 0; s < S; ++s) {
    const float* ps = dp + s * HLL + row * L_;
    x0 += ps[t]; x1 += ps[t + 128]; x2 += ps[t + 256];
  }
  __shared__ float sm[2], ss[2];
  float m = wred_max(fmaxf(x0, fmaxf(x1, x2)));
  if ((t & 63) == 0) sm[wid] = m;
  __syncthreads();
  m = fmaxf(sm[0], sm[1]);
  float e0 = __expf(x0 - m), e1 = __expf(x1 - m), e2 = __expf(x2 - m);
  float s2 = wred_sum(e0 + e1 + e2);
  if ((t & 63) == 0) ss[wid] = s2;
  __syncthreads();
  float inv = 1.0f / (ss[0] + ss[1]);
  __bf16* op = ab + row * L_;
  op[t] = (__bf16)(e0 * inv);
  op[t + 128] = (__bf16)(e1 * inv);
  op[t + 256] = (__bf16)(e2 * inv);
}

// ---------------------------------------------------------------------------
extern "C" void kernel_launch(void* const* d_in, const int* in_sizes, int n_in,
                              void* d_out, int out_size, void* d_ws,
                              size_t ws_size, hipStream_t stream) {
  (void)in_sizes; (void)n_in; (void)out_size;
  const float* m = (const float*)d_in[0];
  const float* pair = (const float*)d_in[1];
  const float* Wq_w = (const float*)d_in[2];
  const float* Wkv_w = (const float*)d_in[3];
  const float* Wo_w = (const float*)d_in[4];
  const float* bo_w = (const float*)d_in[5];
  const float* Wq_h = (const float*)d_in[6];
  const float* Wkv_h = (const float*)d_in[7];
  const float* Wo_h = (const float*)d_in[8];
  const float* bo_h = (const float*)d_in[9];
  const float* ln_g = (const float*)d_in[10];
  const float* ln_b = (const float*)d_in[11];
  const float* Wpair = (const float*)d_in[12];
  const float* Wsq = (const float*)d_in[13];
  const float* bsq = (const float*)d_in[14];
  const float* Wsk = (const float*)d_in[15];
  const float* bsk = (const float*)d_in[16];
  float* out = (float*)d_out;

  // ---- choose chunking (CH) and split count (S = 8/CH) to fit workspace ----
  const size_t fixedBase = 22446080u;
  int CH = 1;
  for (; CH < 8; CH *= 2) {
    size_t partials = (size_t)(8 / CH) * 4718592u;
    size_t o = 201326592u / CH;
    if (o < 25165824u) o = 25165824u;
    if (fixedBase + partials + o <= ws_size) break;
  }
  const int S = 8 / CH;
  const int Lc = L_ / CH;
  const int Rc = R_ / CH;

  unsigned char* base = (unsigned char*)d_ws;
  __bf16* m_bf = (__bf16*)base;       base += 12582912;
  __bf16* WTw = (__bf16*)base;        base += 393216;
  __bf16* WThqk = (__bf16*)base;      base += 262144;
  __bf16* WTvh = (__bf16*)base;       base += 131072;
  __bf16* WoTw = (__bf16*)base;       base += 131072;
  __bf16* WoTh = (__bf16*)base;       base += 131072;
  __bf16* WskT = (__bf16*)base;       base += 32768;
  __bf16* WsqT = (__bf16*)base;       base += 32768;
  float* wtie = (float*)base;         base += 1572864;
  float* pb = (float*)base;           base += 4718592;
  __bf16* attnb = (__bf16*)base;      base += 2359296;
  __bf16* qsb = (__bf16*)base;        base += 98304;
  float* dotsP = (float*)base;        base += (size_t)S * 4718592u;
  unsigned char* ovl = base;
  __bf16* ksb = (__bf16*)ovl;  // phase A only

  const size_t BUF = 25165824u / CH;
  __bf16* qb = (__bf16*)ovl;
  __bf16* kb = qb + BUF;
  __bf16* vb = kb + BUF;
  __bf16* ob = vb + BUF;

  prep_kernel<<<3208, 256, 0, stream>>>(m, m_bf, Wq_w, Wkv_w, Wq_h, Wkv_h, Wo_w,
                                        Wo_h, Wsk, Wsq, WTw, WThqk, WTvh, WoTw,
                                        WoTh, WskT, WsqT);

  // tie projections (ks rows 0..383 tiles, qs rows 384..386) + softmax + pair bias
  mm_k<8><<<dim3(1, 387), 256, 0, stream>>>(m_bf, WskT, bsk, bsq, ksb, qsb, WsqT,
                                            nullptr, 128, 0, Rc, 0, 0, 1);
  tie_kernel<<<L_ * H_, 128, 0, stream>>>(qsb, ksb, wtie);
  lnpb_kernel<<<(L_ * L_) / 256, 256, 0, stream>>>(pair, ln_g, ln_b, Wpair, pb);

  if (CH == 1) {
    // ---- horizontal fusion: fattw (3072) || mm_k<1> (3072) || mm_k<6> (1536)
    mega_kernel<<<7680, 256, 0, stream>>>(m_bf, WTw, ob, WThqk, wtie, qb, kb,
                                          WTvh, vb, Rc);
    // w-path epilogue (reads ob from fattw)
    mm_k<4><<<dim3(1, L_), 256, 0, stream>>>(ob, WoTw, bo_w, nullptr, nullptr, nullptr,
                                             nullptr, out, 512, 0, Rc, 0, 0, 1);
    // h-path dots (reads qb/kb from mm1)
    mm_k<2><<<9 * H_ * S, 256, 0, stream>>>(qb, kb, nullptr, nullptr, nullptr,
                                            nullptr, nullptr, dotsP,
                                            (Rc * 64) / S, 0, Rc, Rc * 64, 1, S);
    sm_kernel<<<H_ * L_, 128, 0, stream>>>(pb, dotsP, S, attnb);
    // oh (writes ob — after mm_k<4> consumed it)
    mm_k<3><<<12 * Rc, 256, 0, stream>>>(attnb, vb, nullptr, nullptr, ob, nullptr,
                                         nullptr, nullptr, 384, 0, Rc, 0, 0, 1);
    mm_k<5><<<dim3(1, Rc * 3), 256, 0, stream>>>(ob, WoTh, bo_h, nullptr, nullptr, nullptr,
                                                 nullptr, out, 512, 0, Rc, 0, 0, 1);
  } else {
    for (int c = 0; c < CH; ++c) {
      int l0 = c * Lc;
      fattw_kernel<<<Lc * H_, 256, 0, stream>>>(m_bf, WTw, ob, l0);
      mm_k<4><<<dim3(1, Lc), 256, 0, stream>>>(ob, WoTw, bo_w, nullptr, nullptr, nullptr,
                                               nullptr, out, 512, l0, Rc, 0, 0, 1);
    }
    for (int c = 0; c < CH; ++c) {
      int r0 = c * Rc;
      mm_k<1><<<dim3(8, Rc * 3), 256, 0, stream>>>(m_bf, WThqk, nullptr, wtie, qb, kb,
                                                   nullptr, nullptr, 128, r0, Rc, 0, 0, 1);
      mm_k<2><<<9 * H_ * S, 256, 0, stream>>>(qb, kb, nullptr, nullptr, nullptr,
                                              nullptr, nullptr, dotsP,
                                              (Rc * 64) / S, r0, Rc, Rc * 64,
                                              (c == 0) ? 1 : 0, S);
    }
    sm_kernel<<<H_ * L_, 128, 0, stream>>>(pb, dotsP, S, attnb);
    for (int c = 0; c < CH; ++c) {
      int r0 = c * Rc;
      mm_k<6><<<12 * Rc, 256, 0, stream>>>(WTvh, m_bf, nullptr, nullptr, vb, nullptr,
                                           nullptr, nullptr, 128, r0, Rc, 0, 0, 1);
      mm_k<3><<<12 * Rc, 256, 0, stream>>>(attnb, vb, nullptr, nullptr, ob, nullptr,
                                           nullptr, nullptr, 384, r0, Rc, 0, 0, 1);
      mm_k<5><<<dim3(1, Rc * 3), 256, 0, stream>>>(ob, WoTh, bo_h, nullptr, nullptr, nullptr,
                                                   nullptr, out, 512, r0, Rc, 0, 0, 1);
    }
  }
}

// Round 13
// 420.845 us; speedup vs baseline: 1.1424x; 1.0760x over previous
//
#include <hip/hip_runtime.h>
#include <math.h>

#define L_ 384
#define R_ 128
#define D_ 128
#define H_ 8
#define DH_ 64
#define INNER_ 512

typedef __bf16 bf16x8 __attribute__((ext_vector_type(8)));
typedef __bf16 bf16x4 __attribute__((ext_vector_type(4)));
typedef float f32x4 __attribute__((ext_vector_type(4)));

__device__ __forceinline__ float wred_sum(float v) {
#pragma unroll
  for (int o = 32; o > 0; o >>= 1) v += __shfl_xor(v, o, 64);
  return v;
}
__device__ __forceinline__ float wred_max(float v) {
#pragma unroll
  for (int o = 32; o > 0; o >>= 1) v = fmaxf(v, __shfl_xor(v, o, 64));
  return v;
}

// ---------------------------------------------------------------------------
// prep: m fp32->bf16 (blocks 0..3071) + all weight transposes (blocks 3072..3207)
// ---------------------------------------------------------------------------
__global__ __launch_bounds__(256) void prep_kernel(
    const float* __restrict__ m, __bf16* __restrict__ m_bf,
    const float* __restrict__ Wq_w, const float* __restrict__ Wkv_w,
    const float* __restrict__ Wq_h, const float* __restrict__ Wkv_h,
    const float* __restrict__ Wo_w, const float* __restrict__ Wo_h,
    const float* __restrict__ Wsk, const float* __restrict__ Wsq,
    __bf16* __restrict__ WTw, __bf16* __restrict__ WThqk,
    __bf16* __restrict__ WTvh, __bf16* __restrict__ WoTw,
    __bf16* __restrict__ WoTh, __bf16* __restrict__ WskT,
    __bf16* __restrict__ WsqT) {
  __shared__ float Ls[64 * 65];
  int b = blockIdx.x;
  int t = threadIdx.x;
  if (b < 3072) {
    int i = b * 256 + t;
    float4 a = *(const float4*)(m + (size_t)i * 8);
    float4 c = *(const float4*)(m + (size_t)i * 8 + 4);
    bf16x8 o;
    o[0] = (__bf16)a.x; o[1] = (__bf16)a.y; o[2] = (__bf16)a.z; o[3] = (__bf16)a.w;
    o[4] = (__bf16)c.x; o[5] = (__bf16)c.y; o[6] = (__bf16)c.z; o[7] = (__bf16)c.w;
    *(uint4*)(m_bf + (size_t)i * 8) = __builtin_bit_cast(uint4, o);
    return;
  }
  int j = b - 3072;
  const float* src; __bf16* dst; int Kd, Ns, noff, gx, base;
  if (j < 16)       { src = Wq_w;  dst = WTw;             Kd = 128; Ns = 512;  noff = 0;   gx = 8;  base = 0; }
  else if (j < 48)  { src = Wkv_w; dst = WTw + 512 * 128; Kd = 128; Ns = 1024; noff = 0;   gx = 16; base = 16; }
  else if (j < 64)  { src = Wq_h;  dst = WThqk;           Kd = 128; Ns = 512;  noff = 0;   gx = 8;  base = 48; }
  else if (j < 80)  { src = Wkv_h; dst = WThqk + 512 * 128; Kd = 128; Ns = 1024; noff = 0; gx = 8;  base = 64; }
  else if (j < 96)  { src = Wkv_h; dst = WTvh;            Kd = 128; Ns = 1024; noff = 512; gx = 8;  base = 80; }
  else if (j < 112) { src = Wo_w;  dst = WoTw;            Kd = 512; Ns = 128;  noff = 0;   gx = 2;  base = 96; }
  else if (j < 128) { src = Wo_h;  dst = WoTh;            Kd = 512; Ns = 128;  noff = 0;   gx = 2;  base = 112; }
  else if (j < 132) { src = Wsk;   dst = WskT;            Kd = 128; Ns = 128;  noff = 0;   gx = 2;  base = 128; }
  else              { src = Wsq;   dst = WsqT;            Kd = 128; Ns = 128;  noff = 0;   gx = 2;  base = 132; }
  int jl = j - base;
  int n0 = (jl % gx) * 64, k0 = (jl / gx) * 64;
#pragma unroll
  for (int u = 0; u < 4; ++u) {
    int flat = t + 256 * u;
    int kr = flat >> 4, nc = (flat & 15) * 4;
    float4 v = *(const float4*)&src[(size_t)(k0 + kr) * Ns + noff + n0 + nc];
    Ls[kr * 65 + nc + 0] = v.x;
    Ls[kr * 65 + nc + 1] = v.y;
    Ls[kr * 65 + nc + 2] = v.z;
    Ls[kr * 65 + nc + 3] = v.w;
  }
  __syncthreads();
#pragma unroll
  for (int u = 0; u < 2; ++u) {
    int flat = t + 256 * u;
    int nr = flat >> 3, kc = (flat & 7) * 8;
    bf16x8 o;
#pragma unroll
    for (int q = 0; q < 8; ++q) o[q] = (__bf16)Ls[(kc + q) * 65 + nr];
    *(uint4*)&dst[(size_t)(n0 + nr) * Kd + k0 + kc] = __builtin_bit_cast(uint4, o);
  }
}

// ---------------------------------------------------------------------------
// Shared GEMM body: bf16 MFMA, 128x128 tile, BK=64, 4 waves 2x2, 16x16x32.
// Caller computes n0/m0/h/s/kOff/zr. Needs >= 36864 B of LDS at shm.
// ---------------------------------------------------------------------------
template <int MODE>
__device__ __forceinline__ void mmk_body(
    __bf16* shm,
    const __bf16* __restrict__ A, const __bf16* __restrict__ B,
    const float* __restrict__ bias, const float* __restrict__ tie,
    __bf16* __restrict__ O0, __bf16* __restrict__ O1, __bf16* __restrict__ O2,
    float* __restrict__ F0,
    int K, int c0, int Rc, int KT, int firstChunk, int S,
    int n0, int m0, int h, int s, int kOff, int zr) {
  __bf16* As = shm;
  __bf16* Bs = shm + 128 * 72;
  const int t = threadIdx.x;
  const int lane = t & 63, w = t >> 6;
  const int wm = w >> 1, wn = w & 1;
  const int pbase = (MODE == 8 && m0 >= 49152) ? 49152 : 0;
  const __bf16* Bmat = (MODE == 8 && pbase) ? (const __bf16*)O2 : B;

  f32x4 acc[4][4];
#pragma unroll
  for (int i = 0; i < 4; ++i)
#pragma unroll
    for (int j = 0; j < 4; ++j) acc[i][j] = (f32x4){0.f, 0.f, 0.f, 0.f};

  for (int k0 = 0; k0 < K; k0 += 64) {
#pragma unroll
    for (int u = 0; u < 4; ++u) {
      int flat = t + 256 * u;
      int row = flat >> 3;
      int c8 = (flat & 7) << 3;
      const __bf16* ap;
      int p = m0 + row;
      if (MODE == 1) ap = A + ((size_t)(c0 * L_ + p)) * 128 + k0 + c8;
      else if (MODE == 2) ap = A + ((size_t)(h * L_ + p)) * KT + kOff + k0 + c8;
      else if (MODE == 3) ap = A + ((size_t)(h * L_ + p)) * L_ + k0 + c8;
      else if (MODE == 4) ap = A + (size_t)p * INNER_ + k0 + c8;
      else if (MODE == 5) { int rrel = p / L_, l = p - rrel * L_;
        ap = A + (((size_t)((k0 >> 6) * L_ + l)) * Rc + rrel) * 64 + c8; }
      else if (MODE == 8) ap = A + (size_t)(p - pbase) * 128 + k0 + c8;
      else ap = A + (size_t)p * 128 + k0 + c8;
      *(uint4*)&As[row * 72 + c8] = *(const uint4*)ap;
      const __bf16* bp;
      int n = n0 + row;
      if (MODE == 1 || MODE == 8) bp = Bmat + (size_t)n * 128 + k0 + c8;
      else if (MODE == 2) bp = B + ((size_t)(h * L_ + n)) * KT + kOff + k0 + c8;
      else if (MODE == 3) bp = B + ((size_t)(h * Rc * 64 + n)) * L_ + k0 + c8;
      else if (MODE == 4 || MODE == 5) bp = B + (size_t)n * INNER_ + k0 + c8;
      else bp = B + ((size_t)((c0 + zr) * L_ + n)) * 128 + k0 + c8;
      *(uint4*)&Bs[row * 72 + c8] = *(const uint4*)bp;
    }
    __syncthreads();
    {
      int lc = lane & 15, q8 = (lane >> 4) << 3;
#pragma unroll
      for (int kt = 0; kt < 2; ++kt) {
        bf16x8 af[4], bfr[4];
#pragma unroll
        for (int i = 0; i < 4; ++i) {
          af[i] = *(const bf16x8*)&As[(wm * 64 + i * 16 + lc) * 72 + kt * 32 + q8];
          bfr[i] = *(const bf16x8*)&Bs[(wn * 64 + i * 16 + lc) * 72 + kt * 32 + q8];
        }
#pragma unroll
        for (int i = 0; i < 4; ++i)
#pragma unroll
          for (int j = 0; j < 4; ++j)
            acc[i][j] = __builtin_amdgcn_mfma_f32_16x16x32_bf16(af[i], bfr[j], acc[i][j], 0, 0, 0);
      }
    }
    __syncthreads();
  }

  const int lce = lane & 15, lr4 = (lane >> 4) << 2;

  // MODE 1 (qh blocks): stage the 256 tie weights into LDS, pull into regs.
  float tw[4][4];
  if (MODE == 1 && n0 < 512) {
    float* tieS = (float*)shm;  // safe: all LDS reads done (barrier above)
    int row = t >> 1, hh2 = t & 1;
    int pmt = m0 + row;
    int rrelt = pmt / L_, lt = pmt - rrelt * L_;
    int h0 = n0 >> 6;
    tieS[row * 2 + hh2] = tie[((size_t)(lt * H_ + h0 + hh2)) * R_ + c0 + rrelt];
    __syncthreads();
#pragma unroll
    for (int i = 0; i < 4; ++i)
#pragma unroll
      for (int g = 0; g < 4; ++g)
        tw[i][g] = tieS[(wm * 64 + i * 16 + lr4 + g) * 2 + wn];
    __syncthreads();
  }

  if (MODE == 1 || MODE == 3 || MODE == 6 || MODE == 8) {
    // ---- bf16 epilogue: stage full 128x128 tile, store uint4 (8 bf16) ----
    __bf16* St = shm;  // pitch 136 bf16, 34816 B
    const float* bb8 = (MODE == 8) ? (pbase ? tie : bias) : nullptr;
#pragma unroll
    for (int i = 0; i < 4; ++i)
#pragma unroll
      for (int j = 0; j < 4; ++j)
#pragma unroll
        for (int g = 0; g < 4; ++g) {
          float v = acc[i][j][g];
          if (MODE == 1 && n0 < 512) v *= tw[i][g];
          if (MODE == 8) v += bb8[n0 + wn * 64 + j * 16 + lce];
          St[(wm * 64 + i * 16 + lr4 + g) * 136 + wn * 64 + j * 16 + lce] = (__bf16)v;
        }
    __syncthreads();
#pragma unroll
    for (int u = 0; u < 8; ++u) {
      int flat = t + 256 * u;
      int row = flat >> 4, c8 = (flat & 15) << 3;
      uint4 val = *(uint4*)&St[row * 136 + c8];
      int pm = m0 + row, pn = n0 + c8;
      if (MODE == 1) {
        int nn = pn;
        int rrel = pm / L_, l = pm - rrel * L_;
        if (nn < 512) {
          int hh = nn >> 6, dh = nn & 63;
          *(uint4*)&O0[(((size_t)(hh * L_ + l)) * Rc + rrel) * 64 + dh] = val;
        } else {
          nn -= 512;
          int hh = nn >> 6, dh = nn & 63;
          *(uint4*)&O1[(((size_t)(hh * L_ + l)) * Rc + rrel) * 64 + dh] = val;
        }
      } else if (MODE == 3) {
        *(uint4*)&O0[((size_t)(h * L_ + pm)) * ((size_t)Rc * 64) + pn] = val;
      } else if (MODE == 6) {
        *(uint4*)&O0[(((size_t)((pm >> 6) * Rc + zr)) * 64 + (pm & 63)) * (size_t)L_ + pn] = val;
      } else {  // MODE 8
        __bf16* dst = pbase ? O1 : O0;
        *(uint4*)&dst[(size_t)(pm - pbase) * 128 + pn] = val;
      }
    }
  } else {
    // ---- fp32 epilogue (modes 2/4/5): 2 half-tiles of 64 rows, float4 ----
    float* Sf = (float*)shm;  // 64 rows, pitch 132 fp32, 33792 B
#pragma unroll
    for (int half = 0; half < 2; ++half) {
      if (half) __syncthreads();
      if (wm == half) {
#pragma unroll
        for (int i = 0; i < 4; ++i)
#pragma unroll
          for (int j = 0; j < 4; ++j)
#pragma unroll
            for (int g = 0; g < 4; ++g)
              Sf[(i * 16 + lr4 + g) * 132 + wn * 64 + j * 16 + lce] = acc[i][j][g];
      }
      __syncthreads();
#pragma unroll
      for (int u = 0; u < 8; ++u) {
        int flat = t + 256 * u;
        int row = flat >> 5, c4 = (flat & 31) << 2;
        float4 v = *(float4*)&Sf[row * 132 + c4];
        int pm = m0 + half * 64 + row, pn = n0 + c4;
        if (MODE == 2) {
          float* ptr = F0 + ((size_t)(s * H_ + h)) * (L_ * L_) + (size_t)pm * L_ + pn;
          v.x *= 0.125f; v.y *= 0.125f; v.z *= 0.125f; v.w *= 0.125f;
          if (firstChunk) {
            *(float4*)ptr = v;
          } else {
            float4 o = *(float4*)ptr;
            o.x += v.x; o.y += v.y; o.z += v.z; o.w += v.w;
            *(float4*)ptr = o;
          }
        } else if (MODE == 4) {
          float4 bv = *(const float4*)&bias[pn];
          int lrel = pm >> 7, rr = pm & 127;
          float4 o;
          o.x = 0.5f * (v.x + bv.x); o.y = 0.5f * (v.y + bv.y);
          o.z = 0.5f * (v.z + bv.z); o.w = 0.5f * (v.w + bv.w);
          *(float4*)&F0[((size_t)(rr * L_ + c0 + lrel)) * 128 + pn] = o;
        } else {  // MODE 5: RMW accumulate into out
          float4 bv = *(const float4*)&bias[pn];
          int rrel = pm / L_, l = pm - rrel * L_;
          float* ptr = F0 + ((size_t)((c0 + rrel) * L_ + l)) * 128 + pn;
          float4 o = *(float4*)ptr;
          o.x += 0.5f * (v.x + bv.x); o.y += 0.5f * (v.y + bv.y);
          o.z += 0.5f * (v.z + bv.z); o.w += 0.5f * (v.w + bv.w);
          *(float4*)ptr = o;
        }
      }
    }
  }
}

// ---------------------------------------------------------------------------
// standalone mm_k wrapper
// ---------------------------------------------------------------------------
template <int MODE>
__global__ __launch_bounds__(256) void mm_k(
    const __bf16* __restrict__ A, const __bf16* __restrict__ B,
    const float* __restrict__ bias, const float* __restrict__ tie,
    __bf16* __restrict__ O0, __bf16* __restrict__ O1, __bf16* __restrict__ O2,
    float* __restrict__ F0,
    int K, int c0, int Rc, int KT, int firstChunk, int S) {
  __shared__ __bf16 shm[2 * 128 * 72];
  int n0, m0, h = 0, s = 0, kOff = 0, zr = 0;
  if (MODE == 2) {
    int b = blockIdx.x;
    int xcd = b & 7, t2 = b >> 3;
    int i3 = t2 % 3, slot = t2 / 3;
    int g = xcd * (gridDim.x / 24) + slot;
    n0 = i3 * 128;
    m0 = (g % 3) * 128;
    int z = g / 3;
    h = z / S; s = z % S; kOff = s * K;
  } else if (MODE == 1) {
    const int gx = 8;
    int nb = gx * gridDim.y;
    int bid = blockIdx.y * gx + blockIdx.x;
    int vv = (bid & 7) * (nb >> 3) + (bid >> 3);
    n0 = (vv % gx) * 128;
    m0 = (vv / gx) * 128;
  } else if (MODE == 3) {
    int nwg = gridDim.x, bid = blockIdx.x;
    int vv = (bid & 7) * (nwg >> 3) + (bid >> 3);
    int y = vv % 3; int tt = vv / 3;
    int half = Rc >> 1;
    int nx = tt % half; h = tt / half;
    n0 = nx * 128; m0 = y * 128;
  } else if (MODE == 6) {
    int nwg = gridDim.x, bid = blockIdx.x;
    int vv = (bid & 7) * (nwg >> 3) + (bid >> 3);
    int y = vv & 3; int tt = vv >> 2;
    int x = tt % 3; zr = tt / 3;
    n0 = x * 128; m0 = y * 128;
  } else {
    n0 = blockIdx.x * 128;
    m0 = blockIdx.y * 128;
  }
  mmk_body<MODE>(shm, A, B, bias, tie, O0, O1, O2, F0, K, c0, Rc, KT,
                 firstChunk, S, n0, m0, h, s, kOff, zr);
}

// ---------------------------------------------------------------------------
// FUSED column attention body (round-7 proven): v = remapped block index.
// Needs 26112 bf16 (52224 B) of LDS.
// ---------------------------------------------------------------------------
__device__ __forceinline__ void fattw_body(__bf16* smem,
                                           const __bf16* __restrict__ m_bf,
                                           const __bf16* __restrict__ WTw,
                                           __bf16* __restrict__ ob,
                                           int c0, int v) {
  __bf16* Xs = smem;           // [128][136] proj (17408)
  __bf16* Wg = smem + 17408;   // [64][136]  proj per-group (8704)
  __bf16* Qs = smem;           // [128][72]  attn (9216)
  __bf16* Ks = smem + 9216;    // [128][72]  attn (ends 18432)
  __bf16* Ps = smem;           // [128][136] over Qs+Ks (0..17408)
  __bf16* Vt = smem + 17408;   // [64][136]  over Wg (17408..26112)
  __bf16* Ot = smem;           // [128][72]  after PV

  int lrel = v >> 3, h = v & 7;
  int l = c0 + lrel;
  int t = threadIdx.x;
  const int lane = t & 63, w = t >> 6;
  const int lc = lane & 15, q8 = (lane >> 4) << 3;
  const int lr4 = (lane >> 4) << 2;

  // stage x_l [128][136] (coalesced)
#pragma unroll
  for (int u = 0; u < 8; ++u) {
    int flat = t + 256 * u;
    int row = flat >> 4, c8 = (flat & 15) << 3;
    *(uint4*)&Xs[row * 136 + c8] =
        *(const uint4*)&m_bf[((size_t)(row * L_ + l)) * 128 + c8];
  }

  f32x4 accp[2][12];
#pragma unroll
  for (int i = 0; i < 2; ++i)
#pragma unroll
    for (int j = 0; j < 12; ++j) accp[i][j] = (f32x4){0.f, 0.f, 0.f, 0.f};

  // proj GEMM in 3 qkv groups: stage Wg[64][136] -> 32 MFMAs, full K=128 each
#pragma unroll
  for (int g = 0; g < 3; ++g) {
#pragma unroll
    for (int u = 0; u < 4; ++u) {
      int flat = t + 256 * u;
      int row = flat >> 4, c8 = (flat & 15) << 3;
      *(uint4*)&Wg[row * 136 + c8] =
          *(const uint4*)&WTw[((size_t)(g * 512 + h * 64 + row)) * 128 + c8];
    }
    __syncthreads();
#pragma unroll
    for (int kt = 0; kt < 4; ++kt) {
      bf16x8 a0 = *(const bf16x8*)&Xs[(w * 32 + lc) * 136 + kt * 32 + q8];
      bf16x8 a1 = *(const bf16x8*)&Xs[(w * 32 + 16 + lc) * 136 + kt * 32 + q8];
#pragma unroll
      for (int j = 0; j < 4; ++j) {
        bf16x8 b = *(const bf16x8*)&Wg[(j * 16 + lc) * 136 + kt * 32 + q8];
        accp[0][g * 4 + j] = __builtin_amdgcn_mfma_f32_16x16x32_bf16(a0, b, accp[0][g * 4 + j], 0, 0, 0);
        accp[1][g * 4 + j] = __builtin_amdgcn_mfma_f32_16x16x32_bf16(a1, b, accp[1][g * 4 + j], 0, 0, 0);
      }
    }
    __syncthreads();
  }

  // scatter q/k into attn LDS (v stays in registers)
#pragma unroll
  for (int i = 0; i < 2; ++i)
#pragma unroll
    for (int j = 0; j < 8; ++j)
#pragma unroll
      for (int g = 0; g < 4; ++g) {
        int r_loc = w * 32 + i * 16 + lr4 + g;
        __bf16 val = (__bf16)accp[i][j][g];
        if (j < 4) Qs[r_loc * 72 + j * 16 + lc] = val;
        else Ks[r_loc * 72 + (j - 4) * 16 + lc] = val;
      }
  __syncthreads();

  // QK^T
  f32x4 s[2][8];
#pragma unroll
  for (int i = 0; i < 2; ++i)
#pragma unroll
    for (int n = 0; n < 8; ++n) s[i][n] = (f32x4){0.f, 0.f, 0.f, 0.f};
#pragma unroll
  for (int kt = 0; kt < 2; ++kt) {
    bf16x8 a[2];
#pragma unroll
    for (int i = 0; i < 2; ++i)
      a[i] = *(const bf16x8*)&Qs[(w * 32 + i * 16 + lc) * 72 + kt * 32 + q8];
#pragma unroll
    for (int n = 0; n < 8; ++n) {
      bf16x8 b = *(const bf16x8*)&Ks[(n * 16 + lc) * 72 + kt * 32 + q8];
#pragma unroll
      for (int i = 0; i < 2; ++i)
        s[i][n] = __builtin_amdgcn_mfma_f32_16x16x32_bf16(a[i], b, s[i][n], 0, 0, 0);
    }
  }

  // softmax over 128 cols (4-lane-group reduce across n-frags)
  float linv[2][4];
#pragma unroll
  for (int i = 0; i < 2; ++i) {
#pragma unroll
    for (int g = 0; g < 4; ++g) {
      float mx = -1e30f;
#pragma unroll
      for (int n = 0; n < 8; ++n) mx = fmaxf(mx, s[i][n][g]);
      mx = fmaxf(mx, __shfl_xor(mx, 1, 64));
      mx = fmaxf(mx, __shfl_xor(mx, 2, 64));
      mx = fmaxf(mx, __shfl_xor(mx, 4, 64));
      mx = fmaxf(mx, __shfl_xor(mx, 8, 64));
      float sum = 0.f;
#pragma unroll
      for (int n = 0; n < 8; ++n) {
        float e = __expf(0.125f * (s[i][n][g] - mx));
        s[i][n][g] = e;
        sum += e;
      }
      sum += __shfl_xor(sum, 1, 64);
      sum += __shfl_xor(sum, 2, 64);
      sum += __shfl_xor(sum, 4, 64);
      sum += __shfl_xor(sum, 8, 64);
      linv[i][g] = 1.0f / sum;
    }
  }
  __syncthreads();  // Qs/Ks reads done; Ps/Vt may overlay

  // write Ps (over Qs+Ks) and Vt from registers (b64-packed, 4 r per store)
#pragma unroll
  for (int i = 0; i < 2; ++i)
#pragma unroll
    for (int n = 0; n < 8; ++n)
#pragma unroll
      for (int g = 0; g < 4; ++g)
        Ps[(size_t)(w * 32 + i * 16 + lr4 + g) * 136 + n * 16 + lc] = (__bf16)s[i][n][g];
#pragma unroll
  for (int i = 0; i < 2; ++i)
#pragma unroll
    for (int j = 8; j < 12; ++j) {
      bf16x4 pv;
#pragma unroll
      for (int g = 0; g < 4; ++g) pv[g] = (__bf16)accp[i][j][g];
      *(uint2*)&Vt[(size_t)((j - 8) * 16 + lc) * 136 + w * 32 + i * 16 + lr4] =
          __builtin_bit_cast(uint2, pv);
    }
  __syncthreads();

  // PV
  f32x4 o[2][4];
#pragma unroll
  for (int i = 0; i < 2; ++i)
#pragma unroll
    for (int n = 0; n < 4; ++n) o[i][n] = (f32x4){0.f, 0.f, 0.f, 0.f};
#pragma unroll
  for (int kt = 0; kt < 4; ++kt) {
    bf16x8 a[2];
#pragma unroll
    for (int i = 0; i < 2; ++i)
      a[i] = *(const bf16x8*)&Ps[(w * 32 + i * 16 + lc) * 136 + kt * 32 + q8];
#pragma unroll
    for (int n = 0; n < 4; ++n) {
      bf16x8 b = *(const bf16x8*)&Vt[(n * 16 + lc) * 136 + kt * 32 + q8];
#pragma unroll
      for (int i = 0; i < 2; ++i)
        o[i][n] = __builtin_amdgcn_mfma_f32_16x16x32_bf16(a[i], b, o[i][n], 0, 0, 0);
    }
  }

  // staged, vectorized ob write
  __syncthreads();
#pragma unroll
  for (int i = 0; i < 2; ++i)
#pragma unroll
    for (int n = 0; n < 4; ++n)
#pragma unroll
      for (int g = 0; g < 4; ++g) {
        int r = w * 32 + i * 16 + lr4 + g;
        int dh = n * 16 + lc;
        Ot[r * 72 + dh] = (__bf16)(o[i][n][g] * linv[i][g]);
      }
  __syncthreads();
#pragma unroll
  for (int u = 0; u < 4; ++u) {
    int flat = t + 256 * u;
    int r = flat >> 3, c8 = (flat & 7) << 3;
    uint4 val = *(uint4*)&Ot[r * 72 + c8];
    *(uint4*)&ob[((size_t)(lrel * R_ + r)) * INNER_ + h * 64 + c8] = val;
  }
}

// standalone fattw (CH>1 fallback)
__global__ __launch_bounds__(256, 3) void fattw_kernel(const __bf16* __restrict__ m_bf,
                                                       const __bf16* __restrict__ WTw,
                                                       __bf16* __restrict__ ob, int c0) {
  __shared__ __bf16 smem[26112];
  int bid = blockIdx.x;
  int v = (bid & 7) * (gridDim.x >> 3) + (bid >> 3);
  fattw_body(smem, m_bf, WTw, ob, c0, v);
}

// ---------------------------------------------------------------------------
// pair LN + Wpair body (576 blocks of 256 threads). Needs 4160 B of LDS.
// ---------------------------------------------------------------------------
__device__ __forceinline__ void lnpb_body(float* smem_f,
                                          const float* __restrict__ pair,
                                          const float* __restrict__ g,
                                          const float* __restrict__ b,
                                          const float* __restrict__ wp,
                                          float* __restrict__ pb, int lbid) {
  float* gws = smem_f;          // [1024]
  float* c1s = smem_f + 1024;   // [8]
  float* c2s = smem_f + 1032;   // [8]
  int t = threadIdx.x;
#pragma unroll
  for (int u = 0; u < 4; ++u) {
    int idx = t * 4 + u;
    int d = idx >> 3, h = idx & 7;
    gws[idx] = g[d] * wp[d * 8 + h];
  }
  __syncthreads();
  if (t < 8) {
    float s1 = 0.f, s2 = 0.f;
    for (int d = 0; d < 128; ++d) {
      s1 += gws[d * 8 + t];
      s2 += b[d] * wp[d * 8 + t];
    }
    c1s[t] = s1;
    c2s[t] = s2;
  }
  __syncthreads();
  int pid = lbid * 256 + t;
  const float4* xp = (const float4*)(pair + (size_t)pid * 128);
  float sum = 0.f, sumsq = 0.f;
  float dots[8] = {};
#pragma unroll 8
  for (int i = 0; i < 32; ++i) {
    float4 v = xp[i];
#pragma unroll
    for (int j = 0; j < 4; ++j) {
      float e = (&v.x)[j];
      sum += e;
      sumsq = fmaf(e, e, sumsq);
      const float* gr = &gws[(i * 4 + j) * 8];
#pragma unroll
      for (int hh = 0; hh < 8; ++hh) dots[hh] = fmaf(e, gr[hh], dots[hh]);
    }
  }
  float mu = sum * (1.0f / 128.0f);
  float var = sumsq * (1.0f / 128.0f) - mu * mu;
  float rs = 1.0f / sqrtf(var + 1e-5f);
#pragma unroll
  for (int hh = 0; hh < 8; ++hh)
    pb[(size_t)hh * (L_ * L_) + pid] = rs * (dots[hh] - mu * c1s[hh]) + c2s[hh];
}

__global__ __launch_bounds__(256) void lnpb_kernel(const float* __restrict__ pair,
                                                   const float* __restrict__ g,
                                                   const float* __restrict__ b,
                                                   const float* __restrict__ wp,
                                                   float* __restrict__ pb) {
  __shared__ float smem_f[1040];
  lnpb_body(smem_f, pair, g, b, wp, pb, blockIdx.x);
}

// ---------------------------------------------------------------------------
// MEGA1 (CH==1): fattw (3072) || mm_k<1> (3072) || mm_k<6> (1536) in 40-block
// superblocks [8 fattw][8 mm1][8 fattw][8 mm1][8 mm6] (blocks 0..7679), plus
// lnpb (576) appended as blocks 7680..8255 (fills tail drain; no XCD needs).
// LDS 52224 B -> 3 blocks/CU.
// ---------------------------------------------------------------------------
__global__ __launch_bounds__(256, 3) void mega_kernel(
    const __bf16* __restrict__ m_bf, const __bf16* __restrict__ WTw,
    __bf16* __restrict__ ob_w,
    const __bf16* __restrict__ WThqk, const float* __restrict__ wtie,
    __bf16* __restrict__ qb, __bf16* __restrict__ kb,
    const __bf16* __restrict__ WTvh, __bf16* __restrict__ vb, int Rc,
    const float* __restrict__ pair, const float* __restrict__ ln_g,
    const float* __restrict__ ln_b, const float* __restrict__ Wpair,
    float* __restrict__ pb) {
  __shared__ __bf16 smem[26112];  // 52224 B
  int gb = blockIdx.x;
  if (gb >= 7680) {
    lnpb_body((float*)smem, pair, ln_g, ln_b, Wpair, pb, gb - 7680);
    return;
  }
  int sb = gb / 40, wb = gb - sb * 40;
  int sub = wb >> 3, xl = wb & 7;
  if (sub == 0 || sub == 2) {
    int lbid = sb * 16 + ((sub == 2) ? 8 : 0) + xl;
    int v = (lbid & 7) * (3072 >> 3) + (lbid >> 3);
    fattw_body(smem, m_bf, WTw, ob_w, 0, v);
  } else if (sub == 1 || sub == 3) {
    int lbid = sb * 16 + ((sub == 3) ? 8 : 0) + xl;
    int vv = (lbid & 7) * (3072 >> 3) + (lbid >> 3);
    int n0 = (vv % 8) * 128, m0 = (vv / 8) * 128;
    mmk_body<1>(smem, m_bf, WThqk, nullptr, wtie, qb, kb, nullptr, nullptr,
                128, 0, Rc, 0, 0, 1, n0, m0, 0, 0, 0, 0);
  } else {
    int lbid = sb * 8 + xl;
    int vv = (lbid & 7) * (1536 >> 3) + (lbid >> 3);
    int y = vv & 3, tt = vv >> 2;
    int x = tt % 3, zr = tt / 3;
    mmk_body<6>(smem, WTvh, m_bf, nullptr, nullptr, vb, nullptr, nullptr,
                nullptr, 128, 0, Rc, 0, 0, 1, x * 128, y * 128, 0, 0, 0, zr);
  }
}

// ---------------------------------------------------------------------------
// MEGA2 (CH==1): mm_k<4> (384) || mm_k<2> (576) = 960 blocks, 24 superblocks
// of 40: [8 mm4][8 mm2][8 mm4][8 mm2][8 mm2]. Each 8-run is 8-aligned so
// mm2's XCD split-K decode carries over (nwg2=576, nwg2/24=24).
// ---------------------------------------------------------------------------
__global__ __launch_bounds__(256) void mega2_kernel(
    const __bf16* __restrict__ ob, const __bf16* __restrict__ WoTw,
    const float* __restrict__ bo_w, float* __restrict__ out,
    const __bf16* __restrict__ qb, const __bf16* __restrict__ kb,
    float* __restrict__ dotsP, int Rc, int S) {
  __shared__ __bf16 shm[2 * 128 * 72];
  int gb = blockIdx.x;
  int sb = gb / 40, wb = gb - sb * 40;
  int sub = wb >> 3, xl = wb & 7;
  if (sub == 0 || sub == 2) {
    // mm_k<4>: lbid in [0,384)
    int lbid = sb * 16 + ((sub == 2) ? 8 : 0) + xl;
    mmk_body<4>(shm, ob, WoTw, bo_w, nullptr, nullptr, nullptr, nullptr, out,
                512, 0, Rc, 0, 0, 1, 0, lbid * 128, 0, 0, 0, 0);
  } else {
    // mm_k<2>: lbid in [0,576)
    int gidx = (sub == 1) ? 0 : (sub == 3) ? 1 : 2;
    int lbid = sb * 24 + gidx * 8 + xl;
    int xcd = lbid & 7, t2 = lbid >> 3;
    int i3 = t2 % 3, slot = t2 / 3;
    int g = xcd * 24 + slot;
    int n0 = i3 * 128;
    int m0 = (g % 3) * 128;
    int z = g / 3;
    int h = z / S, s = z % S;
    int K = (Rc * 64) / S;
    mmk_body<2>(shm, qb, kb, nullptr, nullptr, nullptr, nullptr, nullptr,
                dotsP, K, 0, Rc, Rc * 64, 1, S, n0, m0, h, s, s * K, 0);
  }
}

// ---------------------------------------------------------------------------
// tie softmax (bf16 inputs)
// ---------------------------------------------------------------------------
__global__ __launch_bounds__(128) void tie_kernel(const __bf16* __restrict__ qs,
                                                  const __bf16* __restrict__ ks,
                                                  float* __restrict__ wtie) {
  int bid = blockIdx.x;
  int l = bid >> 3, h = bid & 7;
  int r = threadIdx.x;
  int wid = r >> 6;
  const __bf16* qp = qs + (size_t)l * 128 + h * 16;
  const __bf16* kp = ks + ((size_t)r * L_ + l) * 128 + h * 16;
  bf16x8 q0 = *(const bf16x8*)qp;
  bf16x8 q1 = *(const bf16x8*)(qp + 8);
  bf16x8 k0 = *(const bf16x8*)kp;
  bf16x8 k1 = *(const bf16x8*)(kp + 8);
  float s = 0.f;
#pragma unroll
  for (int i = 0; i < 8; ++i)
    s += (float)q0[i] * (float)k0[i] + (float)q1[i] * (float)k1[i];
  s *= 0.25f;
  __shared__ float sm[2], ss[2];
  float wm = wred_max(s);
  if ((r & 63) == 0) sm[wid] = wm;
  __syncthreads();
  float mx = fmaxf(sm[0], sm[1]);
  float e = __expf(s - mx);
  float wsum = wred_sum(e);
  if ((r & 63) == 0) ss[wid] = wsum;
  __syncthreads();
  float tot = ss[0] + ss[1];
  wtie[((size_t)l * H_ + h) * R_ + r] = e / tot;
}

// ---------------------------------------------------------------------------
// softmax over last dim of (pb + sum of S split-K partials) -> attn bf16
// ---------------------------------------------------------------------------
__global__ __launch_bounds__(128) void sm_kernel(const float* __restrict__ pb,
                                                 const float* __restrict__ dp,
                                                 int S, __bf16* __restrict__ ab) {
  size_t row = blockIdx.x;
  int t = threadIdx.x;
  int wid = t >> 6;
  const float* p0 = pb + row * L_;
  float x0 = p0[t], x1 = p0[t + 128], x2 = p0[t + 256];
  const size_t HLL = (size_t)H_ * L_ * L_;
  for (int s = 0; s < S; ++s) {
    const float* ps = dp + s * HLL + row * L_;
    x0 += ps[t]; x1 += ps[t + 128]; x2 += ps[t + 256];
  }
  __shared__ float sm[2], ss[2];
  float m = wred_max(fmaxf(x0, fmaxf(x1, x2)));
  if ((t & 63) == 0) sm[wid] = m;
  __syncthreads();
  m = fmaxf(sm[0], sm[1]);
  float e0 = __expf(x0 - m), e1 = __expf(x1 - m), e2 = __expf(x2 - m);
  float s2 = wred_sum(e0 + e1 + e2);
  if ((t & 63) == 0) ss[wid] = s2;
  __syncthreads();
  float inv = 1.0f / (ss[0] + ss[1]);
  __bf16* op = ab + row * L_;
  op[t] = (__bf16)(e0 * inv);
  op[t + 128] = (__bf16)(e1 * inv);
  op[t + 256] = (__bf16)(e2 * inv);
}

// ---------------------------------------------------------------------------
extern "C" void kernel_launch(void* const* d_in, const int* in_sizes, int n_in,
                              void* d_out, int out_size, void* d_ws,
                              size_t ws_size, hipStream_t stream) {
  (void)in_sizes; (void)n_in; (void)out_size;
  const float* m = (const float*)d_in[0];
  const float* pair = (const float*)d_in[1];
  const float* Wq_w = (const float*)d_in[2];
  const float* Wkv_w = (const float*)d_in[3];
  const float* Wo_w = (const float*)d_in[4];
  const float* bo_w = (const float*)d_in[5];
  const float* Wq_h = (const float*)d_in[6];
  const float* Wkv_h = (const float*)d_in[7];
  const float* Wo_h = (const float*)d_in[8];
  const float* bo_h = (const float*)d_in[9];
  const float* ln_g = (const float*)d_in[10];
  const float* ln_b = (const float*)d_in[11];
  const float* Wpair = (const float*)d_in[12];
  const float* Wsq = (const float*)d_in[13];
  const float* bsq = (const float*)d_in[14];
  const float* Wsk = (const float*)d_in[15];
  const float* bsk = (const float*)d_in[16];
  float* out = (float*)d_out;

  // ---- choose chunking (CH) and split count (S = 8/CH) to fit workspace ----
  const size_t fixedBase = 22446080u;
  int CH = 1;
  for (; CH < 8; CH *= 2) {
    size_t partials = (size_t)(8 / CH) * 4718592u;
    size_t o = 201326592u / CH;
    if (o < 25165824u) o = 25165824u;
    if (fixedBase + partials + o <= ws_size) break;
  }
  const int S = 8 / CH;
  const int Lc = L_ / CH;
  const int Rc = R_ / CH;

  unsigned char* base = (unsigned char*)d_ws;
  __bf16* m_bf = (__bf16*)base;       base += 12582912;
  __bf16* WTw = (__bf16*)base;        base += 393216;
  __bf16* WThqk = (__bf16*)base;      base += 262144;
  __bf16* WTvh = (__bf16*)base;       base += 131072;
  __bf16* WoTw = (__bf16*)base;       base += 131072;
  __bf16* WoTh = (__bf16*)base;       base += 131072;
  __bf16* WskT = (__bf16*)base;       base += 32768;
  __bf16* WsqT = (__bf16*)base;       base += 32768;
  float* wtie = (float*)base;         base += 1572864;
  float* pb = (float*)base;           base += 4718592;
  __bf16* attnb = (__bf16*)base;      base += 2359296;
  __bf16* qsb = (__bf16*)base;        base += 98304;
  float* dotsP = (float*)base;        base += (size_t)S * 4718592u;
  unsigned char* ovl = base;
  __bf16* ksb = (__bf16*)ovl;  // phase A only

  const size_t BUF = 25165824u / CH;
  __bf16* qb = (__bf16*)ovl;
  __bf16* kb = qb + BUF;
  __bf16* vb = kb + BUF;
  __bf16* ob = vb + BUF;

  prep_kernel<<<3208, 256, 0, stream>>>(m, m_bf, Wq_w, Wkv_w, Wq_h, Wkv_h, Wo_w,
                                        Wo_h, Wsk, Wsq, WTw, WThqk, WTvh, WoTw,
                                        WoTh, WskT, WsqT);

  // tie projections (ks rows 0..383 tiles, qs rows 384..386) + softmax
  mm_k<8><<<dim3(1, 387), 256, 0, stream>>>(m_bf, WskT, bsk, bsq, ksb, qsb, WsqT,
                                            nullptr, 128, 0, Rc, 0, 0, 1);
  tie_kernel<<<L_ * H_, 128, 0, stream>>>(qsb, ksb, wtie);

  if (CH == 1) {
    // mega1: fattw || mm1 || mm6 + lnpb tail
    mega_kernel<<<8256, 256, 0, stream>>>(m_bf, WTw, ob, WThqk, wtie, qb, kb,
                                          WTvh, vb, Rc, pair, ln_g, ln_b,
                                          Wpair, pb);
    // mega2: mm4 (w-path epilogue) || mm2 (h-path dots)
    mega2_kernel<<<960, 256, 0, stream>>>(ob, WoTw, bo_w, out, qb, kb, dotsP,
                                          Rc, S);
    sm_kernel<<<H_ * L_, 128, 0, stream>>>(pb, dotsP, S, attnb);
    mm_k<3><<<12 * Rc, 256, 0, stream>>>(attnb, vb, nullptr, nullptr, ob, nullptr,
                                         nullptr, nullptr, 384, 0, Rc, 0, 0, 1);
    mm_k<5><<<dim3(1, Rc * 3), 256, 0, stream>>>(ob, WoTh, bo_h, nullptr, nullptr, nullptr,
                                                 nullptr, out, 512, 0, Rc, 0, 0, 1);
  } else {
    lnpb_kernel<<<(L_ * L_) / 256, 256, 0, stream>>>(pair, ln_g, ln_b, Wpair, pb);
    for (int c = 0; c < CH; ++c) {
      int l0 = c * Lc;
      fattw_kernel<<<Lc * H_, 256, 0, stream>>>(m_bf, WTw, ob, l0);
      mm_k<4><<<dim3(1, Lc), 256, 0, stream>>>(ob, WoTw, bo_w, nullptr, nullptr, nullptr,
                                               nullptr, out, 512, l0, Rc, 0, 0, 1);
    }
    for (int c = 0; c < CH; ++c) {
      int r0 = c * Rc;
      mm_k<1><<<dim3(8, Rc * 3), 256, 0, stream>>>(m_bf, WThqk, nullptr, wtie, qb, kb,
                                                   nullptr, nullptr, 128, r0, Rc, 0, 0, 1);
      mm_k<2><<<9 * H_ * S, 256, 0, stream>>>(qb, kb, nullptr, nullptr, nullptr,
                                              nullptr, nullptr, dotsP,
                                              (Rc * 64) / S, r0, Rc, Rc * 64,
                                              (c == 0) ? 1 : 0, S);
    }
    sm_kernel<<<H_ * L_, 128, 0, stream>>>(pb, dotsP, S, attnb);
    for (int c = 0; c < CH; ++c) {
      int r0 = c * Rc;
      mm_k<6><<<12 * Rc, 256, 0, stream>>>(WTvh, m_bf, nullptr, nullptr, vb, nullptr,
                                           nullptr, nullptr, 128, r0, Rc, 0, 0, 1);
      mm_k<3><<<12 * Rc, 256, 0, stream>>>(attnb, vb, nullptr, nullptr, ob, nullptr,
                                           nullptr, nullptr, 384, r0, Rc, 0, 0, 1);
      mm_k<5><<<dim3(1, Rc * 3), 256, 0, stream>>>(ob, WoTh, bo_h, nullptr, nullptr, nullptr,
                                                   nullptr, out, 512, r0, Rc, 0, 0, 1);
    }
  }
}